// Round 4
// baseline (863.515 us; speedup 1.0000x reference)
//
#include <hip/hip_runtime.h>
#include <math.h>

#define E_NUM 320000
#define N_NUM 10000
#define NB16  (N_NUM / 16)          // 625 blocks, exact
#define TAB   2048

__device__ __forceinline__ float ssp_f(float x) {
    // softplus(x) - log(2), stable: max(x,0) + log(1+exp(-|x|)) - log2
    return fmaxf(x, 0.f) + __logf(1.f + __expf(-fabsf(x))) - 0.69314718056f;
}

// ---------------------------------------------------------------------------
// counting-sort phase 1: histogram of dst
__global__ __launch_bounds__(256) void hist_kernel(const int* __restrict__ ei,
                                                   int* __restrict__ counts) {
    int e = blockIdx.x * 256 + threadIdx.x;
    if (e < E_NUM) atomicAdd(&counts[ei[E_NUM + e]], 1);
}

// phase 2: exclusive scan over 10000 bins (single block, 256 threads x 40)
__global__ __launch_bounds__(256) void scan_kernel(const int* __restrict__ counts,
                                                   int* __restrict__ offs,
                                                   int* __restrict__ cursor) {
    __shared__ int part[256];
    const int tid = threadIdx.x;
    const int CH = 40;                 // 256*40 = 10240 >= 10000
    int base = tid * CH;
    int s = 0;
    for (int i = 0; i < CH; ++i) {
        int idx = base + i;
        if (idx < N_NUM) s += counts[idx];
    }
    part[tid] = s;
    __syncthreads();
    for (int off = 1; off < 256; off <<= 1) {
        int v = (tid >= off) ? part[tid - off] : 0;
        __syncthreads();
        part[tid] += v;
        __syncthreads();
    }
    int run = (tid > 0) ? part[tid - 1] : 0;
    for (int i = 0; i < CH; ++i) {
        int idx = base + i;
        if (idx < N_NUM) {
            offs[idx] = run;
            cursor[idx] = run;
            run += counts[idx];
        }
    }
    if (tid == 255) offs[N_NUM] = part[255];
}

// phase 3: scatter edges to dst-sorted order; precompute table index + frac
__global__ __launch_bounds__(256) void scatter_kernel(const int* __restrict__ ei,
                                                      const float* __restrict__ dist,
                                                      int* __restrict__ cursor,
                                                      int* __restrict__ src_s,
                                                      int* __restrict__ i0_s,
                                                      float* __restrict__ fr_s) {
    int e = blockIdx.x * 256 + threadIdx.x;
    if (e >= E_NUM) return;
    int d = ei[E_NUM + e];
    int pos = atomicAdd(&cursor[d], 1);
    src_s[pos] = ei[e];
    float t = dist[e] * ((float)(TAB - 1) / 10.0f);
    int i0 = (int)t;
    if (i0 > TAB - 2) i0 = TAB - 2;
    i0_s[pos] = i0;
    fr_s[pos] = t - (float)i0;
}

// ---------------------------------------------------------------------------
// Build interleaved filter tables:
//   tabI[l][i][c] = ( W_l(d_i)[c], W_l(d_{i+1})[c] )  as float pairs
// so the agg lerp pair for cols (c, c+1) is ONE float4 at tabI + i*256 + c*2.
// W(d) = ((ssp(ea(d)@w1+b1)@w2)+b2) * C(d); d_i = i * 10/(TAB-1).
__global__ __launch_bounds__(256) void table_kernel(const float* __restrict__ mlp_w1,
                                                    const float* __restrict__ mlp_b1,
                                                    const float* __restrict__ mlp_w2,
                                                    const float* __restrict__ mlp_b2,
                                                    float* __restrict__ tabI) {
    __shared__ float eaT[50][68];
    __shared__ float hT[128][68];
    const int tid = threadIdx.x;
    const int l = blockIdx.x / (TAB / 64);
    const int r0 = (blockIdx.x % (TAB / 64)) * 64;
    const float DG = 10.0f / (float)(TAB - 1);
    const float STEP = 10.0f / 49.0f;
    const float COEFF = -0.5f / (STEP * STEP);
    const float* w1 = mlp_w1 + l * 6400;
    const float* b1 = mlp_b1 + l * 128;
    const float* w2 = mlp_w2 + l * 16384;
    const float* b2 = mlp_b2 + l * 128;
    float* tl = tabI + (size_t)l * TAB * 256;

    for (int i = tid; i < 50 * 64; i += 256) {
        int k = i >> 6, e = i & 63;
        float d = (float)(r0 + e) * DG;
        float t = d - (float)k * STEP;
        eaT[k][e] = __expf(COEFF * t * t);
    }
    __syncthreads();

    const int eg = tid & 15;   // rows eg*4 .. +3
    const int jg = tid >> 4;   // cols jg*8 .. +7

    float acc[4][8];
    #pragma unroll
    for (int i = 0; i < 4; ++i)
        #pragma unroll
        for (int j = 0; j < 8; ++j) acc[i][j] = 0.f;
    {
        const float* Bj = w1 + jg * 8;
        #pragma unroll 2
        for (int k = 0; k < 50; ++k) {
            float4 a = *(const float4*)&eaT[k][eg * 4];
            float b[8];
            *(float4*)&b[0] = *(const float4*)(Bj + k * 128);
            *(float4*)&b[4] = *(const float4*)(Bj + k * 128 + 4);
            float av[4] = {a.x, a.y, a.z, a.w};
            #pragma unroll
            for (int i = 0; i < 4; ++i)
                #pragma unroll
                for (int j = 0; j < 8; ++j) acc[i][j] = fmaf(av[i], b[j], acc[i][j]);
        }
    }
    {
        float b1v[8];
        *(float4*)&b1v[0] = *(const float4*)(b1 + jg * 8);
        *(float4*)&b1v[4] = *(const float4*)(b1 + jg * 8 + 4);
        #pragma unroll
        for (int j = 0; j < 8; ++j) {
            float4 v;
            v.x = ssp_f(acc[0][j] + b1v[j]);
            v.y = ssp_f(acc[1][j] + b1v[j]);
            v.z = ssp_f(acc[2][j] + b1v[j]);
            v.w = ssp_f(acc[3][j] + b1v[j]);
            *(float4*)&hT[jg * 8 + j][eg * 4] = v;
        }
    }
    __syncthreads();

    float acc2[4][8];
    #pragma unroll
    for (int i = 0; i < 4; ++i)
        #pragma unroll
        for (int j = 0; j < 8; ++j) acc2[i][j] = 0.f;
    {
        const float* Bj = w2 + jg * 8;
        #pragma unroll 4
        for (int k = 0; k < 128; ++k) {
            float4 a = *(const float4*)&hT[k][eg * 4];
            float b[8];
            *(float4*)&b[0] = *(const float4*)(Bj + k * 128);
            *(float4*)&b[4] = *(const float4*)(Bj + k * 128 + 4);
            float av[4] = {a.x, a.y, a.z, a.w};
            #pragma unroll
            for (int i = 0; i < 4; ++i)
                #pragma unroll
                for (int j = 0; j < 8; ++j) acc2[i][j] = fmaf(av[i], b[j], acc2[i][j]);
        }
    }

    float bv[8];
    *(float4*)&bv[0] = *(const float4*)(b2 + jg * 8);
    *(float4*)&bv[4] = *(const float4*)(b2 + jg * 8 + 4);
    #pragma unroll
    for (int i = 0; i < 4; ++i) {
        int row = r0 + eg * 4 + i;
        float d = (float)row * DG;
        float C = 0.5f * (__cosf(d * 0.31415926535f) + 1.0f);
        float o[8];
        #pragma unroll
        for (int j = 0; j < 8; ++j) o[j] = (acc2[i][j] + bv[j]) * C;
        // interleaved writes: this row is slot .x of row, slot .y of row-1
        float* tr = tl + (size_t)row * 256;
        #pragma unroll
        for (int j = 0; j < 8; ++j) tr[(jg * 8 + j) * 2] = o[j];
        if (row > 0) {
            float* tp = tl + (size_t)(row - 1) * 256;
            #pragma unroll
            for (int j = 0; j < 8; ++j) tp[(jg * 8 + j) * 2 + 1] = o[j];
        }
    }
}

// ---------------------------------------------------------------------------
// Layer 0 front: h = emb[x]; xf = h @ lin1_w[0].  16 rows/block, 512 threads.
__global__ __launch_bounds__(512) void embed_lin1_kernel(const int* __restrict__ x,
                                                         const float* __restrict__ emb,
                                                         const float* __restrict__ B,
                                                         float* __restrict__ h,
                                                         float* __restrict__ xf) {
    __shared__ float AT[128][17];
    __shared__ int s_x[16];
    const int tid = threadIdx.x;
    const int n0 = blockIdx.x * 16;

    if (tid < 16) s_x[tid] = x[n0 + tid];
    __syncthreads();
    for (int i = tid; i < 16 * 128; i += 512) {
        int r = i >> 7, c = i & 127;
        float v = emb[s_x[r] * 128 + c];
        AT[c][r] = v;
        h[(size_t)(n0 + r) * 128 + c] = v;
    }
    __syncthreads();

    const int r  = tid & 15;
    const int c0 = (tid >> 4) * 4;
    float acc[4] = {0.f, 0.f, 0.f, 0.f};
    for (int k = 0; k < 128; k += 4) {
        float a[4];
        #pragma unroll
        for (int u = 0; u < 4; ++u) a[u] = AT[k + u][r];
        #pragma unroll
        for (int u = 0; u < 4; ++u) {
            float4 b = *(const float4*)(B + (size_t)(k + u) * 128 + c0);
            acc[0] = fmaf(a[u], b.x, acc[0]);
            acc[1] = fmaf(a[u], b.y, acc[1]);
            acc[2] = fmaf(a[u], b.z, acc[2]);
            acc[3] = fmaf(a[u], b.w, acc[3]);
        }
    }
    *(float4*)(xf + (size_t)(n0 + r) * 128 + c0) = *(float4*)acc;
}

// ---------------------------------------------------------------------------
// Fused layer kernel: 16 nodes/block, 512 threads (8 waves).
//   phase A: agg (sorted segments, lerp from interleaved table) -> LDS
//   stage 1: conv  = agg @ lin2_w + lin2_b ; t = ssp(conv)
//   stage 2: h_new = h + t @ lin_w + lin_b
//   stage 3: xf_out = h_new @ lin1_next                (if !LAST)
//   head   : gs += colsum(ssp(h_new@o1w+o1b)@o2w+o2b)  (if LAST)
template <bool LAST>
__global__ __launch_bounds__(512) void layer_kernel(const int* __restrict__ offs,
                                                    const int* __restrict__ src_s,
                                                    const int* __restrict__ i0_s,
                                                    const float* __restrict__ fr_s,
                                                    const float* __restrict__ xf,
                                                    const float* __restrict__ tabI,
                                                    const float* __restrict__ lin2_w,
                                                    const float* __restrict__ lin2_b,
                                                    const float* __restrict__ lin_w,
                                                    const float* __restrict__ lin_b,
                                                    const float* __restrict__ lin1_next,
                                                    float* __restrict__ h,
                                                    float* __restrict__ xf_out,
                                                    const float* __restrict__ o1w,
                                                    const float* __restrict__ o1b,
                                                    const float* __restrict__ o2w,
                                                    const float* __restrict__ o2b,
                                                    float* __restrict__ gs) {
    __shared__ float AT[128][17];
    const int tid = threadIdx.x;
    const int n0 = blockIdx.x * 16;

    // ---- phase A: aggregate this block's 16 nodes into AT (k-major) ----
    {
        const int wv = tid >> 6;       // 0..7
        const int lane = tid & 63;
        const int c2 = lane * 2;
        for (int nl = wv; nl < 16; nl += 8) {
            int node = n0 + nl;
            int beg = offs[node], end = offs[node + 1];
            float accA0 = 0.f, accA1 = 0.f, accB0 = 0.f, accB1 = 0.f;
            int e = beg;
            for (; e + 4 <= end; e += 4) {
                int   s[4], i0[4];
                float f[4];
                #pragma unroll
                for (int u = 0; u < 4; ++u) {
                    s[u]  = src_s[e + u];
                    i0[u] = i0_s[e + u];
                    f[u]  = fr_s[e + u];
                }
                float2 xv[4];
                float4 tv[4];
                #pragma unroll
                for (int u = 0; u < 4; ++u) {
                    xv[u] = *(const float2*)(xf + (size_t)s[u] * 128 + c2);
                    tv[u] = *(const float4*)(tabI + (size_t)i0[u] * 256 + c2 * 2);
                }
                #pragma unroll
                for (int u = 0; u < 4; ++u) {
                    float w0 = fmaf(f[u], tv[u].y - tv[u].x, tv[u].x);
                    float w1 = fmaf(f[u], tv[u].w - tv[u].z, tv[u].z);
                    if (u & 1) {
                        accB0 = fmaf(xv[u].x, w0, accB0);
                        accB1 = fmaf(xv[u].y, w1, accB1);
                    } else {
                        accA0 = fmaf(xv[u].x, w0, accA0);
                        accA1 = fmaf(xv[u].y, w1, accA1);
                    }
                }
            }
            for (; e < end; ++e) {
                int   s  = src_s[e];
                int   i0 = i0_s[e];
                float f  = fr_s[e];
                float2 xv = *(const float2*)(xf + (size_t)s * 128 + c2);
                float4 tv = *(const float4*)(tabI + (size_t)i0 * 256 + c2 * 2);
                float w0 = fmaf(f, tv.y - tv.x, tv.x);
                float w1 = fmaf(f, tv.w - tv.z, tv.z);
                accA0 = fmaf(xv.x, w0, accA0);
                accA1 = fmaf(xv.y, w1, accA1);
            }
            AT[c2][nl]     = accA0 + accB0;
            AT[c2 + 1][nl] = accA1 + accB1;
        }
    }
    __syncthreads();

    const int r  = tid & 15;
    const int c0 = (tid >> 4) * 4;

    // ---- stage 1: conv = agg @ lin2_w ; t = ssp(conv + lin2_b) ----
    float acc[4] = {0.f, 0.f, 0.f, 0.f};
    for (int k = 0; k < 128; k += 4) {
        float a[4];
        #pragma unroll
        for (int u = 0; u < 4; ++u) a[u] = AT[k + u][r];
        #pragma unroll
        for (int u = 0; u < 4; ++u) {
            float4 b = *(const float4*)(lin2_w + (size_t)(k + u) * 128 + c0);
            acc[0] = fmaf(a[u], b.x, acc[0]);
            acc[1] = fmaf(a[u], b.y, acc[1]);
            acc[2] = fmaf(a[u], b.z, acc[2]);
            acc[3] = fmaf(a[u], b.w, acc[3]);
        }
    }
    float tval[4];
    {
        float4 bv = *(const float4*)(lin2_b + c0);
        tval[0] = ssp_f(acc[0] + bv.x);
        tval[1] = ssp_f(acc[1] + bv.y);
        tval[2] = ssp_f(acc[2] + bv.z);
        tval[3] = ssp_f(acc[3] + bv.w);
    }
    __syncthreads();   // all stage-1 reads of AT done
    #pragma unroll
    for (int j = 0; j < 4; ++j) AT[c0 + j][r] = tval[j];
    __syncthreads();

    // ---- stage 2: h_new = h + t @ lin_w + lin_b ----
    float acc2[4] = {0.f, 0.f, 0.f, 0.f};
    for (int k = 0; k < 128; k += 4) {
        float a[4];
        #pragma unroll
        for (int u = 0; u < 4; ++u) a[u] = AT[k + u][r];
        #pragma unroll
        for (int u = 0; u < 4; ++u) {
            float4 b = *(const float4*)(lin_w + (size_t)(k + u) * 128 + c0);
            acc2[0] = fmaf(a[u], b.x, acc2[0]);
            acc2[1] = fmaf(a[u], b.y, acc2[1]);
            acc2[2] = fmaf(a[u], b.z, acc2[2]);
            acc2[3] = fmaf(a[u], b.w, acc2[3]);
        }
    }
    float hn[4];
    {
        float4 bv = *(const float4*)(lin_b + c0);
        float* hr = h + (size_t)(n0 + r) * 128 + c0;
        float4 hv = *(const float4*)hr;
        hn[0] = hv.x + acc2[0] + bv.x;
        hn[1] = hv.y + acc2[1] + bv.y;
        hn[2] = hv.z + acc2[2] + bv.z;
        hn[3] = hv.w + acc2[3] + bv.w;
        if (!LAST) *(float4*)hr = *(float4*)hn;   // next layer needs h
    }
    __syncthreads();   // all stage-2 reads of AT done
    #pragma unroll
    for (int j = 0; j < 4; ++j) AT[c0 + j][r] = hn[j];
    __syncthreads();

    if constexpr (!LAST) {
        // ---- stage 3: xf_out = h_new @ lin1_next ----
        float acc3[4] = {0.f, 0.f, 0.f, 0.f};
        for (int k = 0; k < 128; k += 4) {
            float a[4];
            #pragma unroll
            for (int u = 0; u < 4; ++u) a[u] = AT[k + u][r];
            #pragma unroll
            for (int u = 0; u < 4; ++u) {
                float4 b = *(const float4*)(lin1_next + (size_t)(k + u) * 128 + c0);
                acc3[0] = fmaf(a[u], b.x, acc3[0]);
                acc3[1] = fmaf(a[u], b.y, acc3[1]);
                acc3[2] = fmaf(a[u], b.z, acc3[2]);
                acc3[3] = fmaf(a[u], b.w, acc3[3]);
            }
        }
        *(float4*)(xf_out + (size_t)(n0 + r) * 128 + c0) = *(float4*)acc3;
    } else {
        // ---- fused head: t1 = ssp(h_new@o1w+o1b); t2 = t1@o2w+o2b; colsum ----
        __shared__ float BT[64][17];
        __shared__ float red[16][64];
        const int cH = (tid >> 4) * 2;   // 32 groups x 2 cols = 64

        float a1[2] = {0.f, 0.f};
        for (int k = 0; k < 128; k += 4) {
            float a[4];
            #pragma unroll
            for (int u = 0; u < 4; ++u) a[u] = AT[k + u][r];
            #pragma unroll
            for (int u = 0; u < 4; ++u) {
                float2 b = *(const float2*)(o1w + (size_t)(k + u) * 64 + cH);
                a1[0] = fmaf(a[u], b.x, a1[0]);
                a1[1] = fmaf(a[u], b.y, a1[1]);
            }
        }
        float t1[2];
        {
            float2 bv = *(const float2*)(o1b + cH);
            t1[0] = ssp_f(a1[0] + bv.x);
            t1[1] = ssp_f(a1[1] + bv.y);
        }
        __syncthreads();
        BT[cH][r]     = t1[0];
        BT[cH + 1][r] = t1[1];
        __syncthreads();

        float a2[2] = {0.f, 0.f};
        for (int k = 0; k < 64; k += 4) {
            float a[4];
            #pragma unroll
            for (int u = 0; u < 4; ++u) a[u] = BT[k + u][r];
            #pragma unroll
            for (int u = 0; u < 4; ++u) {
                float2 b = *(const float2*)(o2w + (size_t)(k + u) * 64 + cH);
                a2[0] = fmaf(a[u], b.x, a2[0]);
                a2[1] = fmaf(a[u], b.y, a2[1]);
            }
        }
        {
            float2 bv = *(const float2*)(o2b + cH);
            red[r][cH]     = a2[0] + bv.x;
            red[r][cH + 1] = a2[1] + bv.y;
        }
        __syncthreads();
        if (tid < 64) {
            float s = 0.f;
            #pragma unroll
            for (int rr = 0; rr < 16; ++rr) s += red[rr][tid];
            atomicAdd(&gs[tid], s);
        }
    }
}

// out[i] = ro_b[i] + sum_k gs[k] * ro_w[k][i]
__global__ void final_kernel(const float* __restrict__ gs,
                             const float* __restrict__ ro_w,
                             const float* __restrict__ ro_b,
                             float* __restrict__ out) {
    int i = threadIdx.x;
    if (i < 12) {
        float s = ro_b[i];
        for (int k = 0; k < 64; ++k) s = fmaf(gs[k], ro_w[k * 12 + i], s);
        out[i] = s;
    }
}

// ---------------------------------------------------------------------------
extern "C" void kernel_launch(void* const* d_in, const int* in_sizes, int n_in,
                              void* d_out, int out_size, void* d_ws, size_t ws_size,
                              hipStream_t stream) {
    const int*   x      = (const int*)d_in[0];
    const int*   ei     = (const int*)d_in[1];
    const float* dist   = (const float*)d_in[2];
    const float* emb    = (const float*)d_in[3];
    const float* mlp_w1 = (const float*)d_in[4];
    const float* mlp_b1 = (const float*)d_in[5];
    const float* mlp_w2 = (const float*)d_in[6];
    const float* mlp_b2 = (const float*)d_in[7];
    const float* lin1_w = (const float*)d_in[8];
    const float* lin2_w = (const float*)d_in[9];
    const float* lin2_b = (const float*)d_in[10];
    const float* lin_w  = (const float*)d_in[11];
    const float* lin_b  = (const float*)d_in[12];
    const float* out1_w = (const float*)d_in[13];
    const float* out1_b = (const float*)d_in[14];
    const float* out2_w = (const float*)d_in[15];
    const float* out2_b = (const float*)d_in[16];
    const float* ro_w   = (const float*)d_in[17];
    const float* ro_b   = (const float*)d_in[18];
    float* out = (float*)d_out;

    // workspace layout
    float* h      = (float*)d_ws;                    // N*128
    float* xf0    = h + N_NUM * 128;                 // N*128
    float* xf1    = xf0 + N_NUM * 128;               // N*128
    float* tabI   = xf1 + N_NUM * 128;               // 6*TAB*256
    float* fr_s   = tabI + 6 * TAB * 256;            // E
    float* gs     = fr_s + E_NUM;                    // 64
    int*   src_s  = (int*)(gs + 64);                 // E
    int*   i0_s   = src_s + E_NUM;                   // E
    int*   offs   = i0_s + E_NUM;                    // N+1
    int*   cursor = offs + N_NUM + 1;                // N
    int*   counts = cursor + N_NUM;                  // N

    hipMemsetAsync(counts, 0, N_NUM * sizeof(int), stream);
    hipMemsetAsync(gs, 0, 64 * sizeof(float), stream);

    // sort edges by dst (once; dst constant across layers)
    hist_kernel<<<(E_NUM + 255) / 256, 256, 0, stream>>>(ei, counts);
    scan_kernel<<<1, 256, 0, stream>>>(counts, offs, cursor);
    scatter_kernel<<<(E_NUM + 255) / 256, 256, 0, stream>>>(ei, dist, cursor,
                                                            src_s, i0_s, fr_s);

    // build all 6 layer filter tables (interleaved lerp-pair layout)
    table_kernel<<<6 * (TAB / 64), 256, 0, stream>>>(mlp_w1, mlp_b1, mlp_w2,
                                                     mlp_b2, tabI);

    // layer 0 front: h = emb[x], xf0 = h @ lin1_w[0]
    embed_lin1_kernel<<<NB16, 512, 0, stream>>>(x, emb, lin1_w, h, xf0);

    for (int l = 0; l < 6; ++l) {
        float* xin  = (l & 1) ? xf1 : xf0;
        float* xout = (l & 1) ? xf0 : xf1;
        const float* tl = tabI + (size_t)l * TAB * 256;
        if (l < 5) {
            layer_kernel<false><<<NB16, 512, 0, stream>>>(
                offs, src_s, i0_s, fr_s, xin, tl,
                lin2_w + l * 16384, lin2_b + l * 128,
                lin_w + l * 16384, lin_b + l * 128,
                lin1_w + (l + 1) * 16384, h, xout,
                nullptr, nullptr, nullptr, nullptr, nullptr);
        } else {
            layer_kernel<true><<<NB16, 512, 0, stream>>>(
                offs, src_s, i0_s, fr_s, xin, tl,
                lin2_w + l * 16384, lin2_b + l * 128,
                lin_w + l * 16384, lin_b + l * 128,
                nullptr, h, nullptr,
                out1_w, out1_b, out2_w, out2_b, gs);
        }
    }

    final_kernel<<<1, 64, 0, stream>>>(gs, ro_w, ro_b, out);
}

// Round 5
// 777.464 us; speedup vs baseline: 1.1107x; 1.1107x over previous
//
#include <hip/hip_runtime.h>
#include <math.h>

#define E_NUM 320000
#define N_NUM 10000
#define NB16  (N_NUM / 16)          // 625 blocks, exact
#define TAB   2048

typedef unsigned short ushort_t;

__device__ __forceinline__ float ssp_f(float x) {
    // softplus(x) - log(2), stable: max(x,0) + log(1+exp(-|x|)) - log2
    return fmaxf(x, 0.f) + __logf(1.f + __expf(-fabsf(x))) - 0.69314718056f;
}

__device__ __forceinline__ float bf2f(ushort_t u) {
    union { unsigned int i; float f; } v;
    v.i = ((unsigned int)u) << 16;
    return v.f;
}
__device__ __forceinline__ ushort_t f2bf(float f) {
    union { float f; unsigned int i; } v;
    v.f = f;
    unsigned int u = v.i;
    unsigned int r = (u + 0x7FFFu + ((u >> 16) & 1u)) >> 16;   // RNE
    return (ushort_t)r;
}

// ---------------------------------------------------------------------------
// counting-sort phase 1: histogram of dst
__global__ __launch_bounds__(256) void hist_kernel(const int* __restrict__ ei,
                                                   int* __restrict__ counts) {
    int e = blockIdx.x * 256 + threadIdx.x;
    if (e < E_NUM) atomicAdd(&counts[ei[E_NUM + e]], 1);
}

// phase 2: exclusive scan over 10000 bins (single block, 256 threads x 40)
__global__ __launch_bounds__(256) void scan_kernel(const int* __restrict__ counts,
                                                   int* __restrict__ offs,
                                                   int* __restrict__ cursor) {
    __shared__ int part[256];
    const int tid = threadIdx.x;
    const int CH = 40;                 // 256*40 = 10240 >= 10000
    int base = tid * CH;
    int s = 0;
    for (int i = 0; i < CH; ++i) {
        int idx = base + i;
        if (idx < N_NUM) s += counts[idx];
    }
    part[tid] = s;
    __syncthreads();
    for (int off = 1; off < 256; off <<= 1) {
        int v = (tid >= off) ? part[tid - off] : 0;
        __syncthreads();
        part[tid] += v;
        __syncthreads();
    }
    int run = (tid > 0) ? part[tid - 1] : 0;
    for (int i = 0; i < CH; ++i) {
        int idx = base + i;
        if (idx < N_NUM) {
            offs[idx] = run;
            cursor[idx] = run;
            run += counts[idx];
        }
    }
    if (tid == 255) offs[N_NUM] = part[255];
}

// phase 3: scatter edges to dst-sorted order; pack meta = {src, (i0<<16)|fr16}
__global__ __launch_bounds__(256) void scatter_kernel(const int* __restrict__ ei,
                                                      const float* __restrict__ dist,
                                                      int* __restrict__ cursor,
                                                      int2* __restrict__ meta) {
    int e = blockIdx.x * 256 + threadIdx.x;
    if (e >= E_NUM) return;
    int d = ei[E_NUM + e];
    int pos = atomicAdd(&cursor[d], 1);
    float t = dist[e] * ((float)(TAB - 1) / 10.0f);
    int i0 = (int)t;
    if (i0 > TAB - 2) i0 = TAB - 2;
    float fr = t - (float)i0;
    int fr16 = (int)(fr * 65535.0f + 0.5f);
    meta[pos] = make_int2(ei[e], (i0 << 16) | fr16);
}

// ---------------------------------------------------------------------------
// Build bf16 interleaved filter tables:
//   tabB[l][i] row = 64 pairs x 4 bf16: (W_i[c], W_{i+1}[c], W_i[c+1], W_{i+1}[c+1])
// so the lerp pair for cols (c,c+1) is ONE 8 B load at tabB + i*256 + c*2 (ushorts).
// W(d) = ((ssp(ea(d)@w1+b1)@w2)+b2) * C(d); d_i = i * 10/(TAB-1).
__global__ __launch_bounds__(256) void table_kernel(const float* __restrict__ mlp_w1,
                                                    const float* __restrict__ mlp_b1,
                                                    const float* __restrict__ mlp_w2,
                                                    const float* __restrict__ mlp_b2,
                                                    ushort_t* __restrict__ tabB) {
    __shared__ float eaT[50][68];
    __shared__ float hT[128][68];
    const int tid = threadIdx.x;
    const int l = blockIdx.x / (TAB / 64);
    const int r0 = (blockIdx.x % (TAB / 64)) * 64;
    const float DG = 10.0f / (float)(TAB - 1);
    const float STEP = 10.0f / 49.0f;
    const float COEFF = -0.5f / (STEP * STEP);
    const float* w1 = mlp_w1 + l * 6400;
    const float* b1 = mlp_b1 + l * 128;
    const float* w2 = mlp_w2 + l * 16384;
    const float* b2 = mlp_b2 + l * 128;
    ushort_t* tl = tabB + (size_t)l * TAB * 256;

    for (int i = tid; i < 50 * 64; i += 256) {
        int k = i >> 6, e = i & 63;
        float d = (float)(r0 + e) * DG;
        float t = d - (float)k * STEP;
        eaT[k][e] = __expf(COEFF * t * t);
    }
    __syncthreads();

    const int eg = tid & 15;   // rows eg*4 .. +3
    const int jg = tid >> 4;   // cols jg*8 .. +7

    float acc[4][8];
    #pragma unroll
    for (int i = 0; i < 4; ++i)
        #pragma unroll
        for (int j = 0; j < 8; ++j) acc[i][j] = 0.f;
    {
        const float* Bj = w1 + jg * 8;
        #pragma unroll 2
        for (int k = 0; k < 50; ++k) {
            float4 a = *(const float4*)&eaT[k][eg * 4];
            float b[8];
            *(float4*)&b[0] = *(const float4*)(Bj + k * 128);
            *(float4*)&b[4] = *(const float4*)(Bj + k * 128 + 4);
            float av[4] = {a.x, a.y, a.z, a.w};
            #pragma unroll
            for (int i = 0; i < 4; ++i)
                #pragma unroll
                for (int j = 0; j < 8; ++j) acc[i][j] = fmaf(av[i], b[j], acc[i][j]);
        }
    }
    {
        float b1v[8];
        *(float4*)&b1v[0] = *(const float4*)(b1 + jg * 8);
        *(float4*)&b1v[4] = *(const float4*)(b1 + jg * 8 + 4);
        #pragma unroll
        for (int j = 0; j < 8; ++j) {
            float4 v;
            v.x = ssp_f(acc[0][j] + b1v[j]);
            v.y = ssp_f(acc[1][j] + b1v[j]);
            v.z = ssp_f(acc[2][j] + b1v[j]);
            v.w = ssp_f(acc[3][j] + b1v[j]);
            *(float4*)&hT[jg * 8 + j][eg * 4] = v;
        }
    }
    __syncthreads();

    float acc2[4][8];
    #pragma unroll
    for (int i = 0; i < 4; ++i)
        #pragma unroll
        for (int j = 0; j < 8; ++j) acc2[i][j] = 0.f;
    {
        const float* Bj = w2 + jg * 8;
        #pragma unroll 4
        for (int k = 0; k < 128; ++k) {
            float4 a = *(const float4*)&hT[k][eg * 4];
            float b[8];
            *(float4*)&b[0] = *(const float4*)(Bj + k * 128);
            *(float4*)&b[4] = *(const float4*)(Bj + k * 128 + 4);
            float av[4] = {a.x, a.y, a.z, a.w};
            #pragma unroll
            for (int i = 0; i < 4; ++i)
                #pragma unroll
                for (int j = 0; j < 8; ++j) acc2[i][j] = fmaf(av[i], b[j], acc2[i][j]);
        }
    }

    float bv[8];
    *(float4*)&bv[0] = *(const float4*)(b2 + jg * 8);
    *(float4*)&bv[4] = *(const float4*)(b2 + jg * 8 + 4);
    #pragma unroll
    for (int i = 0; i < 4; ++i) {
        int row = r0 + eg * 4 + i;
        float d = (float)row * DG;
        float C = 0.5f * (__cosf(d * 0.31415926535f) + 1.0f);
        #pragma unroll
        for (int j = 0; j < 8; ++j) {
            int col = jg * 8 + j;
            ushort_t b = f2bf((acc2[i][j] + bv[j]) * C);
            int base = (col >> 1) * 4 + (col & 1) * 2;
            tl[(size_t)row * 256 + base] = b;                       // slot W_row
            if (row > 0)
                tl[(size_t)(row - 1) * 256 + base + 1] = b;         // slot W_{row+1} of prev
        }
    }
}

// ---------------------------------------------------------------------------
// Layer 0 front: h = emb[x]; xf = bf16(h @ lin1_w[0]).  16 rows/block, 512 thr.
__global__ __launch_bounds__(512) void embed_lin1_kernel(const int* __restrict__ x,
                                                         const float* __restrict__ emb,
                                                         const float* __restrict__ B,
                                                         float* __restrict__ h,
                                                         ushort_t* __restrict__ xf) {
    __shared__ float AT[128][17];
    __shared__ int s_x[16];
    const int tid = threadIdx.x;
    const int n0 = blockIdx.x * 16;

    if (tid < 16) s_x[tid] = x[n0 + tid];
    __syncthreads();
    for (int i = tid; i < 16 * 128; i += 512) {
        int r = i >> 7, c = i & 127;
        float v = emb[s_x[r] * 128 + c];
        AT[c][r] = v;
        h[(size_t)(n0 + r) * 128 + c] = v;
    }
    __syncthreads();

    const int r  = tid & 15;
    const int c0 = (tid >> 4) * 4;
    float acc[4] = {0.f, 0.f, 0.f, 0.f};
    for (int k = 0; k < 128; k += 4) {
        float a[4];
        #pragma unroll
        for (int u = 0; u < 4; ++u) a[u] = AT[k + u][r];
        #pragma unroll
        for (int u = 0; u < 4; ++u) {
            float4 b = *(const float4*)(B + (size_t)(k + u) * 128 + c0);
            acc[0] = fmaf(a[u], b.x, acc[0]);
            acc[1] = fmaf(a[u], b.y, acc[1]);
            acc[2] = fmaf(a[u], b.z, acc[2]);
            acc[3] = fmaf(a[u], b.w, acc[3]);
        }
    }
    ushort_t o[4];
    #pragma unroll
    for (int j = 0; j < 4; ++j) o[j] = f2bf(acc[j]);
    *(ushort2*)(xf + (size_t)(n0 + r) * 128 + c0)     = *(ushort2*)&o[0];
    *(ushort2*)(xf + (size_t)(n0 + r) * 128 + c0 + 2) = *(ushort2*)&o[2];
}

// ---------------------------------------------------------------------------
// Fused layer kernel: 16 nodes/block, 512 threads (8 waves).
//   phase A: agg from bf16 xf + bf16 interleaved table -> LDS (fp32 acc)
//   stage 1: conv  = agg @ lin2_w + lin2_b ; t = ssp(conv)
//   stage 2: h_new = h + t @ lin_w + lin_b
//   stage 3: xf_out = bf16(h_new @ lin1_next)          (if !LAST)
//   head   : gs += colsum(ssp(h_new@o1w+o1b)@o2w+o2b)  (if LAST)
template <bool LAST>
__global__ __launch_bounds__(512) void layer_kernel(const int* __restrict__ offs,
                                                    const int2* __restrict__ meta,
                                                    const ushort_t* __restrict__ xf,
                                                    const ushort_t* __restrict__ tabB,
                                                    const float* __restrict__ lin2_w,
                                                    const float* __restrict__ lin2_b,
                                                    const float* __restrict__ lin_w,
                                                    const float* __restrict__ lin_b,
                                                    const float* __restrict__ lin1_next,
                                                    float* __restrict__ h,
                                                    ushort_t* __restrict__ xf_out,
                                                    const float* __restrict__ o1w,
                                                    const float* __restrict__ o1b,
                                                    const float* __restrict__ o2w,
                                                    const float* __restrict__ o2b,
                                                    float* __restrict__ gs) {
    __shared__ float AT[128][17];
    const int tid = threadIdx.x;
    const int n0 = blockIdx.x * 16;

    // ---- phase A: aggregate this block's 16 nodes into AT (k-major) ----
    {
        const int wv = tid >> 6;       // 0..7
        const int lane = tid & 63;
        const int c2 = lane * 2;
        for (int nl = wv; nl < 16; nl += 8) {
            int node = n0 + nl;
            int beg = offs[node], end = offs[node + 1];
            float accA0 = 0.f, accA1 = 0.f, accB0 = 0.f, accB1 = 0.f;
            int e = beg;
            for (; e + 4 <= end; e += 4) {
                int2 m[4];
                #pragma unroll
                for (int u = 0; u < 4; ++u) m[u] = meta[e + u];
                ushort2 xv[4];
                ushort4 tv[4];
                #pragma unroll
                for (int u = 0; u < 4; ++u) {
                    xv[u] = *(const ushort2*)(xf + (size_t)m[u].x * 128 + c2);
                    int i0 = ((unsigned int)m[u].y) >> 16;
                    tv[u] = *(const ushort4*)(tabB + (size_t)i0 * 256 + c2 * 2);
                }
                #pragma unroll
                for (int u = 0; u < 4; ++u) {
                    float f = (float)(m[u].y & 0xffff) * (1.0f / 65535.0f);
                    float t00 = bf2f(tv[u].x), t01 = bf2f(tv[u].y);
                    float t10 = bf2f(tv[u].z), t11 = bf2f(tv[u].w);
                    float w0 = fmaf(f, t01 - t00, t00);
                    float w1 = fmaf(f, t11 - t10, t10);
                    float x0 = bf2f(xv[u].x), x1 = bf2f(xv[u].y);
                    if (u & 1) {
                        accB0 = fmaf(x0, w0, accB0);
                        accB1 = fmaf(x1, w1, accB1);
                    } else {
                        accA0 = fmaf(x0, w0, accA0);
                        accA1 = fmaf(x1, w1, accA1);
                    }
                }
            }
            for (; e < end; ++e) {
                int2 m = meta[e];
                ushort2 xv = *(const ushort2*)(xf + (size_t)m.x * 128 + c2);
                int i0 = ((unsigned int)m.y) >> 16;
                ushort4 tv = *(const ushort4*)(tabB + (size_t)i0 * 256 + c2 * 2);
                float f = (float)(m.y & 0xffff) * (1.0f / 65535.0f);
                float t00 = bf2f(tv.x), t01 = bf2f(tv.y);
                float t10 = bf2f(tv.z), t11 = bf2f(tv.w);
                float w0 = fmaf(f, t01 - t00, t00);
                float w1 = fmaf(f, t11 - t10, t10);
                accA0 = fmaf(bf2f(xv.x), w0, accA0);
                accA1 = fmaf(bf2f(xv.y), w1, accA1);
            }
            AT[c2][nl]     = accA0 + accB0;
            AT[c2 + 1][nl] = accA1 + accB1;
        }
    }
    __syncthreads();

    const int r  = tid & 15;
    const int c0 = (tid >> 4) * 4;

    // ---- stage 1: conv = agg @ lin2_w ; t = ssp(conv + lin2_b) ----
    float acc[4] = {0.f, 0.f, 0.f, 0.f};
    for (int k = 0; k < 128; k += 4) {
        float a[4];
        #pragma unroll
        for (int u = 0; u < 4; ++u) a[u] = AT[k + u][r];
        #pragma unroll
        for (int u = 0; u < 4; ++u) {
            float4 b = *(const float4*)(lin2_w + (size_t)(k + u) * 128 + c0);
            acc[0] = fmaf(a[u], b.x, acc[0]);
            acc[1] = fmaf(a[u], b.y, acc[1]);
            acc[2] = fmaf(a[u], b.z, acc[2]);
            acc[3] = fmaf(a[u], b.w, acc[3]);
        }
    }
    float tval[4];
    {
        float4 bv = *(const float4*)(lin2_b + c0);
        tval[0] = ssp_f(acc[0] + bv.x);
        tval[1] = ssp_f(acc[1] + bv.y);
        tval[2] = ssp_f(acc[2] + bv.z);
        tval[3] = ssp_f(acc[3] + bv.w);
    }
    __syncthreads();   // all stage-1 reads of AT done
    #pragma unroll
    for (int j = 0; j < 4; ++j) AT[c0 + j][r] = tval[j];
    __syncthreads();

    // ---- stage 2: h_new = h + t @ lin_w + lin_b ----
    float acc2[4] = {0.f, 0.f, 0.f, 0.f};
    for (int k = 0; k < 128; k += 4) {
        float a[4];
        #pragma unroll
        for (int u = 0; u < 4; ++u) a[u] = AT[k + u][r];
        #pragma unroll
        for (int u = 0; u < 4; ++u) {
            float4 b = *(const float4*)(lin_w + (size_t)(k + u) * 128 + c0);
            acc2[0] = fmaf(a[u], b.x, acc2[0]);
            acc2[1] = fmaf(a[u], b.y, acc2[1]);
            acc2[2] = fmaf(a[u], b.z, acc2[2]);
            acc2[3] = fmaf(a[u], b.w, acc2[3]);
        }
    }
    float hn[4];
    {
        float4 bv = *(const float4*)(lin_b + c0);
        float* hr = h + (size_t)(n0 + r) * 128 + c0;
        float4 hv = *(const float4*)hr;
        hn[0] = hv.x + acc2[0] + bv.x;
        hn[1] = hv.y + acc2[1] + bv.y;
        hn[2] = hv.z + acc2[2] + bv.z;
        hn[3] = hv.w + acc2[3] + bv.w;
        if (!LAST) *(float4*)hr = *(float4*)hn;   // next layer needs h
    }
    __syncthreads();   // all stage-2 reads of AT done
    #pragma unroll
    for (int j = 0; j < 4; ++j) AT[c0 + j][r] = hn[j];
    __syncthreads();

    if constexpr (!LAST) {
        // ---- stage 3: xf_out = bf16(h_new @ lin1_next) ----
        float acc3[4] = {0.f, 0.f, 0.f, 0.f};
        for (int k = 0; k < 128; k += 4) {
            float a[4];
            #pragma unroll
            for (int u = 0; u < 4; ++u) a[u] = AT[k + u][r];
            #pragma unroll
            for (int u = 0; u < 4; ++u) {
                float4 b = *(const float4*)(lin1_next + (size_t)(k + u) * 128 + c0);
                acc3[0] = fmaf(a[u], b.x, acc3[0]);
                acc3[1] = fmaf(a[u], b.y, acc3[1]);
                acc3[2] = fmaf(a[u], b.z, acc3[2]);
                acc3[3] = fmaf(a[u], b.w, acc3[3]);
            }
        }
        ushort_t o[4];
        #pragma unroll
        for (int j = 0; j < 4; ++j) o[j] = f2bf(acc3[j]);
        *(ushort2*)(xf_out + (size_t)(n0 + r) * 128 + c0)     = *(ushort2*)&o[0];
        *(ushort2*)(xf_out + (size_t)(n0 + r) * 128 + c0 + 2) = *(ushort2*)&o[2];
    } else {
        // ---- fused head: t1 = ssp(h_new@o1w+o1b); t2 = t1@o2w+o2b; colsum ----
        __shared__ float BT[64][17];
        __shared__ float red[16][64];
        const int cH = (tid >> 4) * 2;   // 32 groups x 2 cols = 64

        float a1[2] = {0.f, 0.f};
        for (int k = 0; k < 128; k += 4) {
            float a[4];
            #pragma unroll
            for (int u = 0; u < 4; ++u) a[u] = AT[k + u][r];
            #pragma unroll
            for (int u = 0; u < 4; ++u) {
                float2 b = *(const float2*)(o1w + (size_t)(k + u) * 64 + cH);
                a1[0] = fmaf(a[u], b.x, a1[0]);
                a1[1] = fmaf(a[u], b.y, a1[1]);
            }
        }
        float t1[2];
        {
            float2 bv = *(const float2*)(o1b + cH);
            t1[0] = ssp_f(a1[0] + bv.x);
            t1[1] = ssp_f(a1[1] + bv.y);
        }
        __syncthreads();
        BT[cH][r]     = t1[0];
        BT[cH + 1][r] = t1[1];
        __syncthreads();

        float a2[2] = {0.f, 0.f};
        for (int k = 0; k < 64; k += 4) {
            float a[4];
            #pragma unroll
            for (int u = 0; u < 4; ++u) a[u] = BT[k + u][r];
            #pragma unroll
            for (int u = 0; u < 4; ++u) {
                float2 b = *(const float2*)(o2w + (size_t)(k + u) * 64 + cH);
                a2[0] = fmaf(a[u], b.x, a2[0]);
                a2[1] = fmaf(a[u], b.y, a2[1]);
            }
        }
        {
            float2 bv = *(const float2*)(o2b + cH);
            red[r][cH]     = a2[0] + bv.x;
            red[r][cH + 1] = a2[1] + bv.y;
        }
        __syncthreads();
        if (tid < 64) {
            float s = 0.f;
            #pragma unroll
            for (int rr = 0; rr < 16; ++rr) s += red[rr][tid];
            atomicAdd(&gs[tid], s);
        }
    }
}

// out[i] = ro_b[i] + sum_k gs[k] * ro_w[k][i]
__global__ void final_kernel(const float* __restrict__ gs,
                             const float* __restrict__ ro_w,
                             const float* __restrict__ ro_b,
                             float* __restrict__ out) {
    int i = threadIdx.x;
    if (i < 12) {
        float s = ro_b[i];
        for (int k = 0; k < 64; ++k) s = fmaf(gs[k], ro_w[k * 12 + i], s);
        out[i] = s;
    }
}

// ---------------------------------------------------------------------------
extern "C" void kernel_launch(void* const* d_in, const int* in_sizes, int n_in,
                              void* d_out, int out_size, void* d_ws, size_t ws_size,
                              hipStream_t stream) {
    const int*   x      = (const int*)d_in[0];
    const int*   ei     = (const int*)d_in[1];
    const float* dist   = (const float*)d_in[2];
    const float* emb    = (const float*)d_in[3];
    const float* mlp_w1 = (const float*)d_in[4];
    const float* mlp_b1 = (const float*)d_in[5];
    const float* mlp_w2 = (const float*)d_in[6];
    const float* mlp_b2 = (const float*)d_in[7];
    const float* lin1_w = (const float*)d_in[8];
    const float* lin2_w = (const float*)d_in[9];
    const float* lin2_b = (const float*)d_in[10];
    const float* lin_w  = (const float*)d_in[11];
    const float* lin_b  = (const float*)d_in[12];
    const float* out1_w = (const float*)d_in[13];
    const float* out1_b = (const float*)d_in[14];
    const float* out2_w = (const float*)d_in[15];
    const float* out2_b = (const float*)d_in[16];
    const float* ro_w   = (const float*)d_in[17];
    const float* ro_b   = (const float*)d_in[18];
    float* out = (float*)d_out;

    // workspace layout (16B-aligned chunks)
    char* base = (char*)d_ws;
    float*    h     = (float*)base;     base += (size_t)N_NUM * 128 * 4;
    ushort_t* tabB  = (ushort_t*)base;  base += (size_t)6 * TAB * 256 * 2;
    ushort_t* xf0   = (ushort_t*)base;  base += (size_t)N_NUM * 128 * 2;
    ushort_t* xf1   = (ushort_t*)base;  base += (size_t)N_NUM * 128 * 2;
    int2*     meta  = (int2*)base;      base += (size_t)E_NUM * 8;
    float*    gs    = (float*)base;     base += 64 * 4;
    int*      offs  = (int*)base;       base += (N_NUM + 1) * 4;
    int*      cursor= (int*)base;       base += N_NUM * 4;
    int*      counts= (int*)base;       base += N_NUM * 4;

    hipMemsetAsync(counts, 0, N_NUM * sizeof(int), stream);
    hipMemsetAsync(gs, 0, 64 * sizeof(float), stream);

    // sort edges by dst (once; dst constant across layers)
    hist_kernel<<<(E_NUM + 255) / 256, 256, 0, stream>>>(ei, counts);
    scan_kernel<<<1, 256, 0, stream>>>(counts, offs, cursor);
    scatter_kernel<<<(E_NUM + 255) / 256, 256, 0, stream>>>(ei, dist, cursor, meta);

    // build all 6 layer filter tables (bf16 interleaved lerp-pair layout)
    table_kernel<<<6 * (TAB / 64), 256, 0, stream>>>(mlp_w1, mlp_b1, mlp_w2,
                                                     mlp_b2, tabB);

    // layer 0 front: h = emb[x], xf0 = bf16(h @ lin1_w[0])
    embed_lin1_kernel<<<NB16, 512, 0, stream>>>(x, emb, lin1_w, h, xf0);

    for (int l = 0; l < 6; ++l) {
        ushort_t* xin  = (l & 1) ? xf1 : xf0;
        ushort_t* xout = (l & 1) ? xf0 : xf1;
        const ushort_t* tl = tabB + (size_t)l * TAB * 256;
        if (l < 5) {
            layer_kernel<false><<<NB16, 512, 0, stream>>>(
                offs, meta, xin, tl,
                lin2_w + l * 16384, lin2_b + l * 128,
                lin_w + l * 16384, lin_b + l * 128,
                lin1_w + (l + 1) * 16384, h, xout,
                nullptr, nullptr, nullptr, nullptr, nullptr);
        } else {
            layer_kernel<true><<<NB16, 512, 0, stream>>>(
                offs, meta, xin, tl,
                lin2_w + l * 16384, lin2_b + l * 128,
                lin_w + l * 16384, lin_b + l * 128,
                nullptr, h, nullptr,
                out1_w, out1_b, out2_w, out2_b, gs);
        }
    }

    final_kernel<<<1, 64, 0, stream>>>(gs, ro_w, ro_b, out);
}

// Round 6
// 661.991 us; speedup vs baseline: 1.3044x; 1.1744x over previous
//
#include <hip/hip_runtime.h>
#include <math.h>

#define E_NUM 320000
#define N_NUM 10000
#define NB8   (N_NUM / 8)           // 1250 blocks, exact
#define TAB   2048

typedef unsigned short ushort_t;

__device__ __forceinline__ float ssp_f(float x) {
    // softplus(x) - log(2), stable: max(x,0) + log(1+exp(-|x|)) - log2
    return fmaxf(x, 0.f) + __logf(1.f + __expf(-fabsf(x))) - 0.69314718056f;
}

__device__ __forceinline__ float bf2f(ushort_t u) {
    union { unsigned int i; float f; } v;
    v.i = ((unsigned int)u) << 16;
    return v.f;
}
__device__ __forceinline__ ushort_t f2bf(float f) {
    union { float f; unsigned int i; } v;
    v.f = f;
    unsigned int u = v.i;
    unsigned int r = (u + 0x7FFFu + ((u >> 16) & 1u)) >> 16;   // RNE
    return (ushort_t)r;
}

// ---------------------------------------------------------------------------
// counting-sort phase 1: histogram of dst
__global__ __launch_bounds__(256) void hist_kernel(const int* __restrict__ ei,
                                                   int* __restrict__ counts) {
    int e = blockIdx.x * 256 + threadIdx.x;
    if (e < E_NUM) atomicAdd(&counts[ei[E_NUM + e]], 1);
}

// phase 2: exclusive scan over 10000 bins (single block, 256 threads x 40)
__global__ __launch_bounds__(256) void scan_kernel(const int* __restrict__ counts,
                                                   int* __restrict__ offs,
                                                   int* __restrict__ cursor) {
    __shared__ int part[256];
    const int tid = threadIdx.x;
    const int CH = 40;                 // 256*40 = 10240 >= 10000
    int base = tid * CH;
    int s = 0;
    for (int i = 0; i < CH; ++i) {
        int idx = base + i;
        if (idx < N_NUM) s += counts[idx];
    }
    part[tid] = s;
    __syncthreads();
    for (int off = 1; off < 256; off <<= 1) {
        int v = (tid >= off) ? part[tid - off] : 0;
        __syncthreads();
        part[tid] += v;
        __syncthreads();
    }
    int run = (tid > 0) ? part[tid - 1] : 0;
    for (int i = 0; i < CH; ++i) {
        int idx = base + i;
        if (idx < N_NUM) {
            offs[idx] = run;
            cursor[idx] = run;
            run += counts[idx];
        }
    }
    if (tid == 255) offs[N_NUM] = part[255];
}

// phase 3: scatter edges to dst-sorted order; pack meta = {src, (i0<<16)|fr16}
__global__ __launch_bounds__(256) void scatter_kernel(const int* __restrict__ ei,
                                                      const float* __restrict__ dist,
                                                      int* __restrict__ cursor,
                                                      int2* __restrict__ meta) {
    int e = blockIdx.x * 256 + threadIdx.x;
    if (e >= E_NUM) return;
    int d = ei[E_NUM + e];
    int pos = atomicAdd(&cursor[d], 1);
    float t = dist[e] * ((float)(TAB - 1) / 10.0f);
    int i0 = (int)t;
    if (i0 > TAB - 2) i0 = TAB - 2;
    float fr = t - (float)i0;
    int fr16 = (int)(fr * 65535.0f + 0.5f);
    meta[pos] = make_int2(ei[e], (i0 << 16) | fr16);
}

// ---------------------------------------------------------------------------
// Build bf16 interleaved filter tables:
//   tabB[l][i] row = 64 pairs x 4 bf16: (W_i[c], W_{i+1}[c], W_i[c+1], W_{i+1}[c+1])
// so the lerp pair for cols (c,c+1) is ONE 8 B load at tabB + i*256 + c*2 (ushorts).
__global__ __launch_bounds__(256) void table_kernel(const float* __restrict__ mlp_w1,
                                                    const float* __restrict__ mlp_b1,
                                                    const float* __restrict__ mlp_w2,
                                                    const float* __restrict__ mlp_b2,
                                                    ushort_t* __restrict__ tabB) {
    __shared__ float eaT[50][68];
    __shared__ float hT[128][68];
    const int tid = threadIdx.x;
    const int l = blockIdx.x / (TAB / 64);
    const int r0 = (blockIdx.x % (TAB / 64)) * 64;
    const float DG = 10.0f / (float)(TAB - 1);
    const float STEP = 10.0f / 49.0f;
    const float COEFF = -0.5f / (STEP * STEP);
    const float* w1 = mlp_w1 + l * 6400;
    const float* b1 = mlp_b1 + l * 128;
    const float* w2 = mlp_w2 + l * 16384;
    const float* b2 = mlp_b2 + l * 128;
    ushort_t* tl = tabB + (size_t)l * TAB * 256;

    for (int i = tid; i < 50 * 64; i += 256) {
        int k = i >> 6, e = i & 63;
        float d = (float)(r0 + e) * DG;
        float t = d - (float)k * STEP;
        eaT[k][e] = __expf(COEFF * t * t);
    }
    __syncthreads();

    const int eg = tid & 15;   // rows eg*4 .. +3
    const int jg = tid >> 4;   // cols jg*8 .. +7

    float acc[4][8];
    #pragma unroll
    for (int i = 0; i < 4; ++i)
        #pragma unroll
        for (int j = 0; j < 8; ++j) acc[i][j] = 0.f;
    {
        const float* Bj = w1 + jg * 8;
        #pragma unroll 2
        for (int k = 0; k < 50; ++k) {
            float4 a = *(const float4*)&eaT[k][eg * 4];
            float b[8];
            *(float4*)&b[0] = *(const float4*)(Bj + k * 128);
            *(float4*)&b[4] = *(const float4*)(Bj + k * 128 + 4);
            float av[4] = {a.x, a.y, a.z, a.w};
            #pragma unroll
            for (int i = 0; i < 4; ++i)
                #pragma unroll
                for (int j = 0; j < 8; ++j) acc[i][j] = fmaf(av[i], b[j], acc[i][j]);
        }
    }
    {
        float b1v[8];
        *(float4*)&b1v[0] = *(const float4*)(b1 + jg * 8);
        *(float4*)&b1v[4] = *(const float4*)(b1 + jg * 8 + 4);
        #pragma unroll
        for (int j = 0; j < 8; ++j) {
            float4 v;
            v.x = ssp_f(acc[0][j] + b1v[j]);
            v.y = ssp_f(acc[1][j] + b1v[j]);
            v.z = ssp_f(acc[2][j] + b1v[j]);
            v.w = ssp_f(acc[3][j] + b1v[j]);
            *(float4*)&hT[jg * 8 + j][eg * 4] = v;
        }
    }
    __syncthreads();

    float acc2[4][8];
    #pragma unroll
    for (int i = 0; i < 4; ++i)
        #pragma unroll
        for (int j = 0; j < 8; ++j) acc2[i][j] = 0.f;
    {
        const float* Bj = w2 + jg * 8;
        #pragma unroll 4
        for (int k = 0; k < 128; ++k) {
            float4 a = *(const float4*)&hT[k][eg * 4];
            float b[8];
            *(float4*)&b[0] = *(const float4*)(Bj + k * 128);
            *(float4*)&b[4] = *(const float4*)(Bj + k * 128 + 4);
            float av[4] = {a.x, a.y, a.z, a.w};
            #pragma unroll
            for (int i = 0; i < 4; ++i)
                #pragma unroll
                for (int j = 0; j < 8; ++j) acc2[i][j] = fmaf(av[i], b[j], acc2[i][j]);
        }
    }

    float bv[8];
    *(float4*)&bv[0] = *(const float4*)(b2 + jg * 8);
    *(float4*)&bv[4] = *(const float4*)(b2 + jg * 8 + 4);
    #pragma unroll
    for (int i = 0; i < 4; ++i) {
        int row = r0 + eg * 4 + i;
        float d = (float)row * DG;
        float C = 0.5f * (__cosf(d * 0.31415926535f) + 1.0f);
        #pragma unroll
        for (int j = 0; j < 8; ++j) {
            int col = jg * 8 + j;
            ushort_t b = f2bf((acc2[i][j] + bv[j]) * C);
            int base = (col >> 1) * 4 + (col & 1) * 2;
            tl[(size_t)row * 256 + base] = b;                       // slot W_row
            if (row > 0)
                tl[(size_t)(row - 1) * 256 + base + 1] = b;         // slot W_{row+1} of prev
        }
    }
}

// ---------------------------------------------------------------------------
// aggregation helpers: 4 edges (quad) / 1 edge into 2-column accumulators
__device__ __forceinline__ void agg_quad(const int2* __restrict__ meta, int e,
                                         const ushort_t* __restrict__ xf,
                                         const ushort_t* __restrict__ tabB,
                                         int c2,
                                         float& p0, float& p1,
                                         float& q0, float& q1) {
    int2 m0 = meta[e], m1 = meta[e + 1], m2 = meta[e + 2], m3 = meta[e + 3];
    ushort2 x0 = *(const ushort2*)(xf + (size_t)m0.x * 128 + c2);
    ushort2 x1 = *(const ushort2*)(xf + (size_t)m1.x * 128 + c2);
    ushort2 x2 = *(const ushort2*)(xf + (size_t)m2.x * 128 + c2);
    ushort2 x3 = *(const ushort2*)(xf + (size_t)m3.x * 128 + c2);
    ushort4 t0 = *(const ushort4*)(tabB + (size_t)(((unsigned)m0.y) >> 16) * 256 + c2 * 2);
    ushort4 t1 = *(const ushort4*)(tabB + (size_t)(((unsigned)m1.y) >> 16) * 256 + c2 * 2);
    ushort4 t2 = *(const ushort4*)(tabB + (size_t)(((unsigned)m2.y) >> 16) * 256 + c2 * 2);
    ushort4 t3 = *(const ushort4*)(tabB + (size_t)(((unsigned)m3.y) >> 16) * 256 + c2 * 2);

    float f0 = (float)(m0.y & 0xffff) * (1.0f / 65535.0f);
    float f1 = (float)(m1.y & 0xffff) * (1.0f / 65535.0f);
    float f2 = (float)(m2.y & 0xffff) * (1.0f / 65535.0f);
    float f3 = (float)(m3.y & 0xffff) * (1.0f / 65535.0f);

    float w;
    w = fmaf(f0, bf2f(t0.y) - bf2f(t0.x), bf2f(t0.x)); p0 = fmaf(bf2f(x0.x), w, p0);
    w = fmaf(f0, bf2f(t0.w) - bf2f(t0.z), bf2f(t0.z)); p1 = fmaf(bf2f(x0.y), w, p1);
    w = fmaf(f1, bf2f(t1.y) - bf2f(t1.x), bf2f(t1.x)); q0 = fmaf(bf2f(x1.x), w, q0);
    w = fmaf(f1, bf2f(t1.w) - bf2f(t1.z), bf2f(t1.z)); q1 = fmaf(bf2f(x1.y), w, q1);
    w = fmaf(f2, bf2f(t2.y) - bf2f(t2.x), bf2f(t2.x)); p0 = fmaf(bf2f(x2.x), w, p0);
    w = fmaf(f2, bf2f(t2.w) - bf2f(t2.z), bf2f(t2.z)); p1 = fmaf(bf2f(x2.y), w, p1);
    w = fmaf(f3, bf2f(t3.y) - bf2f(t3.x), bf2f(t3.x)); q0 = fmaf(bf2f(x3.x), w, q0);
    w = fmaf(f3, bf2f(t3.w) - bf2f(t3.z), bf2f(t3.z)); q1 = fmaf(bf2f(x3.y), w, q1);
}

__device__ __forceinline__ void agg_one(const int2* __restrict__ meta, int e,
                                        const ushort_t* __restrict__ xf,
                                        const ushort_t* __restrict__ tabB,
                                        int c2, float& p0, float& p1) {
    int2 m = meta[e];
    ushort2 xv = *(const ushort2*)(xf + (size_t)m.x * 128 + c2);
    ushort4 tv = *(const ushort4*)(tabB + (size_t)(((unsigned)m.y) >> 16) * 256 + c2 * 2);
    float f = (float)(m.y & 0xffff) * (1.0f / 65535.0f);
    float w0 = fmaf(f, bf2f(tv.y) - bf2f(tv.x), bf2f(tv.x));
    float w1 = fmaf(f, bf2f(tv.w) - bf2f(tv.z), bf2f(tv.z));
    p0 = fmaf(bf2f(xv.x), w0, p0);
    p1 = fmaf(bf2f(xv.y), w1, p1);
}

// ---------------------------------------------------------------------------
// Layer 0 front: h = emb[x]; xf = bf16(h @ lin1_w[0]).  8 rows/block, 256 thr.
__global__ __launch_bounds__(256) void embed_lin1_kernel(const int* __restrict__ x,
                                                         const float* __restrict__ emb,
                                                         const float* __restrict__ B,
                                                         float* __restrict__ h,
                                                         ushort_t* __restrict__ xf) {
    __shared__ float AT[128][9];
    __shared__ int s_x[8];
    const int tid = threadIdx.x;
    const int n0 = blockIdx.x * 8;

    if (tid < 8) s_x[tid] = x[n0 + tid];
    __syncthreads();
    for (int i = tid; i < 8 * 128; i += 256) {
        int r = i >> 7, c = i & 127;
        float v = emb[s_x[r] * 128 + c];
        AT[c][r] = v;
        h[(size_t)(n0 + r) * 128 + c] = v;
    }
    __syncthreads();

    const int r  = tid & 7;
    const int c0 = (tid >> 3) * 4;
    float acc[4] = {0.f, 0.f, 0.f, 0.f};
    for (int k = 0; k < 128; k += 4) {
        float a[4];
        #pragma unroll
        for (int u = 0; u < 4; ++u) a[u] = AT[k + u][r];
        #pragma unroll
        for (int u = 0; u < 4; ++u) {
            float4 b = *(const float4*)(B + (size_t)(k + u) * 128 + c0);
            acc[0] = fmaf(a[u], b.x, acc[0]);
            acc[1] = fmaf(a[u], b.y, acc[1]);
            acc[2] = fmaf(a[u], b.z, acc[2]);
            acc[3] = fmaf(a[u], b.w, acc[3]);
        }
    }
    ushort4 o;
    o.x = f2bf(acc[0]); o.y = f2bf(acc[1]); o.z = f2bf(acc[2]); o.w = f2bf(acc[3]);
    *(ushort4*)(xf + (size_t)(n0 + r) * 128 + c0) = o;
}

// ---------------------------------------------------------------------------
// Fused layer kernel: 8 nodes/block, 256 threads (4 waves).
//   phase A: each wave aggregates TWO nodes (dual independent edge streams,
//            scalar meta via readfirstlane, 4-edge quads) -> LDS, fp32 acc
//   stage 1: conv  = agg @ lin2_w + lin2_b ; t = ssp(conv)
//   stage 2: h_new = h + t @ lin_w + lin_b
//   stage 3: xf_out = bf16(h_new @ lin1_next)          (if !LAST)
//   head   : gs += colsum(ssp(h_new@o1w+o1b)@o2w+o2b)  (if LAST)
template <bool LAST>
__global__ __launch_bounds__(256) void layer_kernel(const int* __restrict__ offs,
                                                    const int2* __restrict__ meta,
                                                    const ushort_t* __restrict__ xf,
                                                    const ushort_t* __restrict__ tabB,
                                                    const float* __restrict__ lin2_w,
                                                    const float* __restrict__ lin2_b,
                                                    const float* __restrict__ lin_w,
                                                    const float* __restrict__ lin_b,
                                                    const float* __restrict__ lin1_next,
                                                    float* __restrict__ h,
                                                    ushort_t* __restrict__ xf_out,
                                                    const float* __restrict__ o1w,
                                                    const float* __restrict__ o1b,
                                                    const float* __restrict__ o2w,
                                                    const float* __restrict__ o2b,
                                                    float* __restrict__ gs) {
    __shared__ float AT[128][9];
    const int tid = threadIdx.x;
    const int n0 = blockIdx.x * 8;

    // ---- phase A: wave wv aggregates nodes n0+wv and n0+wv+4 ----
    {
        const int wv = tid >> 6;       // 0..3
        const int lane = tid & 63;
        const int c2 = lane * 2;
        const int nA = n0 + wv;
        const int nB = n0 + wv + 4;
        int eA   = __builtin_amdgcn_readfirstlane(offs[nA]);
        int endA = __builtin_amdgcn_readfirstlane(offs[nA + 1]);
        int eB   = __builtin_amdgcn_readfirstlane(offs[nB]);
        int endB = __builtin_amdgcn_readfirstlane(offs[nB + 1]);

        float aA0 = 0.f, aA1 = 0.f, aA0b = 0.f, aA1b = 0.f;
        float aB0 = 0.f, aB1 = 0.f, aB0b = 0.f, aB1b = 0.f;

        // dual-stream main loop: 4+4 edges per iteration, two independent chains
        while (eA + 4 <= endA && eB + 4 <= endB) {
            agg_quad(meta, eA, xf, tabB, c2, aA0, aA1, aA0b, aA1b);
            agg_quad(meta, eB, xf, tabB, c2, aB0, aB1, aB0b, aB1b);
            eA += 4; eB += 4;
        }
        for (; eA + 4 <= endA; eA += 4)
            agg_quad(meta, eA, xf, tabB, c2, aA0, aA1, aA0b, aA1b);
        for (; eB + 4 <= endB; eB += 4)
            agg_quad(meta, eB, xf, tabB, c2, aB0, aB1, aB0b, aB1b);
        for (; eA < endA; ++eA)
            agg_one(meta, eA, xf, tabB, c2, aA0, aA1);
        for (; eB < endB; ++eB)
            agg_one(meta, eB, xf, tabB, c2, aB0, aB1);

        AT[c2][wv]         = aA0 + aA0b;
        AT[c2 + 1][wv]     = aA1 + aA1b;
        AT[c2][wv + 4]     = aB0 + aB0b;
        AT[c2 + 1][wv + 4] = aB1 + aB1b;
    }
    __syncthreads();

    const int r  = tid & 7;
    const int c0 = (tid >> 3) * 4;

    // ---- stage 1: conv = agg @ lin2_w ; t = ssp(conv + lin2_b) ----
    float acc[4] = {0.f, 0.f, 0.f, 0.f};
    for (int k = 0; k < 128; k += 4) {
        float a[4];
        #pragma unroll
        for (int u = 0; u < 4; ++u) a[u] = AT[k + u][r];
        #pragma unroll
        for (int u = 0; u < 4; ++u) {
            float4 b = *(const float4*)(lin2_w + (size_t)(k + u) * 128 + c0);
            acc[0] = fmaf(a[u], b.x, acc[0]);
            acc[1] = fmaf(a[u], b.y, acc[1]);
            acc[2] = fmaf(a[u], b.z, acc[2]);
            acc[3] = fmaf(a[u], b.w, acc[3]);
        }
    }
    float tval[4];
    {
        float4 bv = *(const float4*)(lin2_b + c0);
        tval[0] = ssp_f(acc[0] + bv.x);
        tval[1] = ssp_f(acc[1] + bv.y);
        tval[2] = ssp_f(acc[2] + bv.z);
        tval[3] = ssp_f(acc[3] + bv.w);
    }
    __syncthreads();   // all stage-1 reads of AT done
    #pragma unroll
    for (int j = 0; j < 4; ++j) AT[c0 + j][r] = tval[j];
    __syncthreads();

    // ---- stage 2: h_new = h + t @ lin_w + lin_b ----
    float acc2[4] = {0.f, 0.f, 0.f, 0.f};
    for (int k = 0; k < 128; k += 4) {
        float a[4];
        #pragma unroll
        for (int u = 0; u < 4; ++u) a[u] = AT[k + u][r];
        #pragma unroll
        for (int u = 0; u < 4; ++u) {
            float4 b = *(const float4*)(lin_w + (size_t)(k + u) * 128 + c0);
            acc2[0] = fmaf(a[u], b.x, acc2[0]);
            acc2[1] = fmaf(a[u], b.y, acc2[1]);
            acc2[2] = fmaf(a[u], b.z, acc2[2]);
            acc2[3] = fmaf(a[u], b.w, acc2[3]);
        }
    }
    float hn[4];
    {
        float4 bv = *(const float4*)(lin_b + c0);
        float* hr = h + (size_t)(n0 + r) * 128 + c0;
        float4 hv = *(const float4*)hr;
        hn[0] = hv.x + acc2[0] + bv.x;
        hn[1] = hv.y + acc2[1] + bv.y;
        hn[2] = hv.z + acc2[2] + bv.z;
        hn[3] = hv.w + acc2[3] + bv.w;
        if (!LAST) *(float4*)hr = *(float4*)hn;   // next layer needs h
    }
    __syncthreads();   // all stage-2 reads of AT done
    #pragma unroll
    for (int j = 0; j < 4; ++j) AT[c0 + j][r] = hn[j];
    __syncthreads();

    if constexpr (!LAST) {
        // ---- stage 3: xf_out = bf16(h_new @ lin1_next) ----
        float acc3[4] = {0.f, 0.f, 0.f, 0.f};
        for (int k = 0; k < 128; k += 4) {
            float a[4];
            #pragma unroll
            for (int u = 0; u < 4; ++u) a[u] = AT[k + u][r];
            #pragma unroll
            for (int u = 0; u < 4; ++u) {
                float4 b = *(const float4*)(lin1_next + (size_t)(k + u) * 128 + c0);
                acc3[0] = fmaf(a[u], b.x, acc3[0]);
                acc3[1] = fmaf(a[u], b.y, acc3[1]);
                acc3[2] = fmaf(a[u], b.z, acc3[2]);
                acc3[3] = fmaf(a[u], b.w, acc3[3]);
            }
        }
        ushort4 o;
        o.x = f2bf(acc3[0]); o.y = f2bf(acc3[1]);
        o.z = f2bf(acc3[2]); o.w = f2bf(acc3[3]);
        *(ushort4*)(xf_out + (size_t)(n0 + r) * 128 + c0) = o;
    } else {
        // ---- fused head: t1 = ssp(h_new@o1w+o1b); t2 = t1@o2w+o2b; colsum ----
        __shared__ float BT[64][9];
        __shared__ float red[8][64];
        const int cH = (tid >> 3) * 2;   // 32 groups x 2 cols = 64

        float a1[2] = {0.f, 0.f};
        for (int k = 0; k < 128; k += 4) {
            float a[4];
            #pragma unroll
            for (int u = 0; u < 4; ++u) a[u] = AT[k + u][r];
            #pragma unroll
            for (int u = 0; u < 4; ++u) {
                float2 b = *(const float2*)(o1w + (size_t)(k + u) * 64 + cH);
                a1[0] = fmaf(a[u], b.x, a1[0]);
                a1[1] = fmaf(a[u], b.y, a1[1]);
            }
        }
        float t1[2];
        {
            float2 bv = *(const float2*)(o1b + cH);
            t1[0] = ssp_f(a1[0] + bv.x);
            t1[1] = ssp_f(a1[1] + bv.y);
        }
        __syncthreads();
        BT[cH][r]     = t1[0];
        BT[cH + 1][r] = t1[1];
        __syncthreads();

        float a2[2] = {0.f, 0.f};
        for (int k = 0; k < 64; k += 4) {
            float a[4];
            #pragma unroll
            for (int u = 0; u < 4; ++u) a[u] = BT[k + u][r];
            #pragma unroll
            for (int u = 0; u < 4; ++u) {
                float2 b = *(const float2*)(o2w + (size_t)(k + u) * 64 + cH);
                a2[0] = fmaf(a[u], b.x, a2[0]);
                a2[1] = fmaf(a[u], b.y, a2[1]);
            }
        }
        {
            float2 bv = *(const float2*)(o2b + cH);
            red[r][cH]     = a2[0] + bv.x;
            red[r][cH + 1] = a2[1] + bv.y;
        }
        __syncthreads();
        if (tid < 64) {
            float s = 0.f;
            #pragma unroll
            for (int rr = 0; rr < 8; ++rr) s += red[rr][tid];
            atomicAdd(&gs[tid], s);
        }
    }
}

// out[i] = ro_b[i] + sum_k gs[k] * ro_w[k][i]
__global__ void final_kernel(const float* __restrict__ gs,
                             const float* __restrict__ ro_w,
                             const float* __restrict__ ro_b,
                             float* __restrict__ out) {
    int i = threadIdx.x;
    if (i < 12) {
        float s = ro_b[i];
        for (int k = 0; k < 64; ++k) s = fmaf(gs[k], ro_w[k * 12 + i], s);
        out[i] = s;
    }
}

// ---------------------------------------------------------------------------
extern "C" void kernel_launch(void* const* d_in, const int* in_sizes, int n_in,
                              void* d_out, int out_size, void* d_ws, size_t ws_size,
                              hipStream_t stream) {
    const int*   x      = (const int*)d_in[0];
    const int*   ei     = (const int*)d_in[1];
    const float* dist   = (const float*)d_in[2];
    const float* emb    = (const float*)d_in[3];
    const float* mlp_w1 = (const float*)d_in[4];
    const float* mlp_b1 = (const float*)d_in[5];
    const float* mlp_w2 = (const float*)d_in[6];
    const float* mlp_b2 = (const float*)d_in[7];
    const float* lin1_w = (const float*)d_in[8];
    const float* lin2_w = (const float*)d_in[9];
    const float* lin2_b = (const float*)d_in[10];
    const float* lin_w  = (const float*)d_in[11];
    const float* lin_b  = (const float*)d_in[12];
    const float* out1_w = (const float*)d_in[13];
    const float* out1_b = (const float*)d_in[14];
    const float* out2_w = (const float*)d_in[15];
    const float* out2_b = (const float*)d_in[16];
    const float* ro_w   = (const float*)d_in[17];
    const float* ro_b   = (const float*)d_in[18];
    float* out = (float*)d_out;

    // workspace layout (16B-aligned chunks)
    char* base = (char*)d_ws;
    float*    h     = (float*)base;     base += (size_t)N_NUM * 128 * 4;
    ushort_t* tabB  = (ushort_t*)base;  base += (size_t)6 * TAB * 256 * 2;
    ushort_t* xf0   = (ushort_t*)base;  base += (size_t)N_NUM * 128 * 2;
    ushort_t* xf1   = (ushort_t*)base;  base += (size_t)N_NUM * 128 * 2;
    int2*     meta  = (int2*)base;      base += (size_t)E_NUM * 8;
    float*    gs    = (float*)base;     base += 64 * 4;
    int*      offs  = (int*)base;       base += (N_NUM + 1) * 4;
    int*      cursor= (int*)base;       base += N_NUM * 4;
    int*      counts= (int*)base;       base += N_NUM * 4;

    hipMemsetAsync(counts, 0, N_NUM * sizeof(int), stream);
    hipMemsetAsync(gs, 0, 64 * sizeof(float), stream);

    // sort edges by dst (once; dst constant across layers)
    hist_kernel<<<(E_NUM + 255) / 256, 256, 0, stream>>>(ei, counts);
    scan_kernel<<<1, 256, 0, stream>>>(counts, offs, cursor);
    scatter_kernel<<<(E_NUM + 255) / 256, 256, 0, stream>>>(ei, dist, cursor, meta);

    // build all 6 layer filter tables (bf16 interleaved lerp-pair layout)
    table_kernel<<<6 * (TAB / 64), 256, 0, stream>>>(mlp_w1, mlp_b1, mlp_w2,
                                                     mlp_b2, tabB);

    // layer 0 front: h = emb[x], xf0 = bf16(h @ lin1_w[0])
    embed_lin1_kernel<<<NB8, 256, 0, stream>>>(x, emb, lin1_w, h, xf0);

    for (int l = 0; l < 6; ++l) {
        ushort_t* xin  = (l & 1) ? xf1 : xf0;
        ushort_t* xout = (l & 1) ? xf0 : xf1;
        const ushort_t* tl = tabB + (size_t)l * TAB * 256;
        if (l < 5) {
            layer_kernel<false><<<NB8, 256, 0, stream>>>(
                offs, meta, xin, tl,
                lin2_w + l * 16384, lin2_b + l * 128,
                lin_w + l * 16384, lin_b + l * 128,
                lin1_w + (l + 1) * 16384, h, xout,
                nullptr, nullptr, nullptr, nullptr, nullptr);
        } else {
            layer_kernel<true><<<NB8, 256, 0, stream>>>(
                offs, meta, xin, tl,
                lin2_w + l * 16384, lin2_b + l * 128,
                lin_w + l * 16384, lin_b + l * 128,
                nullptr, h, nullptr,
                out1_w, out1_b, out2_w, out2_b, gs);
        }
    }

    final_kernel<<<1, 64, 0, stream>>>(gs, ro_w, ro_b, out);
}

// Round 7
// 398.015 us; speedup vs baseline: 2.1696x; 1.6632x over previous
//
#include <hip/hip_runtime.h>
#include <math.h>

#define E_NUM 320000
#define N_NUM 10000
#define NB8   (N_NUM / 8)           // 1250 blocks (embed)
#define NB16  (N_NUM / 16)          // 625 blocks (layer)
#define TAB   2048

typedef unsigned short ushort_t;
typedef short short8_t __attribute__((ext_vector_type(8)));   // 8 bf16 (4 VGPRs)
typedef float f32x4    __attribute__((ext_vector_type(4)));   // MFMA acc

__device__ __forceinline__ float ssp_f(float x) {
    return fmaxf(x, 0.f) + __logf(1.f + __expf(-fabsf(x))) - 0.69314718056f;
}

__device__ __forceinline__ float bf2f(ushort_t u) {
    union { unsigned int i; float f; } v;
    v.i = ((unsigned int)u) << 16;
    return v.f;
}
__device__ __forceinline__ ushort_t f2bf(float f) {
    union { float f; unsigned int i; } v;
    v.f = f;
    unsigned int u = v.i;
    unsigned int r = (u + 0x7FFFu + ((u >> 16) & 1u)) >> 16;   // RNE
    return (ushort_t)r;
}

// ---------------------------------------------------------------------------
// counting-sort phase 1: histogram of dst
__global__ __launch_bounds__(256) void hist_kernel(const int* __restrict__ ei,
                                                   int* __restrict__ counts) {
    int e = blockIdx.x * 256 + threadIdx.x;
    if (e < E_NUM) atomicAdd(&counts[ei[E_NUM + e]], 1);
}

// phase 2: exclusive scan over 10000 bins (single block)
__global__ __launch_bounds__(256) void scan_kernel(const int* __restrict__ counts,
                                                   int* __restrict__ offs,
                                                   int* __restrict__ cursor) {
    __shared__ int part[256];
    const int tid = threadIdx.x;
    const int CH = 40;
    int base = tid * CH;
    int s = 0;
    for (int i = 0; i < CH; ++i) {
        int idx = base + i;
        if (idx < N_NUM) s += counts[idx];
    }
    part[tid] = s;
    __syncthreads();
    for (int off = 1; off < 256; off <<= 1) {
        int v = (tid >= off) ? part[tid - off] : 0;
        __syncthreads();
        part[tid] += v;
        __syncthreads();
    }
    int run = (tid > 0) ? part[tid - 1] : 0;
    for (int i = 0; i < CH; ++i) {
        int idx = base + i;
        if (idx < N_NUM) {
            offs[idx] = run;
            cursor[idx] = run;
            run += counts[idx];
        }
    }
    if (tid == 255) offs[N_NUM] = part[255];
}

// phase 3: scatter edges to dst-sorted order; pack meta = {src, (i0<<16)|fr16}
__global__ __launch_bounds__(256) void scatter_kernel(const int* __restrict__ ei,
                                                      const float* __restrict__ dist,
                                                      int* __restrict__ cursor,
                                                      int2* __restrict__ meta) {
    int e = blockIdx.x * 256 + threadIdx.x;
    if (e >= E_NUM) return;
    int d = ei[E_NUM + e];
    int pos = atomicAdd(&cursor[d], 1);
    float t = dist[e] * ((float)(TAB - 1) / 10.0f);
    int i0 = (int)t;
    if (i0 > TAB - 2) i0 = TAB - 2;
    float fr = t - (float)i0;
    int fr16 = (int)(fr * 65535.0f + 0.5f);
    meta[pos] = make_int2(ei[e], (i0 << 16) | fr16);
}

// ---------------------------------------------------------------------------
// Pack weights into MFMA B-fragment order (bf16):
//   out[((t*KSP + ks)*64 + L)*8 + j] = bf16( W[k][n] ),
//   n = t*16 + (L&15), k = ks*32 + (L>>4)*8 + j
// Regions: 6x lin2 (128x128) | 6x lin_w | 6x lin1_w | o1w (128x64) | o2w (64x64)
__global__ __launch_bounds__(256) void pack_kernel(const float* __restrict__ lin2_w,
                                                   const float* __restrict__ lin_w,
                                                   const float* __restrict__ lin1_w,
                                                   const float* __restrict__ o1w,
                                                   const float* __restrict__ o2w,
                                                   short* __restrict__ wpack) {
    int idx = blockIdx.x * 256 + threadIdx.x;
    const int M128 = 16384;
    if (idx < 18 * M128) {
        int g = idx / M128, r = idx % M128;
        const float* src;
        if (g < 6) src = lin2_w + g * M128;
        else if (g < 12) src = lin_w + (g - 6) * M128;
        else src = lin1_w + (g - 12) * M128;
        int j = r & 7, L = (r >> 3) & 63, ks = (r >> 9) & 3, t = r >> 11;
        int n = t * 16 + (L & 15);
        int k = ks * 32 + (L >> 4) * 8 + j;
        wpack[idx] = (short)f2bf(src[k * 128 + n]);
    } else if (idx < 18 * M128 + 8192) {
        int r = idx - 18 * M128;          // o1w: K=128, N=64
        int j = r & 7, L = (r >> 3) & 63, ks = (r >> 9) & 3, t = r >> 11;
        int n = t * 16 + (L & 15);
        int k = ks * 32 + (L >> 4) * 8 + j;
        wpack[idx] = (short)f2bf(o1w[k * 64 + n]);
    } else if (idx < 18 * M128 + 8192 + 4096) {
        int r = idx - 18 * M128 - 8192;   // o2w: K=64, N=64
        int j = r & 7, L = (r >> 3) & 63, ks = (r >> 9) & 1, t = r >> 10;
        int n = t * 16 + (L & 15);
        int k = ks * 32 + (L >> 4) * 8 + j;
        wpack[idx] = (short)f2bf(o2w[k * 64 + n]);
    }
}

// ---------------------------------------------------------------------------
// Build bf16 interleaved filter tables (unchanged from R6)
__global__ __launch_bounds__(256) void table_kernel(const float* __restrict__ mlp_w1,
                                                    const float* __restrict__ mlp_b1,
                                                    const float* __restrict__ mlp_w2,
                                                    const float* __restrict__ mlp_b2,
                                                    ushort_t* __restrict__ tabB) {
    __shared__ float eaT[50][68];
    __shared__ float hT[128][68];
    const int tid = threadIdx.x;
    const int l = blockIdx.x / (TAB / 64);
    const int r0 = (blockIdx.x % (TAB / 64)) * 64;
    const float DG = 10.0f / (float)(TAB - 1);
    const float STEP = 10.0f / 49.0f;
    const float COEFF = -0.5f / (STEP * STEP);
    const float* w1 = mlp_w1 + l * 6400;
    const float* b1 = mlp_b1 + l * 128;
    const float* w2 = mlp_w2 + l * 16384;
    const float* b2 = mlp_b2 + l * 128;
    ushort_t* tl = tabB + (size_t)l * TAB * 256;

    for (int i = tid; i < 50 * 64; i += 256) {
        int k = i >> 6, e = i & 63;
        float d = (float)(r0 + e) * DG;
        float t = d - (float)k * STEP;
        eaT[k][e] = __expf(COEFF * t * t);
    }
    __syncthreads();

    const int eg = tid & 15;
    const int jg = tid >> 4;

    float acc[4][8];
    #pragma unroll
    for (int i = 0; i < 4; ++i)
        #pragma unroll
        for (int j = 0; j < 8; ++j) acc[i][j] = 0.f;
    {
        const float* Bj = w1 + jg * 8;
        #pragma unroll 2
        for (int k = 0; k < 50; ++k) {
            float4 a = *(const float4*)&eaT[k][eg * 4];
            float b[8];
            *(float4*)&b[0] = *(const float4*)(Bj + k * 128);
            *(float4*)&b[4] = *(const float4*)(Bj + k * 128 + 4);
            float av[4] = {a.x, a.y, a.z, a.w};
            #pragma unroll
            for (int i = 0; i < 4; ++i)
                #pragma unroll
                for (int j = 0; j < 8; ++j) acc[i][j] = fmaf(av[i], b[j], acc[i][j]);
        }
    }
    {
        float b1v[8];
        *(float4*)&b1v[0] = *(const float4*)(b1 + jg * 8);
        *(float4*)&b1v[4] = *(const float4*)(b1 + jg * 8 + 4);
        #pragma unroll
        for (int j = 0; j < 8; ++j) {
            float4 v;
            v.x = ssp_f(acc[0][j] + b1v[j]);
            v.y = ssp_f(acc[1][j] + b1v[j]);
            v.z = ssp_f(acc[2][j] + b1v[j]);
            v.w = ssp_f(acc[3][j] + b1v[j]);
            *(float4*)&hT[jg * 8 + j][eg * 4] = v;
        }
    }
    __syncthreads();

    float acc2[4][8];
    #pragma unroll
    for (int i = 0; i < 4; ++i)
        #pragma unroll
        for (int j = 0; j < 8; ++j) acc2[i][j] = 0.f;
    {
        const float* Bj = w2 + jg * 8;
        #pragma unroll 4
        for (int k = 0; k < 128; ++k) {
            float4 a = *(const float4*)&hT[k][eg * 4];
            float b[8];
            *(float4*)&b[0] = *(const float4*)(Bj + k * 128);
            *(float4*)&b[4] = *(const float4*)(Bj + k * 128 + 4);
            float av[4] = {a.x, a.y, a.z, a.w};
            #pragma unroll
            for (int i = 0; i < 4; ++i)
                #pragma unroll
                for (int j = 0; j < 8; ++j) acc2[i][j] = fmaf(av[i], b[j], acc2[i][j]);
        }
    }

    float bv[8];
    *(float4*)&bv[0] = *(const float4*)(b2 + jg * 8);
    *(float4*)&bv[4] = *(const float4*)(b2 + jg * 8 + 4);
    #pragma unroll
    for (int i = 0; i < 4; ++i) {
        int row = r0 + eg * 4 + i;
        float d = (float)row * DG;
        float C = 0.5f * (__cosf(d * 0.31415926535f) + 1.0f);
        #pragma unroll
        for (int j = 0; j < 8; ++j) {
            int col = jg * 8 + j;
            ushort_t b = f2bf((acc2[i][j] + bv[j]) * C);
            int base = (col >> 1) * 4 + (col & 1) * 2;
            tl[(size_t)row * 256 + base] = b;
            if (row > 0)
                tl[(size_t)(row - 1) * 256 + base + 1] = b;
        }
    }
}

// ---------------------------------------------------------------------------
// aggregation helpers (unchanged from R6)
__device__ __forceinline__ void agg_quad(const int2* __restrict__ meta, int e,
                                         const ushort_t* __restrict__ xf,
                                         const ushort_t* __restrict__ tabB,
                                         int c2,
                                         float& p0, float& p1,
                                         float& q0, float& q1) {
    int2 m0 = meta[e], m1 = meta[e + 1], m2 = meta[e + 2], m3 = meta[e + 3];
    ushort2 x0 = *(const ushort2*)(xf + (size_t)m0.x * 128 + c2);
    ushort2 x1 = *(const ushort2*)(xf + (size_t)m1.x * 128 + c2);
    ushort2 x2 = *(const ushort2*)(xf + (size_t)m2.x * 128 + c2);
    ushort2 x3 = *(const ushort2*)(xf + (size_t)m3.x * 128 + c2);
    ushort4 t0 = *(const ushort4*)(tabB + (size_t)(((unsigned)m0.y) >> 16) * 256 + c2 * 2);
    ushort4 t1 = *(const ushort4*)(tabB + (size_t)(((unsigned)m1.y) >> 16) * 256 + c2 * 2);
    ushort4 t2 = *(const ushort4*)(tabB + (size_t)(((unsigned)m2.y) >> 16) * 256 + c2 * 2);
    ushort4 t3 = *(const ushort4*)(tabB + (size_t)(((unsigned)m3.y) >> 16) * 256 + c2 * 2);

    float f0 = (float)(m0.y & 0xffff) * (1.0f / 65535.0f);
    float f1 = (float)(m1.y & 0xffff) * (1.0f / 65535.0f);
    float f2 = (float)(m2.y & 0xffff) * (1.0f / 65535.0f);
    float f3 = (float)(m3.y & 0xffff) * (1.0f / 65535.0f);

    float w;
    w = fmaf(f0, bf2f(t0.y) - bf2f(t0.x), bf2f(t0.x)); p0 = fmaf(bf2f(x0.x), w, p0);
    w = fmaf(f0, bf2f(t0.w) - bf2f(t0.z), bf2f(t0.z)); p1 = fmaf(bf2f(x0.y), w, p1);
    w = fmaf(f1, bf2f(t1.y) - bf2f(t1.x), bf2f(t1.x)); q0 = fmaf(bf2f(x1.x), w, q0);
    w = fmaf(f1, bf2f(t1.w) - bf2f(t1.z), bf2f(t1.z)); q1 = fmaf(bf2f(x1.y), w, q1);
    w = fmaf(f2, bf2f(t2.y) - bf2f(t2.x), bf2f(t2.x)); p0 = fmaf(bf2f(x2.x), w, p0);
    w = fmaf(f2, bf2f(t2.w) - bf2f(t2.z), bf2f(t2.z)); p1 = fmaf(bf2f(x2.y), w, p1);
    w = fmaf(f3, bf2f(t3.y) - bf2f(t3.x), bf2f(t3.x)); q0 = fmaf(bf2f(x3.x), w, q0);
    w = fmaf(f3, bf2f(t3.w) - bf2f(t3.z), bf2f(t3.z)); q1 = fmaf(bf2f(x3.y), w, q1);
}

__device__ __forceinline__ void agg_one(const int2* __restrict__ meta, int e,
                                        const ushort_t* __restrict__ xf,
                                        const ushort_t* __restrict__ tabB,
                                        int c2, float& p0, float& p1) {
    int2 m = meta[e];
    ushort2 xv = *(const ushort2*)(xf + (size_t)m.x * 128 + c2);
    ushort4 tv = *(const ushort4*)(tabB + (size_t)(((unsigned)m.y) >> 16) * 256 + c2 * 2);
    float f = (float)(m.y & 0xffff) * (1.0f / 65535.0f);
    float w0 = fmaf(f, bf2f(tv.y) - bf2f(tv.x), bf2f(tv.x));
    float w1 = fmaf(f, bf2f(tv.w) - bf2f(tv.z), bf2f(tv.z));
    p0 = fmaf(bf2f(xv.x), w0, p0);
    p1 = fmaf(bf2f(xv.y), w1, p1);
}

// ---------------------------------------------------------------------------
// Layer 0 front: h = emb[x]; xf = bf16(h @ lin1_w[0]).  8 rows/block, 256 thr.
__global__ __launch_bounds__(256) void embed_lin1_kernel(const int* __restrict__ x,
                                                         const float* __restrict__ emb,
                                                         const float* __restrict__ B,
                                                         float* __restrict__ h,
                                                         ushort_t* __restrict__ xf) {
    __shared__ float AT[128][9];
    __shared__ int s_x[8];
    const int tid = threadIdx.x;
    const int n0 = blockIdx.x * 8;

    if (tid < 8) s_x[tid] = x[n0 + tid];
    __syncthreads();
    for (int i = tid; i < 8 * 128; i += 256) {
        int r = i >> 7, c = i & 127;
        float v = emb[s_x[r] * 128 + c];
        AT[c][r] = v;
        h[(size_t)(n0 + r) * 128 + c] = v;
    }
    __syncthreads();

    const int r  = tid & 7;
    const int c0 = (tid >> 3) * 4;
    float acc[4] = {0.f, 0.f, 0.f, 0.f};
    for (int k = 0; k < 128; k += 4) {
        float a[4];
        #pragma unroll
        for (int u = 0; u < 4; ++u) a[u] = AT[k + u][r];
        #pragma unroll
        for (int u = 0; u < 4; ++u) {
            float4 b = *(const float4*)(B + (size_t)(k + u) * 128 + c0);
            acc[0] = fmaf(a[u], b.x, acc[0]);
            acc[1] = fmaf(a[u], b.y, acc[1]);
            acc[2] = fmaf(a[u], b.z, acc[2]);
            acc[3] = fmaf(a[u], b.w, acc[3]);
        }
    }
    ushort4 o;
    o.x = f2bf(acc[0]); o.y = f2bf(acc[1]); o.z = f2bf(acc[2]); o.w = f2bf(acc[3]);
    *(ushort4*)(xf + (size_t)(n0 + r) * 128 + c0) = o;
}

// ---------------------------------------------------------------------------
// MFMA stage: D(16 x 32cols per wave) += A_lds(16x128 bf16) @ Wpacked(128x128 bf16)
// A-frag: lane holds A[m=lane&15][k=ks*32+(lane>>4)*8+j]; row stride 136 shorts.
__device__ __forceinline__ void mfma_stage(const short* A_lds, const short* wp,
                                           int lane, int t0, int t1,
                                           f32x4& acc0, f32x4& acc1) {
    const int m = lane & 15, q = lane >> 4;
    #pragma unroll
    for (int ks = 0; ks < 4; ++ks) {
        short8_t a  = *(const short8_t*)(A_lds + m * 136 + ks * 32 + q * 8);
        short8_t b0 = *(const short8_t*)(wp + (t0 * 4 + ks) * 512 + lane * 8);
        short8_t b1 = *(const short8_t*)(wp + (t1 * 4 + ks) * 512 + lane * 8);
        acc0 = __builtin_amdgcn_mfma_f32_16x16x32_bf16(a, b0, acc0, 0, 0, 0);
        acc1 = __builtin_amdgcn_mfma_f32_16x16x32_bf16(a, b1, acc1, 0, 0, 0);
    }
}

// ---------------------------------------------------------------------------
// Fused MFMA layer kernel: 16 nodes/block, 256 threads (4 waves).
template <bool LAST>
__global__ __launch_bounds__(256) void layer_kernel(const int* __restrict__ offs,
                                                    const int2* __restrict__ meta,
                                                    const ushort_t* __restrict__ xf,
                                                    const ushort_t* __restrict__ tabB,
                                                    const short* __restrict__ w2p,
                                                    const float* __restrict__ lin2_b,
                                                    const short* __restrict__ wlp,
                                                    const float* __restrict__ lin_b,
                                                    const short* __restrict__ w1p,
                                                    float* __restrict__ h,
                                                    ushort_t* __restrict__ xf_out,
                                                    const short* __restrict__ o1p,
                                                    const float* __restrict__ o1b,
                                                    const short* __restrict__ o2p,
                                                    const float* __restrict__ o2b,
                                                    float* __restrict__ gs) {
    __shared__ short A1[16 * 136];   // bf16, row stride 136 shorts (272 B)
    __shared__ short A2[16 * 136];
    __shared__ float red[4][64];
    const int tid = threadIdx.x;
    const int n0 = blockIdx.x * 16;
    const int wv = tid >> 6;
    const int lane = tid & 63;

    // ---- phase A: wave wv aggregates nodes n0+wv*4 .. +3 (4 indep streams) ----
    {
        const int c2 = lane * 2;
        const int nb = n0 + wv * 4;
        int b0 = __builtin_amdgcn_readfirstlane(offs[nb]);
        int b1 = __builtin_amdgcn_readfirstlane(offs[nb + 1]);
        int b2 = __builtin_amdgcn_readfirstlane(offs[nb + 2]);
        int b3 = __builtin_amdgcn_readfirstlane(offs[nb + 3]);
        int b4 = __builtin_amdgcn_readfirstlane(offs[nb + 4]);

        float aA0 = 0.f, aA1 = 0.f, cA0 = 0.f, cA1 = 0.f;
        float aB0 = 0.f, aB1 = 0.f, cB0 = 0.f, cB1 = 0.f;
        float aC0 = 0.f, aC1 = 0.f, cC0 = 0.f, cC1 = 0.f;
        float aD0 = 0.f, aD1 = 0.f, cD0 = 0.f, cD1 = 0.f;
        int eA = b0, eB = b1, eC = b2, eD = b3;

        while (eA + 4 <= b1 && eB + 4 <= b2 && eC + 4 <= b3 && eD + 4 <= b4) {
            agg_quad(meta, eA, xf, tabB, c2, aA0, aA1, cA0, cA1);
            agg_quad(meta, eB, xf, tabB, c2, aB0, aB1, cB0, cB1);
            agg_quad(meta, eC, xf, tabB, c2, aC0, aC1, cC0, cC1);
            agg_quad(meta, eD, xf, tabB, c2, aD0, aD1, cD0, cD1);
            eA += 4; eB += 4; eC += 4; eD += 4;
        }
        for (; eA + 4 <= b1; eA += 4) agg_quad(meta, eA, xf, tabB, c2, aA0, aA1, cA0, cA1);
        for (; eB + 4 <= b2; eB += 4) agg_quad(meta, eB, xf, tabB, c2, aB0, aB1, cB0, cB1);
        for (; eC + 4 <= b3; eC += 4) agg_quad(meta, eC, xf, tabB, c2, aC0, aC1, cC0, cC1);
        for (; eD + 4 <= b4; eD += 4) agg_quad(meta, eD, xf, tabB, c2, aD0, aD1, cD0, cD1);
        for (; eA < b1; ++eA) agg_one(meta, eA, xf, tabB, c2, aA0, aA1);
        for (; eB < b2; ++eB) agg_one(meta, eB, xf, tabB, c2, aB0, aB1);
        for (; eC < b3; ++eC) agg_one(meta, eC, xf, tabB, c2, aC0, aC1);
        for (; eD < b4; ++eD) agg_one(meta, eD, xf, tabB, c2, aD0, aD1);

        unsigned pA = (unsigned)f2bf(aA0 + cA0) | ((unsigned)f2bf(aA1 + cA1) << 16);
        unsigned pB = (unsigned)f2bf(aB0 + cB0) | ((unsigned)f2bf(aB1 + cB1) << 16);
        unsigned pC = (unsigned)f2bf(aC0 + cC0) | ((unsigned)f2bf(aC1 + cC1) << 16);
        unsigned pD = (unsigned)f2bf(aD0 + cD0) | ((unsigned)f2bf(aD1 + cD1) << 16);
        *(unsigned*)&A1[(wv * 4 + 0) * 136 + c2] = pA;
        *(unsigned*)&A1[(wv * 4 + 1) * 136 + c2] = pB;
        *(unsigned*)&A1[(wv * 4 + 2) * 136 + c2] = pC;
        *(unsigned*)&A1[(wv * 4 + 3) * 136 + c2] = pD;
    }
    __syncthreads();

    const int m = lane & 15, q = lane >> 4;
    const int t0 = wv * 2, t1 = wv * 2 + 1;

    // ---- stage 1: t = ssp(agg @ lin2_w + lin2_b) -> A2 ----
    {
        f32x4 acc0 = {0.f, 0.f, 0.f, 0.f}, acc1 = {0.f, 0.f, 0.f, 0.f};
        mfma_stage(A1, w2p, lane, t0, t1, acc0, acc1);
        float bv0 = lin2_b[t0 * 16 + m];
        float bv1 = lin2_b[t1 * 16 + m];
        #pragma unroll
        for (int i = 0; i < 4; ++i) {
            int r = q * 4 + i;
            A2[r * 136 + t0 * 16 + m] = (short)f2bf(ssp_f(acc0[i] + bv0));
            A2[r * 136 + t1 * 16 + m] = (short)f2bf(ssp_f(acc1[i] + bv1));
        }
    }
    __syncthreads();

    // ---- stage 2: h_new = h + t @ lin_w + lin_b -> A1 (+ global h if !LAST) ----
    {
        f32x4 acc0 = {0.f, 0.f, 0.f, 0.f}, acc1 = {0.f, 0.f, 0.f, 0.f};
        mfma_stage(A2, wlp, lane, t0, t1, acc0, acc1);
        float bv0 = lin_b[t0 * 16 + m];
        float bv1 = lin_b[t1 * 16 + m];
        #pragma unroll
        for (int i = 0; i < 4; ++i) {
            int r = q * 4 + i;
            int grow = n0 + r;
            float h0 = h[(size_t)grow * 128 + t0 * 16 + m];
            float h1 = h[(size_t)grow * 128 + t1 * 16 + m];
            float hn0 = h0 + acc0[i] + bv0;
            float hn1 = h1 + acc1[i] + bv1;
            if (!LAST) {
                h[(size_t)grow * 128 + t0 * 16 + m] = hn0;
                h[(size_t)grow * 128 + t1 * 16 + m] = hn1;
            }
            A1[r * 136 + t0 * 16 + m] = (short)f2bf(hn0);
            A1[r * 136 + t1 * 16 + m] = (short)f2bf(hn1);
        }
    }
    __syncthreads();

    if constexpr (!LAST) {
        // ---- stage 3: xf_out = bf16(h_new @ lin1_next) ----
        f32x4 acc0 = {0.f, 0.f, 0.f, 0.f}, acc1 = {0.f, 0.f, 0.f, 0.f};
        mfma_stage(A1, w1p, lane, t0, t1, acc0, acc1);
        #pragma unroll
        for (int i = 0; i < 4; ++i) {
            int r = q * 4 + i;
            int grow = n0 + r;
            xf_out[(size_t)grow * 128 + t0 * 16 + m] = f2bf(acc0[i]);
            xf_out[(size_t)grow * 128 + t1 * 16 + m] = f2bf(acc1[i]);
        }
    } else {
        // ---- fused head: t1 = ssp(h_new@o1w+o1b); t2 = t1@o2w+o2b; colsum ----
        {
            // o1: K=128, N=64 -> wave wv computes col-tile wv
            f32x4 acc = {0.f, 0.f, 0.f, 0.f};
            #pragma unroll
            for (int ks = 0; ks < 4; ++ks) {
                short8_t a = *(const short8_t*)(A1 + m * 136 + ks * 32 + q * 8);
                short8_t b = *(const short8_t*)(o1p + (wv * 4 + ks) * 512 + lane * 8);
                acc = __builtin_amdgcn_mfma_f32_16x16x32_bf16(a, b, acc, 0, 0, 0);
            }
            float bv = o1b[wv * 16 + m];
            #pragma unroll
            for (int i = 0; i < 4; ++i) {
                int r = q * 4 + i;
                A2[r * 136 + wv * 16 + m] = (short)f2bf(ssp_f(acc[i] + bv));
            }
        }
        __syncthreads();
        {
            // o2: K=64, N=64 -> wave wv computes col-tile wv; then colsum
            f32x4 acc = {0.f, 0.f, 0.f, 0.f};
            #pragma unroll
            for (int ks = 0; ks < 2; ++ks) {
                short8_t a = *(const short8_t*)(A2 + m * 136 + ks * 32 + q * 8);
                short8_t b = *(const short8_t*)(o2p + (wv * 2 + ks) * 512 + lane * 8);
                acc = __builtin_amdgcn_mfma_f32_16x16x32_bf16(a, b, acc, 0, 0, 0);
            }
            float bv = o2b[wv * 16 + m];
            float part = acc[0] + acc[1] + acc[2] + acc[3] + 4.0f * bv;
            red[q][wv * 16 + m] = part;
        }
        __syncthreads();
        if (tid < 64) {
            float s = red[0][tid] + red[1][tid] + red[2][tid] + red[3][tid];
            atomicAdd(&gs[tid], s);
        }
    }
}

// out[i] = ro_b[i] + sum_k gs[k] * ro_w[k][i]
__global__ void final_kernel(const float* __restrict__ gs,
                             const float* __restrict__ ro_w,
                             const float* __restrict__ ro_b,
                             float* __restrict__ out) {
    int i = threadIdx.x;
    if (i < 12) {
        float s = ro_b[i];
        for (int k = 0; k < 64; ++k) s = fmaf(gs[k], ro_w[k * 12 + i], s);
        out[i] = s;
    }
}

// ---------------------------------------------------------------------------
extern "C" void kernel_launch(void* const* d_in, const int* in_sizes, int n_in,
                              void* d_out, int out_size, void* d_ws, size_t ws_size,
                              hipStream_t stream) {
    const int*   x      = (const int*)d_in[0];
    const int*   ei     = (const int*)d_in[1];
    const float* dist   = (const float*)d_in[2];
    const float* emb    = (const float*)d_in[3];
    const float* mlp_w1 = (const float*)d_in[4];
    const float* mlp_b1 = (const float*)d_in[5];
    const float* mlp_w2 = (const float*)d_in[6];
    const float* mlp_b2 = (const float*)d_in[7];
    const float* lin1_w = (const float*)d_in[8];
    const float* lin2_w = (const float*)d_in[9];
    const float* lin2_b = (const float*)d_in[10];
    const float* lin_w  = (const float*)d_in[11];
    const float* lin_b  = (const float*)d_in[12];
    const float* out1_w = (const float*)d_in[13];
    const float* out1_b = (const float*)d_in[14];
    const float* out2_w = (const float*)d_in[15];
    const float* out2_b = (const float*)d_in[16];
    const float* ro_w   = (const float*)d_in[17];
    const float* ro_b   = (const float*)d_in[18];
    float* out = (float*)d_out;

    // workspace layout
    char* base = (char*)d_ws;
    float*    h     = (float*)base;     base += (size_t)N_NUM * 128 * 4;
    ushort_t* tabB  = (ushort_t*)base;  base += (size_t)6 * TAB * 256 * 2;
    ushort_t* xf0   = (ushort_t*)base;  base += (size_t)N_NUM * 128 * 2;
    ushort_t* xf1   = (ushort_t*)base;  base += (size_t)N_NUM * 128 * 2;
    int2*     meta  = (int2*)base;      base += (size_t)E_NUM * 8;
    short*    wpack = (short*)base;     base += (size_t)(18 * 16384 + 8192 + 4096) * 2;
    float*    gs    = (float*)base;     base += 64 * 4;
    int*      offs  = (int*)base;       base += (N_NUM + 1) * 4;
    int*      cursor= (int*)base;       base += N_NUM * 4;
    int*      counts= (int*)base;       base += N_NUM * 4;

    hipMemsetAsync(counts, 0, N_NUM * sizeof(int), stream);
    hipMemsetAsync(gs, 0, 64 * sizeof(float), stream);

    // sort edges by dst (once; dst constant across layers)
    hist_kernel<<<(E_NUM + 255) / 256, 256, 0, stream>>>(ei, counts);
    scan_kernel<<<1, 256, 0, stream>>>(counts, offs, cursor);
    scatter_kernel<<<(E_NUM + 255) / 256, 256, 0, stream>>>(ei, dist, cursor, meta);

    // pack weights (MFMA B-frag bf16) + build filter tables
    pack_kernel<<<1200, 256, 0, stream>>>(lin2_w, lin_w, lin1_w, out1_w, out2_w, wpack);
    table_kernel<<<6 * (TAB / 64), 256, 0, stream>>>(mlp_w1, mlp_b1, mlp_w2,
                                                     mlp_b2, tabB);

    // layer 0 front: h = emb[x], xf0 = bf16(h @ lin1_w[0])
    embed_lin1_kernel<<<NB8, 256, 0, stream>>>(x, emb, lin1_w, h, xf0);

    const short* o1p = wpack + 18 * 16384;
    const short* o2p = o1p + 8192;

    for (int l = 0; l < 6; ++l) {
        ushort_t* xin  = (l & 1) ? xf1 : xf0;
        ushort_t* xout = (l & 1) ? xf0 : xf1;
        const ushort_t* tl = tabB + (size_t)l * TAB * 256;
        const short* w2p = wpack + l * 16384;
        const short* wlp = wpack + (6 + l) * 16384;
        if (l < 5) {
            const short* w1p = wpack + (12 + l + 1) * 16384;   // lin1_w[l+1]
            layer_kernel<false><<<NB16, 256, 0, stream>>>(
                offs, meta, xin, tl,
                w2p, lin2_b + l * 128, wlp, lin_b + l * 128, w1p,
                h, xout, nullptr, nullptr, nullptr, nullptr, nullptr);
        } else {
            layer_kernel<true><<<NB16, 256, 0, stream>>>(
                offs, meta, xin, tl,
                w2p, lin2_b + l * 128, wlp, lin_b + l * 128, nullptr,
                h, nullptr, o1p, out1_b, o2p, out2_b, gs);
        }
    }

    final_kernel<<<1, 64, 0, stream>>>(gs, ro_w, ro_b, out);
}

// Round 8
// 390.564 us; speedup vs baseline: 2.2109x; 1.0191x over previous
//
#include <hip/hip_runtime.h>
#include <math.h>

#define E_NUM 320000
#define N_NUM 10000
#define NB8   (N_NUM / 8)           // 1250 blocks (embed)
#define NB16  (N_NUM / 16)          // 625 blocks (layer)
#define TAB   2048

typedef unsigned short ushort_t;
typedef short short8_t __attribute__((ext_vector_type(8)));   // 8 bf16 (4 VGPRs)
typedef float f32x4    __attribute__((ext_vector_type(4)));   // MFMA acc

__device__ __forceinline__ float ssp_f(float x) {
    return fmaxf(x, 0.f) + __logf(1.f + __expf(-fabsf(x))) - 0.69314718056f;
}

__device__ __forceinline__ float bf2f(ushort_t u) {
    union { unsigned int i; float f; } v;
    v.i = ((unsigned int)u) << 16;
    return v.f;
}
__device__ __forceinline__ ushort_t f2bf(float f) {
    union { float f; unsigned int i; } v;
    v.f = f;
    unsigned int u = v.i;
    unsigned int r = (u + 0x7FFFu + ((u >> 16) & 1u)) >> 16;   // RNE
    return (ushort_t)r;
}

// ---------------------------------------------------------------------------
// counting-sort phase 1: histogram of dst
__global__ __launch_bounds__(256) void hist_kernel(const int* __restrict__ ei,
                                                   int* __restrict__ counts) {
    int e = blockIdx.x * 256 + threadIdx.x;
    if (e < E_NUM) atomicAdd(&counts[ei[E_NUM + e]], 1);
}

// phase 2: exclusive scan over 10000 bins (single block)
__global__ __launch_bounds__(256) void scan_kernel(const int* __restrict__ counts,
                                                   int* __restrict__ offs,
                                                   int* __restrict__ cursor) {
    __shared__ int part[256];
    const int tid = threadIdx.x;
    const int CH = 40;
    int base = tid * CH;
    int s = 0;
    for (int i = 0; i < CH; ++i) {
        int idx = base + i;
        if (idx < N_NUM) s += counts[idx];
    }
    part[tid] = s;
    __syncthreads();
    for (int off = 1; off < 256; off <<= 1) {
        int v = (tid >= off) ? part[tid - off] : 0;
        __syncthreads();
        part[tid] += v;
        __syncthreads();
    }
    int run = (tid > 0) ? part[tid - 1] : 0;
    for (int i = 0; i < CH; ++i) {
        int idx = base + i;
        if (idx < N_NUM) {
            offs[idx] = run;
            cursor[idx] = run;
            run += counts[idx];
        }
    }
    if (tid == 255) offs[N_NUM] = part[255];
}

// phase 3: scatter edges to dst-sorted order; pack meta = {src, (i0<<16)|fr16}
__global__ __launch_bounds__(256) void scatter_kernel(const int* __restrict__ ei,
                                                      const float* __restrict__ dist,
                                                      int* __restrict__ cursor,
                                                      int2* __restrict__ meta) {
    int e = blockIdx.x * 256 + threadIdx.x;
    if (e >= E_NUM) return;
    int d = ei[E_NUM + e];
    int pos = atomicAdd(&cursor[d], 1);
    float t = dist[e] * ((float)(TAB - 1) / 10.0f);
    int i0 = (int)t;
    if (i0 > TAB - 2) i0 = TAB - 2;
    float fr = t - (float)i0;
    int fr16 = (int)(fr * 65535.0f + 0.5f);
    meta[pos] = make_int2(ei[e], (i0 << 16) | fr16);
}

// ---------------------------------------------------------------------------
// Pack weights into MFMA B-fragment order (bf16):
//   out[((t*KSP + ks)*64 + L)*8 + j] = bf16( W[k][n] ),
//   n = t*16 + (L&15), k = ks*32 + (L>>4)*8 + j
// Regions: 6x lin2 (128x128) | 6x lin_w | 6x lin1_w | o1w (128x64) | o2w (64x64)
__global__ __launch_bounds__(256) void pack_kernel(const float* __restrict__ lin2_w,
                                                   const float* __restrict__ lin_w,
                                                   const float* __restrict__ lin1_w,
                                                   const float* __restrict__ o1w,
                                                   const float* __restrict__ o2w,
                                                   short* __restrict__ wpack) {
    int idx = blockIdx.x * 256 + threadIdx.x;
    const int M128 = 16384;
    if (idx < 18 * M128) {
        int g = idx / M128, r = idx % M128;
        const float* src;
        if (g < 6) src = lin2_w + g * M128;
        else if (g < 12) src = lin_w + (g - 6) * M128;
        else src = lin1_w + (g - 12) * M128;
        int j = r & 7, L = (r >> 3) & 63, ks = (r >> 9) & 3, t = r >> 11;
        int n = t * 16 + (L & 15);
        int k = ks * 32 + (L >> 4) * 8 + j;
        wpack[idx] = (short)f2bf(src[k * 128 + n]);
    } else if (idx < 18 * M128 + 8192) {
        int r = idx - 18 * M128;          // o1w: K=128, N=64
        int j = r & 7, L = (r >> 3) & 63, ks = (r >> 9) & 3, t = r >> 11;
        int n = t * 16 + (L & 15);
        int k = ks * 32 + (L >> 4) * 8 + j;
        wpack[idx] = (short)f2bf(o1w[k * 64 + n]);
    } else if (idx < 18 * M128 + 8192 + 4096) {
        int r = idx - 18 * M128 - 8192;   // o2w: K=64, N=64
        int j = r & 7, L = (r >> 3) & 63, ks = (r >> 9) & 1, t = r >> 10;
        int n = t * 16 + (L & 15);
        int k = ks * 32 + (L >> 4) * 8 + j;
        wpack[idx] = (short)f2bf(o2w[k * 64 + n]);
    }
}

// ---------------------------------------------------------------------------
// Build bf16 interleaved filter tables. 16 rows/block -> 6*128 = 768 blocks.
//   tabB[l][i] row = 64 col-pairs x 4 bf16: (W_i[c], W_{i+1}[c], W_i[c+1], W_{i+1}[c+1])
__global__ __launch_bounds__(256) void table_kernel(const float* __restrict__ mlp_w1,
                                                    const float* __restrict__ mlp_b1,
                                                    const float* __restrict__ mlp_w2,
                                                    const float* __restrict__ mlp_b2,
                                                    ushort_t* __restrict__ tabB) {
    __shared__ float ea[16][52];
    __shared__ float hT[128][17];
    const int tid = threadIdx.x;
    const int l = blockIdx.x >> 7;              // / 128
    const int r0 = (blockIdx.x & 127) * 16;
    const float DG = 10.0f / (float)(TAB - 1);
    const float STEP = 10.0f / 49.0f;
    const float COEFF = -0.5f / (STEP * STEP);
    const float* w1 = mlp_w1 + l * 6400;
    const float* b1 = mlp_b1 + l * 128;
    const float* w2 = mlp_w2 + l * 16384;
    const float* b2 = mlp_b2 + l * 128;
    ushort_t* tl = tabB + (size_t)l * TAB * 256;

    for (int i = tid; i < 16 * 64; i += 256) {
        int r = i >> 6, k = i & 63;
        if (k < 50) {
            float d = (float)(r0 + r) * DG;
            float t = d - (float)k * STEP;
            ea[r][k] = __expf(COEFF * t * t);
        }
    }
    __syncthreads();

    const int r  = tid & 15;
    const int cg = tid >> 4;    // 16 groups x 8 cols

    // GEMM1: hidden = ssp(ea @ w1 + b1), K=50
    float acc[8];
    #pragma unroll
    for (int j = 0; j < 8; ++j) acc[j] = 0.f;
    for (int k = 0; k < 50; ++k) {
        float a = ea[r][k];
        float4 bA = *(const float4*)(w1 + k * 128 + cg * 8);
        float4 bB = *(const float4*)(w1 + k * 128 + cg * 8 + 4);
        acc[0] = fmaf(a, bA.x, acc[0]); acc[1] = fmaf(a, bA.y, acc[1]);
        acc[2] = fmaf(a, bA.z, acc[2]); acc[3] = fmaf(a, bA.w, acc[3]);
        acc[4] = fmaf(a, bB.x, acc[4]); acc[5] = fmaf(a, bB.y, acc[5]);
        acc[6] = fmaf(a, bB.z, acc[6]); acc[7] = fmaf(a, bB.w, acc[7]);
    }
    {
        float4 bA = *(const float4*)(b1 + cg * 8);
        float4 bB = *(const float4*)(b1 + cg * 8 + 4);
        float bb[8] = {bA.x, bA.y, bA.z, bA.w, bB.x, bB.y, bB.z, bB.w};
        #pragma unroll
        for (int j = 0; j < 8; ++j) hT[cg * 8 + j][r] = ssp_f(acc[j] + bb[j]);
    }
    __syncthreads();

    // GEMM2: W = hidden @ w2 + b2, K=128
    float acc2[8];
    #pragma unroll
    for (int j = 0; j < 8; ++j) acc2[j] = 0.f;
    for (int k = 0; k < 128; ++k) {
        float a = hT[k][r];
        float4 bA = *(const float4*)(w2 + k * 128 + cg * 8);
        float4 bB = *(const float4*)(w2 + k * 128 + cg * 8 + 4);
        acc2[0] = fmaf(a, bA.x, acc2[0]); acc2[1] = fmaf(a, bA.y, acc2[1]);
        acc2[2] = fmaf(a, bA.z, acc2[2]); acc2[3] = fmaf(a, bA.w, acc2[3]);
        acc2[4] = fmaf(a, bB.x, acc2[4]); acc2[5] = fmaf(a, bB.y, acc2[5]);
        acc2[6] = fmaf(a, bB.z, acc2[6]); acc2[7] = fmaf(a, bB.w, acc2[7]);
    }
    {
        int row = r0 + r;
        float d = (float)row * DG;
        float C = 0.5f * (__cosf(d * 0.31415926535f) + 1.0f);
        float4 bA = *(const float4*)(b2 + cg * 8);
        float4 bB = *(const float4*)(b2 + cg * 8 + 4);
        float bb[8] = {bA.x, bA.y, bA.z, bA.w, bB.x, bB.y, bB.z, bB.w};
        #pragma unroll
        for (int j = 0; j < 8; ++j) {
            int col = cg * 8 + j;
            ushort_t b = f2bf((acc2[j] + bb[j]) * C);
            int base = (col >> 1) * 4 + (col & 1) * 2;
            tl[(size_t)row * 256 + base] = b;              // slot W_row
            if (row > 0)
                tl[(size_t)(row - 1) * 256 + base + 1] = b; // slot W_{row+1} of prev
        }
    }
}

// ---------------------------------------------------------------------------
// aggregation helpers
__device__ __forceinline__ void agg_quad(const int2* __restrict__ meta, int e,
                                         const ushort_t* __restrict__ xf,
                                         const ushort_t* __restrict__ tabB,
                                         int c2,
                                         float& p0, float& p1,
                                         float& q0, float& q1) {
    int2 m0 = meta[e], m1 = meta[e + 1], m2 = meta[e + 2], m3 = meta[e + 3];
    ushort2 x0 = *(const ushort2*)(xf + (size_t)m0.x * 128 + c2);
    ushort2 x1 = *(const ushort2*)(xf + (size_t)m1.x * 128 + c2);
    ushort2 x2 = *(const ushort2*)(xf + (size_t)m2.x * 128 + c2);
    ushort2 x3 = *(const ushort2*)(xf + (size_t)m3.x * 128 + c2);
    ushort4 t0 = *(const ushort4*)(tabB + (size_t)(((unsigned)m0.y) >> 16) * 256 + c2 * 2);
    ushort4 t1 = *(const ushort4*)(tabB + (size_t)(((unsigned)m1.y) >> 16) * 256 + c2 * 2);
    ushort4 t2 = *(const ushort4*)(tabB + (size_t)(((unsigned)m2.y) >> 16) * 256 + c2 * 2);
    ushort4 t3 = *(const ushort4*)(tabB + (size_t)(((unsigned)m3.y) >> 16) * 256 + c2 * 2);

    float f0 = (float)(m0.y & 0xffff) * (1.0f / 65535.0f);
    float f1 = (float)(m1.y & 0xffff) * (1.0f / 65535.0f);
    float f2 = (float)(m2.y & 0xffff) * (1.0f / 65535.0f);
    float f3 = (float)(m3.y & 0xffff) * (1.0f / 65535.0f);

    float w;
    w = fmaf(f0, bf2f(t0.y) - bf2f(t0.x), bf2f(t0.x)); p0 = fmaf(bf2f(x0.x), w, p0);
    w = fmaf(f0, bf2f(t0.w) - bf2f(t0.z), bf2f(t0.z)); p1 = fmaf(bf2f(x0.y), w, p1);
    w = fmaf(f1, bf2f(t1.y) - bf2f(t1.x), bf2f(t1.x)); q0 = fmaf(bf2f(x1.x), w, q0);
    w = fmaf(f1, bf2f(t1.w) - bf2f(t1.z), bf2f(t1.z)); q1 = fmaf(bf2f(x1.y), w, q1);
    w = fmaf(f2, bf2f(t2.y) - bf2f(t2.x), bf2f(t2.x)); p0 = fmaf(bf2f(x2.x), w, p0);
    w = fmaf(f2, bf2f(t2.w) - bf2f(t2.z), bf2f(t2.z)); p1 = fmaf(bf2f(x2.y), w, p1);
    w = fmaf(f3, bf2f(t3.y) - bf2f(t3.x), bf2f(t3.x)); q0 = fmaf(bf2f(x3.x), w, q0);
    w = fmaf(f3, bf2f(t3.w) - bf2f(t3.z), bf2f(t3.z)); q1 = fmaf(bf2f(x3.y), w, q1);
}

__device__ __forceinline__ void agg_one(const int2* __restrict__ meta, int e,
                                        const ushort_t* __restrict__ xf,
                                        const ushort_t* __restrict__ tabB,
                                        int c2, float& p0, float& p1) {
    int2 m = meta[e];
    ushort2 xv = *(const ushort2*)(xf + (size_t)m.x * 128 + c2);
    ushort4 tv = *(const ushort4*)(tabB + (size_t)(((unsigned)m.y) >> 16) * 256 + c2 * 2);
    float f = (float)(m.y & 0xffff) * (1.0f / 65535.0f);
    float w0 = fmaf(f, bf2f(tv.y) - bf2f(tv.x), bf2f(tv.x));
    float w1 = fmaf(f, bf2f(tv.w) - bf2f(tv.z), bf2f(tv.z));
    p0 = fmaf(bf2f(xv.x), w0, p0);
    p1 = fmaf(bf2f(xv.y), w1, p1);
}

// ---------------------------------------------------------------------------
// Layer 0 front: h = emb[x]; xf = bf16(h @ lin1_w[0]).  8 rows/block, 256 thr.
__global__ __launch_bounds__(256) void embed_lin1_kernel(const int* __restrict__ x,
                                                         const float* __restrict__ emb,
                                                         const float* __restrict__ B,
                                                         float* __restrict__ h,
                                                         ushort_t* __restrict__ xf) {
    __shared__ float AT[128][9];
    __shared__ int s_x[8];
    const int tid = threadIdx.x;
    const int n0 = blockIdx.x * 8;

    if (tid < 8) s_x[tid] = x[n0 + tid];
    __syncthreads();
    for (int i = tid; i < 8 * 128; i += 256) {
        int r = i >> 7, c = i & 127;
        float v = emb[s_x[r] * 128 + c];
        AT[c][r] = v;
        h[(size_t)(n0 + r) * 128 + c] = v;
    }
    __syncthreads();

    const int r  = tid & 7;
    const int c0 = (tid >> 3) * 4;
    float acc[4] = {0.f, 0.f, 0.f, 0.f};
    for (int k = 0; k < 128; k += 4) {
        float a[4];
        #pragma unroll
        for (int u = 0; u < 4; ++u) a[u] = AT[k + u][r];
        #pragma unroll
        for (int u = 0; u < 4; ++u) {
            float4 b = *(const float4*)(B + (size_t)(k + u) * 128 + c0);
            acc[0] = fmaf(a[u], b.x, acc[0]);
            acc[1] = fmaf(a[u], b.y, acc[1]);
            acc[2] = fmaf(a[u], b.z, acc[2]);
            acc[3] = fmaf(a[u], b.w, acc[3]);
        }
    }
    ushort4 o;
    o.x = f2bf(acc[0]); o.y = f2bf(acc[1]); o.z = f2bf(acc[2]); o.w = f2bf(acc[3]);
    *(ushort4*)(xf + (size_t)(n0 + r) * 128 + c0) = o;
}

// ---------------------------------------------------------------------------
// Fused MFMA layer kernel: 16 nodes/block, 512 threads (8 waves).
// phase A: wave wv aggregates nodes n0+wv*2, +1 (2 indep streams).
// MFMA stages: wave wv computes the 16-col tile t = wv.
template <bool LAST>
__global__ __launch_bounds__(512) void layer_kernel(const int* __restrict__ offs,
                                                    const int2* __restrict__ meta,
                                                    const ushort_t* __restrict__ xf,
                                                    const ushort_t* __restrict__ tabB,
                                                    const short* __restrict__ w2p,
                                                    const float* __restrict__ lin2_b,
                                                    const short* __restrict__ wlp,
                                                    const float* __restrict__ lin_b,
                                                    const short* __restrict__ w1p,
                                                    float* __restrict__ h,
                                                    ushort_t* __restrict__ xf_out,
                                                    const short* __restrict__ o1p,
                                                    const float* __restrict__ o1b,
                                                    const short* __restrict__ o2p,
                                                    const float* __restrict__ o2b,
                                                    float* __restrict__ gs) {
    __shared__ short A1[16 * 136];   // bf16, row stride 136 shorts (272 B)
    __shared__ short A2[16 * 136];
    __shared__ float red[4][64];
    const int tid = threadIdx.x;
    const int n0 = blockIdx.x * 16;
    const int wv = tid >> 6;         // 0..7
    const int lane = tid & 63;

    // ---- phase A ----
    {
        const int c2 = lane * 2;
        const int nb = n0 + wv * 2;
        int b0 = __builtin_amdgcn_readfirstlane(offs[nb]);
        int b1 = __builtin_amdgcn_readfirstlane(offs[nb + 1]);
        int b2 = __builtin_amdgcn_readfirstlane(offs[nb + 2]);

        float aA0 = 0.f, aA1 = 0.f, cA0 = 0.f, cA1 = 0.f;
        float aB0 = 0.f, aB1 = 0.f, cB0 = 0.f, cB1 = 0.f;
        int eA = b0, eB = b1;

        while (eA + 4 <= b1 && eB + 4 <= b2) {
            agg_quad(meta, eA, xf, tabB, c2, aA0, aA1, cA0, cA1);
            agg_quad(meta, eB, xf, tabB, c2, aB0, aB1, cB0, cB1);
            eA += 4; eB += 4;
        }
        for (; eA + 4 <= b1; eA += 4) agg_quad(meta, eA, xf, tabB, c2, aA0, aA1, cA0, cA1);
        for (; eB + 4 <= b2; eB += 4) agg_quad(meta, eB, xf, tabB, c2, aB0, aB1, cB0, cB1);
        for (; eA < b1; ++eA) agg_one(meta, eA, xf, tabB, c2, aA0, aA1);
        for (; eB < b2; ++eB) agg_one(meta, eB, xf, tabB, c2, aB0, aB1);

        unsigned pA = (unsigned)f2bf(aA0 + cA0) | ((unsigned)f2bf(aA1 + cA1) << 16);
        unsigned pB = (unsigned)f2bf(aB0 + cB0) | ((unsigned)f2bf(aB1 + cB1) << 16);
        *(unsigned*)&A1[(wv * 2 + 0) * 136 + c2] = pA;
        *(unsigned*)&A1[(wv * 2 + 1) * 136 + c2] = pB;
    }
    __syncthreads();

    const int m = lane & 15, q = lane >> 4;

    // ---- stage 1: t = ssp(agg @ lin2_w + lin2_b) -> A2 ----
    {
        f32x4 acc = {0.f, 0.f, 0.f, 0.f};
        #pragma unroll
        for (int ks = 0; ks < 4; ++ks) {
            short8_t a = *(const short8_t*)(A1 + m * 136 + ks * 32 + q * 8);
            short8_t b = *(const short8_t*)(w2p + (wv * 4 + ks) * 512 + lane * 8);
            acc = __builtin_amdgcn_mfma_f32_16x16x32_bf16(a, b, acc, 0, 0, 0);
        }
        float bv = lin2_b[wv * 16 + m];
        #pragma unroll
        for (int i = 0; i < 4; ++i) {
            int r = q * 4 + i;
            A2[r * 136 + wv * 16 + m] = (short)f2bf(ssp_f(acc[i] + bv));
        }
    }
    __syncthreads();

    // ---- stage 2: h_new = h + t @ lin_w + lin_b -> A1 (+ global h if !LAST) ----
    {
        f32x4 acc = {0.f, 0.f, 0.f, 0.f};
        #pragma unroll
        for (int ks = 0; ks < 4; ++ks) {
            short8_t a = *(const short8_t*)(A2 + m * 136 + ks * 32 + q * 8);
            short8_t b = *(const short8_t*)(wlp + (wv * 4 + ks) * 512 + lane * 8);
            acc = __builtin_amdgcn_mfma_f32_16x16x32_bf16(a, b, acc, 0, 0, 0);
        }
        float bv = lin_b[wv * 16 + m];
        #pragma unroll
        for (int i = 0; i < 4; ++i) {
            int r = q * 4 + i;
            int grow = n0 + r;
            float h0 = h[(size_t)grow * 128 + wv * 16 + m];
            float hn = h0 + acc[i] + bv;
            if (!LAST) h[(size_t)grow * 128 + wv * 16 + m] = hn;
            A1[r * 136 + wv * 16 + m] = (short)f2bf(hn);
        }
    }
    __syncthreads();

    if constexpr (!LAST) {
        // ---- stage 3: xf_out = bf16(h_new @ lin1_next) ----
        f32x4 acc = {0.f, 0.f, 0.f, 0.f};
        #pragma unroll
        for (int ks = 0; ks < 4; ++ks) {
            short8_t a = *(const short8_t*)(A1 + m * 136 + ks * 32 + q * 8);
            short8_t b = *(const short8_t*)(w1p + (wv * 4 + ks) * 512 + lane * 8);
            acc = __builtin_amdgcn_mfma_f32_16x16x32_bf16(a, b, acc, 0, 0, 0);
        }
        #pragma unroll
        for (int i = 0; i < 4; ++i) {
            int r = q * 4 + i;
            int grow = n0 + r;
            xf_out[(size_t)grow * 128 + wv * 16 + m] = f2bf(acc[i]);
        }
    } else {
        // ---- fused head: waves 0-3 compute o1/o2 col-tiles; colsum -> gs ----
        if (wv < 4) {
            f32x4 acc = {0.f, 0.f, 0.f, 0.f};
            #pragma unroll
            for (int ks = 0; ks < 4; ++ks) {
                short8_t a = *(const short8_t*)(A1 + m * 136 + ks * 32 + q * 8);
                short8_t b = *(const short8_t*)(o1p + (wv * 4 + ks) * 512 + lane * 8);
                acc = __builtin_amdgcn_mfma_f32_16x16x32_bf16(a, b, acc, 0, 0, 0);
            }
            float bv = o1b[wv * 16 + m];
            #pragma unroll
            for (int i = 0; i < 4; ++i) {
                int r = q * 4 + i;
                A2[r * 136 + wv * 16 + m] = (short)f2bf(ssp_f(acc[i] + bv));
            }
        }
        __syncthreads();
        if (wv < 4) {
            f32x4 acc = {0.f, 0.f, 0.f, 0.f};
            #pragma unroll
            for (int ks = 0; ks < 2; ++ks) {
                short8_t a = *(const short8_t*)(A2 + m * 136 + ks * 32 + q * 8);
                short8_t b = *(const short8_t*)(o2p + (wv * 2 + ks) * 512 + lane * 8);
                acc = __builtin_amdgcn_mfma_f32_16x16x32_bf16(a, b, acc, 0, 0, 0);
            }
            float bv = o2b[wv * 16 + m];
            float part = acc[0] + acc[1] + acc[2] + acc[3] + 4.0f * bv;
            red[q][wv * 16 + m] = part;
        }
        __syncthreads();
        if (tid < 64) {
            float s = red[0][tid] + red[1][tid] + red[2][tid] + red[3][tid];
            atomicAdd(&gs[tid], s);
        }
    }
}

// out[i] = ro_b[i] + sum_k gs[k] * ro_w[k][i]
__global__ void final_kernel(const float* __restrict__ gs,
                             const float* __restrict__ ro_w,
                             const float* __restrict__ ro_b,
                             float* __restrict__ out) {
    int i = threadIdx.x;
    if (i < 12) {
        float s = ro_b[i];
        for (int k = 0; k < 64; ++k) s = fmaf(gs[k], ro_w[k * 12 + i], s);
        out[i] = s;
    }
}

// ---------------------------------------------------------------------------
extern "C" void kernel_launch(void* const* d_in, const int* in_sizes, int n_in,
                              void* d_out, int out_size, void* d_ws, size_t ws_size,
                              hipStream_t stream) {
    const int*   x      = (const int*)d_in[0];
    const int*   ei     = (const int*)d_in[1];
    const float* dist   = (const float*)d_in[2];
    const float* emb    = (const float*)d_in[3];
    const float* mlp_w1 = (const float*)d_in[4];
    const float* mlp_b1 = (const float*)d_in[5];
    const float* mlp_w2 = (const float*)d_in[6];
    const float* mlp_b2 = (const float*)d_in[7];
    const float* lin1_w = (const float*)d_in[8];
    const float* lin2_w = (const float*)d_in[9];
    const float* lin2_b = (const float*)d_in[10];
    const float* lin_w  = (const float*)d_in[11];
    const float* lin_b  = (const float*)d_in[12];
    const float* out1_w = (const float*)d_in[13];
    const float* out1_b = (const float*)d_in[14];
    const float* out2_w = (const float*)d_in[15];
    const float* out2_b = (const float*)d_in[16];
    const float* ro_w   = (const float*)d_in[17];
    const float* ro_b   = (const float*)d_in[18];
    float* out = (float*)d_out;

    // workspace layout
    char* base = (char*)d_ws;
    float*    h     = (float*)base;     base += (size_t)N_NUM * 128 * 4;
    ushort_t* tabB  = (ushort_t*)base;  base += (size_t)6 * TAB * 256 * 2;
    ushort_t* xf0   = (ushort_t*)base;  base += (size_t)N_NUM * 128 * 2;
    ushort_t* xf1   = (ushort_t*)base;  base += (size_t)N_NUM * 128 * 2;
    int2*     meta  = (int2*)base;      base += (size_t)E_NUM * 8;
    short*    wpack = (short*)base;     base += (size_t)(18 * 16384 + 8192 + 4096) * 2;
    float*    gs    = (float*)base;     base += 64 * 4;
    int*      offs  = (int*)base;       base += (N_NUM + 1) * 4;
    int*      cursor= (int*)base;       base += N_NUM * 4;
    int*      counts= (int*)base;       base += N_NUM * 4;

    hipMemsetAsync(counts, 0, N_NUM * sizeof(int), stream);
    hipMemsetAsync(gs, 0, 64 * sizeof(float), stream);

    // sort edges by dst (once; dst constant across layers)
    hist_kernel<<<(E_NUM + 255) / 256, 256, 0, stream>>>(ei, counts);
    scan_kernel<<<1, 256, 0, stream>>>(counts, offs, cursor);
    scatter_kernel<<<(E_NUM + 255) / 256, 256, 0, stream>>>(ei, dist, cursor, meta);

    // pack weights (MFMA B-frag bf16) + build filter tables
    pack_kernel<<<1200, 256, 0, stream>>>(lin2_w, lin_w, lin1_w, out1_w, out2_w, wpack);
    table_kernel<<<6 * (TAB / 16), 256, 0, stream>>>(mlp_w1, mlp_b1, mlp_w2,
                                                     mlp_b2, tabB);

    // layer 0 front: h = emb[x], xf0 = bf16(h @ lin1_w[0])
    embed_lin1_kernel<<<NB8, 256, 0, stream>>>(x, emb, lin1_w, h, xf0);

    const short* o1p = wpack + 18 * 16384;
    const short* o2p = o1p + 8192;

    for (int l = 0; l < 6; ++l) {
        ushort_t* xin  = (l & 1) ? xf1 : xf0;
        ushort_t* xout = (l & 1) ? xf0 : xf1;
        const ushort_t* tl = tabB + (size_t)l * TAB * 256;
        const short* w2p = wpack + l * 16384;
        const short* wlp = wpack + (6 + l) * 16384;
        if (l < 5) {
            const short* w1p = wpack + (12 + l + 1) * 16384;   // lin1_w[l+1]
            layer_kernel<false><<<NB16, 512, 0, stream>>>(
                offs, meta, xin, tl,
                w2p, lin2_b + l * 128, wlp, lin_b + l * 128, w1p,
                h, xout, nullptr, nullptr, nullptr, nullptr, nullptr);
        } else {
            layer_kernel<true><<<NB16, 512, 0, stream>>>(
                offs, meta, xin, tl,
                w2p, lin2_b + l * 128, wlp, lin_b + l * 128, nullptr,
                h, nullptr, o1p, out1_b, o2p, out2_b, gs);
        }
    }

    final_kernel<<<1, 64, 0, stream>>>(gs, ro_w, ro_b, out);
}

// Round 9
// 364.622 us; speedup vs baseline: 2.3682x; 1.0711x over previous
//
#include <hip/hip_runtime.h>
#include <math.h>

#define E_NUM 320000
#define N_NUM 10000
#define NB8   (N_NUM / 8)           // 1250 blocks (embed)
#define NB16  (N_NUM / 16)          // 625 blocks (layer)
#define TAB   2048

typedef unsigned short ushort_t;
typedef short short8_t __attribute__((ext_vector_type(8)));   // 8 bf16 (4 VGPRs)
typedef float f32x4    __attribute__((ext_vector_type(4)));   // MFMA acc

// wpack layout (shorts):
//   [0)        6x lin2_w  128x128
//   [98304)    6x lin_w   128x128
//   [196608)   6x lin1_w  128x128
//   [294912)   o1w 128x64
//   [303104)   o2w 64x64
//   [307200)   6x mlp_w1  (K=64 zero-padded)x128  -> 8192 each
//   [356352)   6x mlp_w2  128x128                 -> 16384 each
#define WP_O1   294912
#define WP_O2   303104
#define WP_W1T  307200
#define WP_W2T  356352
#define WP_TOT  454656

__device__ __forceinline__ float ssp_f(float x) {
    return fmaxf(x, 0.f) + __logf(1.f + __expf(-fabsf(x))) - 0.69314718056f;
}

__device__ __forceinline__ float bf2f(ushort_t u) {
    union { unsigned int i; float f; } v;
    v.i = ((unsigned int)u) << 16;
    return v.f;
}
__device__ __forceinline__ ushort_t f2bf(float f) {
    union { float f; unsigned int i; } v;
    v.f = f;
    unsigned int u = v.i;
    unsigned int r = (u + 0x7FFFu + ((u >> 16) & 1u)) >> 16;   // RNE
    return (ushort_t)r;
}

// ---------------------------------------------------------------------------
// counting-sort phase 1: histogram of dst
__global__ __launch_bounds__(256) void hist_kernel(const int* __restrict__ ei,
                                                   int* __restrict__ counts) {
    int e = blockIdx.x * 256 + threadIdx.x;
    if (e < E_NUM) atomicAdd(&counts[ei[E_NUM + e]], 1);
}

// phase 2: exclusive scan over 10000 bins (single block)
__global__ __launch_bounds__(256) void scan_kernel(const int* __restrict__ counts,
                                                   int* __restrict__ offs,
                                                   int* __restrict__ cursor) {
    __shared__ int part[256];
    const int tid = threadIdx.x;
    const int CH = 40;
    int base = tid * CH;
    int s = 0;
    for (int i = 0; i < CH; ++i) {
        int idx = base + i;
        if (idx < N_NUM) s += counts[idx];
    }
    part[tid] = s;
    __syncthreads();
    for (int off = 1; off < 256; off <<= 1) {
        int v = (tid >= off) ? part[tid - off] : 0;
        __syncthreads();
        part[tid] += v;
        __syncthreads();
    }
    int run = (tid > 0) ? part[tid - 1] : 0;
    for (int i = 0; i < CH; ++i) {
        int idx = base + i;
        if (idx < N_NUM) {
            offs[idx] = run;
            cursor[idx] = run;
            run += counts[idx];
        }
    }
    if (tid == 255) offs[N_NUM] = part[255];
}

// phase 3: scatter edges to dst-sorted order; pack meta = {src, (i0<<16)|fr16}
__global__ __launch_bounds__(256) void scatter_kernel(const int* __restrict__ ei,
                                                      const float* __restrict__ dist,
                                                      int* __restrict__ cursor,
                                                      int2* __restrict__ meta) {
    int e = blockIdx.x * 256 + threadIdx.x;
    if (e >= E_NUM) return;
    int d = ei[E_NUM + e];
    int pos = atomicAdd(&cursor[d], 1);
    float t = dist[e] * ((float)(TAB - 1) / 10.0f);
    int i0 = (int)t;
    if (i0 > TAB - 2) i0 = TAB - 2;
    float fr = t - (float)i0;
    int fr16 = (int)(fr * 65535.0f + 0.5f);
    meta[pos] = make_int2(ei[e], (i0 << 16) | fr16);
}

// ---------------------------------------------------------------------------
// Pack all weights into MFMA B-fragment order (bf16).
// B-frag: idx = ((t*KSP + ks)*64 + L)*8 + j ; n = t*16+(L&15), k = ks*32+(L>>4)*8+j
__global__ __launch_bounds__(256) void pack_kernel(const float* __restrict__ lin2_w,
                                                   const float* __restrict__ lin_w,
                                                   const float* __restrict__ lin1_w,
                                                   const float* __restrict__ o1w,
                                                   const float* __restrict__ o2w,
                                                   const float* __restrict__ mlp_w1,
                                                   const float* __restrict__ mlp_w2,
                                                   short* __restrict__ wpack) {
    int idx = blockIdx.x * 256 + threadIdx.x;
    const int M128 = 16384;
    if (idx < 18 * M128) {
        int g = idx / M128, r = idx % M128;
        const float* src;
        if (g < 6) src = lin2_w + g * M128;
        else if (g < 12) src = lin_w + (g - 6) * M128;
        else src = lin1_w + (g - 12) * M128;
        int j = r & 7, L = (r >> 3) & 63, ks = (r >> 9) & 3, t = r >> 11;
        int n = t * 16 + (L & 15);
        int k = ks * 32 + (L >> 4) * 8 + j;
        wpack[idx] = (short)f2bf(src[k * 128 + n]);
    } else if (idx < WP_O2) {
        int r = idx - WP_O1;              // o1w: K=128, N=64
        int j = r & 7, L = (r >> 3) & 63, ks = (r >> 9) & 3, t = r >> 11;
        int n = t * 16 + (L & 15);
        int k = ks * 32 + (L >> 4) * 8 + j;
        wpack[idx] = (short)f2bf(o1w[k * 64 + n]);
    } else if (idx < WP_W1T) {
        int r = idx - WP_O2;              // o2w: K=64, N=64
        int j = r & 7, L = (r >> 3) & 63, ks = (r >> 9) & 1, t = r >> 10;
        int n = t * 16 + (L & 15);
        int k = ks * 32 + (L >> 4) * 8 + j;
        wpack[idx] = (short)f2bf(o2w[k * 64 + n]);
    } else if (idx < WP_W2T) {
        int r2 = idx - WP_W1T;            // mlp_w1: K=50 pad to 64, N=128
        int g = r2 / 8192, r = r2 % 8192;
        int j = r & 7, L = (r >> 3) & 63, ks = (r >> 9) & 1, t = r >> 10;
        int n = t * 16 + (L & 15);
        int k = ks * 32 + (L >> 4) * 8 + j;
        float v = (k < 50) ? mlp_w1[g * 6400 + k * 128 + n] : 0.f;
        wpack[idx] = (short)f2bf(v);
    } else if (idx < WP_TOT) {
        int r2 = idx - WP_W2T;            // mlp_w2: K=128, N=128
        int g = r2 / M128, r = r2 % M128;
        int j = r & 7, L = (r >> 3) & 63, ks = (r >> 9) & 3, t = r >> 11;
        int n = t * 16 + (L & 15);
        int k = ks * 32 + (L >> 4) * 8 + j;
        wpack[idx] = (short)f2bf(mlp_w2[g * M128 + k * 128 + n]);
    }
}

// ---------------------------------------------------------------------------
// MFMA table build: 16 d-rows/block, 512 threads, 6*128 = 768 blocks.
// tabB[l][i] row = 64 col-pairs x 4 bf16 (interleaved lerp pairs).
__global__ __launch_bounds__(512) void table_kernel(const short* __restrict__ w1t,
                                                    const float* __restrict__ mlp_b1,
                                                    const short* __restrict__ w2t,
                                                    const float* __restrict__ mlp_b2,
                                                    ushort_t* __restrict__ tabB) {
    __shared__ short EA[16 * 72];    // bf16 gaussians, K padded to 64
    __shared__ short HD[16 * 136];   // bf16 hidden
    const int tid = threadIdx.x;
    const int wv = tid >> 6;
    const int lane = tid & 63;
    const int l = blockIdx.x >> 7;
    const int r0 = (blockIdx.x & 127) * 16;
    const float DG = 10.0f / (float)(TAB - 1);
    const float STEP = 10.0f / 49.0f;
    const float COEFF = -0.5f / (STEP * STEP);

    for (int i = tid; i < 16 * 64; i += 512) {
        int r = i >> 6, k = i & 63;
        float v = 0.f;
        if (k < 50) {
            float d = (float)(r0 + r) * DG;
            float t = d - (float)k * STEP;
            v = __expf(COEFF * t * t);
        }
        EA[r * 72 + k] = (short)f2bf(v);
    }
    __syncthreads();

    const int m = lane & 15, q = lane >> 4;

    // stage 1: hidden = ssp(ea @ w1 + b1), K=64 (padded)
    {
        f32x4 acc = {0.f, 0.f, 0.f, 0.f};
        #pragma unroll
        for (int ks = 0; ks < 2; ++ks) {
            short8_t a = *(const short8_t*)(EA + m * 72 + ks * 32 + q * 8);
            short8_t b = *(const short8_t*)(w1t + l * 8192 + (wv * 2 + ks) * 512 + lane * 8);
            acc = __builtin_amdgcn_mfma_f32_16x16x32_bf16(a, b, acc, 0, 0, 0);
        }
        float bv = mlp_b1[l * 128 + wv * 16 + m];
        #pragma unroll
        for (int i = 0; i < 4; ++i)
            HD[(q * 4 + i) * 136 + wv * 16 + m] = (short)f2bf(ssp_f(acc[i] + bv));
    }
    __syncthreads();

    // stage 2: W = hidden @ w2 + b2, *C(d), interleaved write
    {
        f32x4 acc = {0.f, 0.f, 0.f, 0.f};
        #pragma unroll
        for (int ks = 0; ks < 4; ++ks) {
            short8_t a = *(const short8_t*)(HD + m * 136 + ks * 32 + q * 8);
            short8_t b = *(const short8_t*)(w2t + l * 16384 + (wv * 4 + ks) * 512 + lane * 8);
            acc = __builtin_amdgcn_mfma_f32_16x16x32_bf16(a, b, acc, 0, 0, 0);
        }
        int col = wv * 16 + m;
        float bv = mlp_b2[l * 128 + col];
        int base = (col >> 1) * 4 + (col & 1) * 2;
        ushort_t* tl = tabB + (size_t)l * TAB * 256;
        #pragma unroll
        for (int i = 0; i < 4; ++i) {
            int row = r0 + q * 4 + i;
            float d = (float)row * DG;
            float C = 0.5f * (__cosf(d * 0.31415926535f) + 1.0f);
            ushort_t w = f2bf((acc[i] + bv) * C);
            tl[(size_t)row * 256 + base] = w;                // slot W_row
            if (row > 0)
                tl[(size_t)(row - 1) * 256 + base + 1] = w;  // slot W_{row+1} of prev
        }
    }
}

// ---------------------------------------------------------------------------
// half-wave lerp-accumulate: 4 cols/lane, one edge
__device__ __forceinline__ void lerp4(short8_t t, float f, ushort4 xv,
                                      float& o0, float& o1, float& o2, float& o3) {
    float l0 = bf2f((ushort_t)t[0]), h0 = bf2f((ushort_t)t[1]);
    float l1 = bf2f((ushort_t)t[2]), h1 = bf2f((ushort_t)t[3]);
    float l2 = bf2f((ushort_t)t[4]), h2 = bf2f((ushort_t)t[5]);
    float l3 = bf2f((ushort_t)t[6]), h3 = bf2f((ushort_t)t[7]);
    float w0 = fmaf(f, h0 - l0, l0);
    float w1 = fmaf(f, h1 - l1, l1);
    float w2 = fmaf(f, h2 - l2, l2);
    float w3 = fmaf(f, h3 - l3, l3);
    o0 = fmaf(bf2f(xv.x), w0, o0);
    o1 = fmaf(bf2f(xv.y), w1, o1);
    o2 = fmaf(bf2f(xv.z), w2, o2);
    o3 = fmaf(bf2f(xv.w), w3, o3);
}

// ---------------------------------------------------------------------------
// Layer 0 front: h = emb[x]; xf = bf16(h @ lin1_w[0]).  8 rows/block, 256 thr.
__global__ __launch_bounds__(256) void embed_lin1_kernel(const int* __restrict__ x,
                                                         const float* __restrict__ emb,
                                                         const float* __restrict__ B,
                                                         float* __restrict__ h,
                                                         ushort_t* __restrict__ xf) {
    __shared__ float AT[128][9];
    __shared__ int s_x[8];
    const int tid = threadIdx.x;
    const int n0 = blockIdx.x * 8;

    if (tid < 8) s_x[tid] = x[n0 + tid];
    __syncthreads();
    for (int i = tid; i < 8 * 128; i += 256) {
        int r = i >> 7, c = i & 127;
        float v = emb[s_x[r] * 128 + c];
        AT[c][r] = v;
        h[(size_t)(n0 + r) * 128 + c] = v;
    }
    __syncthreads();

    const int r  = tid & 7;
    const int c0 = (tid >> 3) * 4;
    float acc[4] = {0.f, 0.f, 0.f, 0.f};
    for (int k = 0; k < 128; k += 4) {
        float a[4];
        #pragma unroll
        for (int u = 0; u < 4; ++u) a[u] = AT[k + u][r];
        #pragma unroll
        for (int u = 0; u < 4; ++u) {
            float4 b = *(const float4*)(B + (size_t)(k + u) * 128 + c0);
            acc[0] = fmaf(a[u], b.x, acc[0]);
            acc[1] = fmaf(a[u], b.y, acc[1]);
            acc[2] = fmaf(a[u], b.z, acc[2]);
            acc[3] = fmaf(a[u], b.w, acc[3]);
        }
    }
    ushort4 o;
    o.x = f2bf(acc[0]); o.y = f2bf(acc[1]); o.z = f2bf(acc[2]); o.w = f2bf(acc[3]);
    *(ushort4*)(xf + (size_t)(n0 + r) * 128 + c0) = o;
}

// ---------------------------------------------------------------------------
// Fused MFMA layer kernel: 16 nodes/block, 512 threads (8 waves).
// phase A: HALF-WAVE edge streams — each half-wave (32 lanes x 4 cols) owns one
//          node's edge stream; one vector load serves 2 edges per wave instr.
// MFMA stages: wave wv computes the 16-col tile t = wv.
template <bool LAST>
__global__ __launch_bounds__(512) void layer_kernel(const int* __restrict__ offs,
                                                    const int2* __restrict__ meta,
                                                    const ushort_t* __restrict__ xf,
                                                    const ushort_t* __restrict__ tabB,
                                                    const short* __restrict__ w2p,
                                                    const float* __restrict__ lin2_b,
                                                    const short* __restrict__ wlp,
                                                    const float* __restrict__ lin_b,
                                                    const short* __restrict__ w1p,
                                                    float* __restrict__ h,
                                                    ushort_t* __restrict__ xf_out,
                                                    const short* __restrict__ o1p,
                                                    const float* __restrict__ o1b,
                                                    const short* __restrict__ o2p,
                                                    const float* __restrict__ o2b,
                                                    float* __restrict__ gs) {
    __shared__ short A1[16 * 136];   // bf16, row stride 136 shorts (272 B)
    __shared__ short A2[16 * 136];
    __shared__ float red[4][64];
    const int tid = threadIdx.x;
    const int n0 = blockIdx.x * 16;
    const int wv = tid >> 6;         // 0..7
    const int lane = tid & 63;

    // ---- phase A: half-wave edge streams ----
    {
        const int half = lane >> 5;
        const int c4 = (lane & 31) * 4;
        const int node = n0 + wv * 2 + half;
        int e   = offs[node];
        int end = offs[node + 1];

        float a0 = 0.f, a1 = 0.f, a2 = 0.f, a3 = 0.f;
        float b0 = 0.f, b1 = 0.f, b2 = 0.f, b3 = 0.f;

        for (; e + 4 <= end; e += 4) {
            int2 m0 = meta[e], m1 = meta[e + 1], m2 = meta[e + 2], m3 = meta[e + 3];
            ushort4 x0 = *(const ushort4*)(xf + (size_t)m0.x * 128 + c4);
            ushort4 x1 = *(const ushort4*)(xf + (size_t)m1.x * 128 + c4);
            ushort4 x2 = *(const ushort4*)(xf + (size_t)m2.x * 128 + c4);
            ushort4 x3 = *(const ushort4*)(xf + (size_t)m3.x * 128 + c4);
            short8_t t0 = *(const short8_t*)(tabB + (size_t)(((unsigned)m0.y) >> 16) * 256 + c4 * 2);
            short8_t t1 = *(const short8_t*)(tabB + (size_t)(((unsigned)m1.y) >> 16) * 256 + c4 * 2);
            short8_t t2 = *(const short8_t*)(tabB + (size_t)(((unsigned)m2.y) >> 16) * 256 + c4 * 2);
            short8_t t3 = *(const short8_t*)(tabB + (size_t)(((unsigned)m3.y) >> 16) * 256 + c4 * 2);
            float f0 = (float)(m0.y & 0xffff) * (1.0f / 65535.0f);
            float f1 = (float)(m1.y & 0xffff) * (1.0f / 65535.0f);
            float f2 = (float)(m2.y & 0xffff) * (1.0f / 65535.0f);
            float f3 = (float)(m3.y & 0xffff) * (1.0f / 65535.0f);
            lerp4(t0, f0, x0, a0, a1, a2, a3);
            lerp4(t1, f1, x1, b0, b1, b2, b3);
            lerp4(t2, f2, x2, a0, a1, a2, a3);
            lerp4(t3, f3, x3, b0, b1, b2, b3);
        }
        for (; e < end; ++e) {
            int2 mm = meta[e];
            ushort4 xv = *(const ushort4*)(xf + (size_t)mm.x * 128 + c4);
            short8_t tv = *(const short8_t*)(tabB + (size_t)(((unsigned)mm.y) >> 16) * 256 + c4 * 2);
            float f = (float)(mm.y & 0xffff) * (1.0f / 65535.0f);
            lerp4(tv, f, xv, a0, a1, a2, a3);
        }

        unsigned p01 = (unsigned)f2bf(a0 + b0) | ((unsigned)f2bf(a1 + b1) << 16);
        unsigned p23 = (unsigned)f2bf(a2 + b2) | ((unsigned)f2bf(a3 + b3) << 16);
        const int row = wv * 2 + half;
        *(unsigned*)&A1[row * 136 + c4]     = p01;
        *(unsigned*)&A1[row * 136 + c4 + 2] = p23;
    }
    __syncthreads();

    const int m = lane & 15, q = lane >> 4;

    // ---- stage 1: t = ssp(agg @ lin2_w + lin2_b) -> A2 ----
    {
        f32x4 acc = {0.f, 0.f, 0.f, 0.f};
        #pragma unroll
        for (int ks = 0; ks < 4; ++ks) {
            short8_t a = *(const short8_t*)(A1 + m * 136 + ks * 32 + q * 8);
            short8_t b = *(const short8_t*)(w2p + (wv * 4 + ks) * 512 + lane * 8);
            acc = __builtin_amdgcn_mfma_f32_16x16x32_bf16(a, b, acc, 0, 0, 0);
        }
        float bv = lin2_b[wv * 16 + m];
        #pragma unroll
        for (int i = 0; i < 4; ++i) {
            int r = q * 4 + i;
            A2[r * 136 + wv * 16 + m] = (short)f2bf(ssp_f(acc[i] + bv));
        }
    }
    __syncthreads();

    // ---- stage 2: h_new = h + t @ lin_w + lin_b -> A1 (+ global h if !LAST) ----
    {
        f32x4 acc = {0.f, 0.f, 0.f, 0.f};
        #pragma unroll
        for (int ks = 0; ks < 4; ++ks) {
            short8_t a = *(const short8_t*)(A2 + m * 136 + ks * 32 + q * 8);
            short8_t b = *(const short8_t*)(wlp + (wv * 4 + ks) * 512 + lane * 8);
            acc = __builtin_amdgcn_mfma_f32_16x16x32_bf16(a, b, acc, 0, 0, 0);
        }
        float bv = lin_b[wv * 16 + m];
        #pragma unroll
        for (int i = 0; i < 4; ++i) {
            int r = q * 4 + i;
            int grow = n0 + r;
            float h0 = h[(size_t)grow * 128 + wv * 16 + m];
            float hn = h0 + acc[i] + bv;
            if (!LAST) h[(size_t)grow * 128 + wv * 16 + m] = hn;
            A1[r * 136 + wv * 16 + m] = (short)f2bf(hn);
        }
    }
    __syncthreads();

    if constexpr (!LAST) {
        // ---- stage 3: xf_out = bf16(h_new @ lin1_next) ----
        f32x4 acc = {0.f, 0.f, 0.f, 0.f};
        #pragma unroll
        for (int ks = 0; ks < 4; ++ks) {
            short8_t a = *(const short8_t*)(A1 + m * 136 + ks * 32 + q * 8);
            short8_t b = *(const short8_t*)(w1p + (wv * 4 + ks) * 512 + lane * 8);
            acc = __builtin_amdgcn_mfma_f32_16x16x32_bf16(a, b, acc, 0, 0, 0);
        }
        #pragma unroll
        for (int i = 0; i < 4; ++i) {
            int r = q * 4 + i;
            int grow = n0 + r;
            xf_out[(size_t)grow * 128 + wv * 16 + m] = f2bf(acc[i]);
        }
    } else {
        // ---- fused head: waves 0-3 compute o1/o2 col-tiles; colsum -> gs ----
        if (wv < 4) {
            f32x4 acc = {0.f, 0.f, 0.f, 0.f};
            #pragma unroll
            for (int ks = 0; ks < 4; ++ks) {
                short8_t a = *(const short8_t*)(A1 + m * 136 + ks * 32 + q * 8);
                short8_t b = *(const short8_t*)(o1p + (wv * 4 + ks) * 512 + lane * 8);
                acc = __builtin_amdgcn_mfma_f32_16x16x32_bf16(a, b, acc, 0, 0, 0);
            }
            float bv = o1b[wv * 16 + m];
            #pragma unroll
            for (int i = 0; i < 4; ++i) {
                int r = q * 4 + i;
                A2[r * 136 + wv * 16 + m] = (short)f2bf(ssp_f(acc[i] + bv));
            }
        }
        __syncthreads();
        if (wv < 4) {
            f32x4 acc = {0.f, 0.f, 0.f, 0.f};
            #pragma unroll
            for (int ks = 0; ks < 2; ++ks) {
                short8_t a = *(const short8_t*)(A2 + m * 136 + ks * 32 + q * 8);
                short8_t b = *(const short8_t*)(o2p + (wv * 2 + ks) * 512 + lane * 8);
                acc = __builtin_amdgcn_mfma_f32_16x16x32_bf16(a, b, acc, 0, 0, 0);
            }
            float bv = o2b[wv * 16 + m];
            float part = acc[0] + acc[1] + acc[2] + acc[3] + 4.0f * bv;
            red[q][wv * 16 + m] = part;
        }
        __syncthreads();
        if (tid < 64) {
            float s = red[0][tid] + red[1][tid] + red[2][tid] + red[3][tid];
            atomicAdd(&gs[tid], s);
        }
    }
}

// out[i] = ro_b[i] + sum_k gs[k] * ro_w[k][i]
__global__ void final_kernel(const float* __restrict__ gs,
                             const float* __restrict__ ro_w,
                             const float* __restrict__ ro_b,
                             float* __restrict__ out) {
    int i = threadIdx.x;
    if (i < 12) {
        float s = ro_b[i];
        for (int k = 0; k < 64; ++k) s = fmaf(gs[k], ro_w[k * 12 + i], s);
        out[i] = s;
    }
}

// ---------------------------------------------------------------------------
extern "C" void kernel_launch(void* const* d_in, const int* in_sizes, int n_in,
                              void* d_out, int out_size, void* d_ws, size_t ws_size,
                              hipStream_t stream) {
    const int*   x      = (const int*)d_in[0];
    const int*   ei     = (const int*)d_in[1];
    const float* dist   = (const float*)d_in[2];
    const float* emb    = (const float*)d_in[3];
    const float* mlp_w1 = (const float*)d_in[4];
    const float* mlp_b1 = (const float*)d_in[5];
    const float* mlp_w2 = (const float*)d_in[6];
    const float* mlp_b2 = (const float*)d_in[7];
    const float* lin1_w = (const float*)d_in[8];
    const float* lin2_w = (const float*)d_in[9];
    const float* lin2_b = (const float*)d_in[10];
    const float* lin_w  = (const float*)d_in[11];
    const float* lin_b  = (const float*)d_in[12];
    const float* out1_w = (const float*)d_in[13];
    const float* out1_b = (const float*)d_in[14];
    const float* out2_w = (const float*)d_in[15];
    const float* out2_b = (const float*)d_in[16];
    const float* ro_w   = (const float*)d_in[17];
    const float* ro_b   = (const float*)d_in[18];
    float* out = (float*)d_out;

    // workspace layout
    char* base = (char*)d_ws;
    float*    h     = (float*)base;     base += (size_t)N_NUM * 128 * 4;
    ushort_t* tabB  = (ushort_t*)base;  base += (size_t)6 * TAB * 256 * 2;
    ushort_t* xf0   = (ushort_t*)base;  base += (size_t)N_NUM * 128 * 2;
    ushort_t* xf1   = (ushort_t*)base;  base += (size_t)N_NUM * 128 * 2;
    int2*     meta  = (int2*)base;      base += (size_t)E_NUM * 8;
    short*    wpack = (short*)base;     base += (size_t)WP_TOT * 2;
    float*    gs    = (float*)base;     base += 64 * 4;
    int*      offs  = (int*)base;       base += (N_NUM + 1) * 4;
    int*      cursor= (int*)base;       base += N_NUM * 4;
    int*      counts= (int*)base;       base += N_NUM * 4;

    hipMemsetAsync(counts, 0, N_NUM * sizeof(int), stream);
    hipMemsetAsync(gs, 0, 64 * sizeof(float), stream);

    // sort edges by dst (once; dst constant across layers)
    hist_kernel<<<(E_NUM + 255) / 256, 256, 0, stream>>>(ei, counts);
    scan_kernel<<<1, 256, 0, stream>>>(counts, offs, cursor);
    scatter_kernel<<<(E_NUM + 255) / 256, 256, 0, stream>>>(ei, dist, cursor, meta);

    // pack all weights (MFMA B-frag bf16), then build filter tables via MFMA
    pack_kernel<<<(WP_TOT + 255) / 256, 256, 0, stream>>>(
        lin2_w, lin_w, lin1_w, out1_w, out2_w, mlp_w1, mlp_w2, wpack);
    table_kernel<<<6 * (TAB / 16), 512, 0, stream>>>(
        wpack + WP_W1T, mlp_b1, wpack + WP_W2T, mlp_b2, tabB);

    // layer 0 front: h = emb[x], xf0 = bf16(h @ lin1_w[0])
    embed_lin1_kernel<<<NB8, 256, 0, stream>>>(x, emb, lin1_w, h, xf0);

    const short* o1p = wpack + WP_O1;
    const short* o2p = wpack + WP_O2;

    for (int l = 0; l < 6; ++l) {
        ushort_t* xin  = (l & 1) ? xf1 : xf0;
        ushort_t* xout = (l & 1) ? xf0 : xf1;
        const ushort_t* tl = tabB + (size_t)l * TAB * 256;
        const short* w2p = wpack + l * 16384;
        const short* wlp = wpack + (6 + l) * 16384;
        if (l < 5) {
            const short* w1p = wpack + (12 + l + 1) * 16384;   // lin1_w[l+1]
            layer_kernel<false><<<NB16, 512, 0, stream>>>(
                offs, meta, xin, tl,
                w2p, lin2_b + l * 128, wlp, lin_b + l * 128, w1p,
                h, xout, nullptr, nullptr, nullptr, nullptr, nullptr);
        } else {
            layer_kernel<true><<<NB16, 512, 0, stream>>>(
                offs, meta, xin, tl,
                w2p, lin2_b + l * 128, wlp, lin_b + l * 128, nullptr,
                h, nullptr, o1p, out1_b, o2p, out2_b, gs);
        }
    }

    final_kernel<<<1, 64, 0, stream>>>(gs, ro_w, ro_b, out);
}

// Round 10
// 352.457 us; speedup vs baseline: 2.4500x; 1.0345x over previous
//
#include <hip/hip_runtime.h>
#include <math.h>

#define E_NUM 320000
#define N_NUM 10000
#define NB8   (N_NUM / 8)           // 1250 blocks (embed)
#define NB16  (N_NUM / 16)          // 625 blocks (layer)
#define TAB   4096

typedef unsigned short ushort_t;
typedef short short8_t __attribute__((ext_vector_type(8)));   // 8 bf16 (4 VGPRs)
typedef float f32x4    __attribute__((ext_vector_type(4)));   // MFMA acc

// wpack layout (shorts):
//   [0)        6x lin2_w  128x128
//   [98304)    6x lin_w   128x128
//   [196608)   6x lin1_w  128x128
//   [294912)   o1w 128x64
//   [303104)   o2w 64x64
//   [307200)   6x mlp_w1  (K=64 zero-padded)x128  -> 8192 each
//   [356352)   6x mlp_w2  128x128                 -> 16384 each
#define WP_O1   294912
#define WP_O2   303104
#define WP_W1T  307200
#define WP_W2T  356352
#define WP_TOT  454656

__device__ __forceinline__ float ssp_f(float x) {
    return fmaxf(x, 0.f) + __logf(1.f + __expf(-fabsf(x))) - 0.69314718056f;
}

__device__ __forceinline__ float bf2f(ushort_t u) {
    union { unsigned int i; float f; } v;
    v.i = ((unsigned int)u) << 16;
    return v.f;
}
__device__ __forceinline__ ushort_t f2bf(float f) {
    union { float f; unsigned int i; } v;
    v.f = f;
    unsigned int u = v.i;
    unsigned int r = (u + 0x7FFFu + ((u >> 16) & 1u)) >> 16;   // RNE
    return (ushort_t)r;
}

// ---------------------------------------------------------------------------
// counting-sort phase 1: histogram of dst
__global__ __launch_bounds__(256) void hist_kernel(const int* __restrict__ ei,
                                                   int* __restrict__ counts) {
    int e = blockIdx.x * 256 + threadIdx.x;
    if (e < E_NUM) atomicAdd(&counts[ei[E_NUM + e]], 1);
}

// phase 2: exclusive scan over 10000 bins (single block)
__global__ __launch_bounds__(256) void scan_kernel(const int* __restrict__ counts,
                                                   int* __restrict__ offs,
                                                   int* __restrict__ cursor) {
    __shared__ int part[256];
    const int tid = threadIdx.x;
    const int CH = 40;
    int base = tid * CH;
    int s = 0;
    for (int i = 0; i < CH; ++i) {
        int idx = base + i;
        if (idx < N_NUM) s += counts[idx];
    }
    part[tid] = s;
    __syncthreads();
    for (int off = 1; off < 256; off <<= 1) {
        int v = (tid >= off) ? part[tid - off] : 0;
        __syncthreads();
        part[tid] += v;
        __syncthreads();
    }
    int run = (tid > 0) ? part[tid - 1] : 0;
    for (int i = 0; i < CH; ++i) {
        int idx = base + i;
        if (idx < N_NUM) {
            offs[idx] = run;
            cursor[idx] = run;
            run += counts[idx];
        }
    }
    if (tid == 255) offs[N_NUM] = part[255];
}

// phase 3: scatter edges to dst-sorted order.
// meta = (i0 << 14) | src ; i0 = nearest table row (12 bits), src 14 bits.
__global__ __launch_bounds__(256) void scatter_kernel(const int* __restrict__ ei,
                                                      const float* __restrict__ dist,
                                                      int* __restrict__ cursor,
                                                      int* __restrict__ meta) {
    int e = blockIdx.x * 256 + threadIdx.x;
    if (e >= E_NUM) return;
    int d = ei[E_NUM + e];
    int pos = atomicAdd(&cursor[d], 1);
    float t = dist[e] * ((float)(TAB - 1) / 10.0f);
    int i0 = (int)(t + 0.5f);
    if (i0 > TAB - 1) i0 = TAB - 1;
    meta[pos] = (i0 << 14) | ei[e];
}

// ---------------------------------------------------------------------------
// Pack all weights into MFMA B-fragment order (bf16).
// B-frag: idx = ((t*KSP + ks)*64 + L)*8 + j ; n = t*16+(L&15), k = ks*32+(L>>4)*8+j
__global__ __launch_bounds__(256) void pack_kernel(const float* __restrict__ lin2_w,
                                                   const float* __restrict__ lin_w,
                                                   const float* __restrict__ lin1_w,
                                                   const float* __restrict__ o1w,
                                                   const float* __restrict__ o2w,
                                                   const float* __restrict__ mlp_w1,
                                                   const float* __restrict__ mlp_w2,
                                                   short* __restrict__ wpack) {
    int idx = blockIdx.x * 256 + threadIdx.x;
    const int M128 = 16384;
    if (idx < 18 * M128) {
        int g = idx / M128, r = idx % M128;
        const float* src;
        if (g < 6) src = lin2_w + g * M128;
        else if (g < 12) src = lin_w + (g - 6) * M128;
        else src = lin1_w + (g - 12) * M128;
        int j = r & 7, L = (r >> 3) & 63, ks = (r >> 9) & 3, t = r >> 11;
        int n = t * 16 + (L & 15);
        int k = ks * 32 + (L >> 4) * 8 + j;
        wpack[idx] = (short)f2bf(src[k * 128 + n]);
    } else if (idx < WP_O2) {
        int r = idx - WP_O1;              // o1w: K=128, N=64
        int j = r & 7, L = (r >> 3) & 63, ks = (r >> 9) & 3, t = r >> 11;
        int n = t * 16 + (L & 15);
        int k = ks * 32 + (L >> 4) * 8 + j;
        wpack[idx] = (short)f2bf(o1w[k * 64 + n]);
    } else if (idx < WP_W1T) {
        int r = idx - WP_O2;              // o2w: K=64, N=64
        int j = r & 7, L = (r >> 3) & 63, ks = (r >> 9) & 1, t = r >> 10;
        int n = t * 16 + (L & 15);
        int k = ks * 32 + (L >> 4) * 8 + j;
        wpack[idx] = (short)f2bf(o2w[k * 64 + n]);
    } else if (idx < WP_W2T) {
        int r2 = idx - WP_W1T;            // mlp_w1: K=50 pad to 64, N=128
        int g = r2 / 8192, r = r2 % 8192;
        int j = r & 7, L = (r >> 3) & 63, ks = (r >> 9) & 1, t = r >> 10;
        int n = t * 16 + (L & 15);
        int k = ks * 32 + (L >> 4) * 8 + j;
        float v = (k < 50) ? mlp_w1[g * 6400 + k * 128 + n] : 0.f;
        wpack[idx] = (short)f2bf(v);
    } else if (idx < WP_TOT) {
        int r2 = idx - WP_W2T;            // mlp_w2: K=128, N=128
        int g = r2 / M128, r = r2 % M128;
        int j = r & 7, L = (r >> 3) & 63, ks = (r >> 9) & 3, t = r >> 11;
        int n = t * 16 + (L & 15);
        int k = ks * 32 + (L >> 4) * 8 + j;
        wpack[idx] = (short)f2bf(mlp_w2[g * M128 + k * 128 + n]);
    }
}

// ---------------------------------------------------------------------------
// MFMA table build: plain row layout tab[l][i][c] (bf16), nearest-neighbor use.
// 16 d-rows/block, 512 threads, 6*(TAB/16) = 1536 blocks.
__global__ __launch_bounds__(512) void table_kernel(const short* __restrict__ w1t,
                                                    const float* __restrict__ mlp_b1,
                                                    const short* __restrict__ w2t,
                                                    const float* __restrict__ mlp_b2,
                                                    ushort_t* __restrict__ tabB) {
    __shared__ short EA[16 * 72];    // bf16 gaussians, K padded to 64
    __shared__ short HD[16 * 136];   // bf16 hidden
    const int tid = threadIdx.x;
    const int wv = tid >> 6;
    const int lane = tid & 63;
    const int l = blockIdx.x >> 8;              // / (TAB/16 = 256)
    const int r0 = (blockIdx.x & 255) * 16;
    const float DG = 10.0f / (float)(TAB - 1);
    const float STEP = 10.0f / 49.0f;
    const float COEFF = -0.5f / (STEP * STEP);

    for (int i = tid; i < 16 * 64; i += 512) {
        int r = i >> 6, k = i & 63;
        float v = 0.f;
        if (k < 50) {
            float d = (float)(r0 + r) * DG;
            float t = d - (float)k * STEP;
            v = __expf(COEFF * t * t);
        }
        EA[r * 72 + k] = (short)f2bf(v);
    }
    __syncthreads();

    const int m = lane & 15, q = lane >> 4;

    // stage 1: hidden = ssp(ea @ w1 + b1), K=64 (padded)
    {
        f32x4 acc = {0.f, 0.f, 0.f, 0.f};
        #pragma unroll
        for (int ks = 0; ks < 2; ++ks) {
            short8_t a = *(const short8_t*)(EA + m * 72 + ks * 32 + q * 8);
            short8_t b = *(const short8_t*)(w1t + l * 8192 + (wv * 2 + ks) * 512 + lane * 8);
            acc = __builtin_amdgcn_mfma_f32_16x16x32_bf16(a, b, acc, 0, 0, 0);
        }
        float bv = mlp_b1[l * 128 + wv * 16 + m];
        #pragma unroll
        for (int i = 0; i < 4; ++i)
            HD[(q * 4 + i) * 136 + wv * 16 + m] = (short)f2bf(ssp_f(acc[i] + bv));
    }
    __syncthreads();

    // stage 2: W = hidden @ w2 + b2, *C(d), plain row write
    {
        f32x4 acc = {0.f, 0.f, 0.f, 0.f};
        #pragma unroll
        for (int ks = 0; ks < 4; ++ks) {
            short8_t a = *(const short8_t*)(HD + m * 136 + ks * 32 + q * 8);
            short8_t b = *(const short8_t*)(w2t + l * 16384 + (wv * 4 + ks) * 512 + lane * 8);
            acc = __builtin_amdgcn_mfma_f32_16x16x32_bf16(a, b, acc, 0, 0, 0);
        }
        int col = wv * 16 + m;
        float bv = mlp_b2[l * 128 + col];
        ushort_t* tl = tabB + (size_t)l * TAB * 128;
        #pragma unroll
        for (int i = 0; i < 4; ++i) {
            int row = r0 + q * 4 + i;
            float d = (float)row * DG;
            float C = 0.5f * (__cosf(d * 0.31415926535f) + 1.0f);
            tl[(size_t)row * 128 + col] = f2bf((acc[i] + bv) * C);
        }
    }
}

// ---------------------------------------------------------------------------
// nearest-neighbor accumulate: 4 cols/lane, one edge
__device__ __forceinline__ void nacc(ushort4 x, ushort4 t,
                                     float& o0, float& o1, float& o2, float& o3) {
    o0 = fmaf(bf2f(x.x), bf2f(t.x), o0);
    o1 = fmaf(bf2f(x.y), bf2f(t.y), o1);
    o2 = fmaf(bf2f(x.z), bf2f(t.z), o2);
    o3 = fmaf(bf2f(x.w), bf2f(t.w), o3);
}

// ---------------------------------------------------------------------------
// Layer 0 front: h = emb[x]; xf = bf16(h @ lin1_w[0]).  8 rows/block, 256 thr.
__global__ __launch_bounds__(256) void embed_lin1_kernel(const int* __restrict__ x,
                                                         const float* __restrict__ emb,
                                                         const float* __restrict__ B,
                                                         float* __restrict__ h,
                                                         ushort_t* __restrict__ xf) {
    __shared__ float AT[128][9];
    __shared__ int s_x[8];
    const int tid = threadIdx.x;
    const int n0 = blockIdx.x * 8;

    if (tid < 8) s_x[tid] = x[n0 + tid];
    __syncthreads();
    for (int i = tid; i < 8 * 128; i += 256) {
        int r = i >> 7, c = i & 127;
        float v = emb[s_x[r] * 128 + c];
        AT[c][r] = v;
        h[(size_t)(n0 + r) * 128 + c] = v;
    }
    __syncthreads();

    const int r  = tid & 7;
    const int c0 = (tid >> 3) * 4;
    float acc[4] = {0.f, 0.f, 0.f, 0.f};
    for (int k = 0; k < 128; k += 4) {
        float a[4];
        #pragma unroll
        for (int u = 0; u < 4; ++u) a[u] = AT[k + u][r];
        #pragma unroll
        for (int u = 0; u < 4; ++u) {
            float4 b = *(const float4*)(B + (size_t)(k + u) * 128 + c0);
            acc[0] = fmaf(a[u], b.x, acc[0]);
            acc[1] = fmaf(a[u], b.y, acc[1]);
            acc[2] = fmaf(a[u], b.z, acc[2]);
            acc[3] = fmaf(a[u], b.w, acc[3]);
        }
    }
    ushort4 o;
    o.x = f2bf(acc[0]); o.y = f2bf(acc[1]); o.z = f2bf(acc[2]); o.w = f2bf(acc[3]);
    *(ushort4*)(xf + (size_t)(n0 + r) * 128 + c0) = o;
}

// ---------------------------------------------------------------------------
// Fused MFMA layer kernel: 16 nodes/block, 512 threads (8 waves).
// phase A: half-wave edge streams, nearest-neighbor table, 8-edge groups.
// MFMA stages: wave wv computes the 16-col tile t = wv.
template <bool LAST>
__global__ __launch_bounds__(512) void layer_kernel(const int* __restrict__ offs,
                                                    const int* __restrict__ meta,
                                                    const ushort_t* __restrict__ xf,
                                                    const ushort_t* __restrict__ tabB,
                                                    const short* __restrict__ w2p,
                                                    const float* __restrict__ lin2_b,
                                                    const short* __restrict__ wlp,
                                                    const float* __restrict__ lin_b,
                                                    const short* __restrict__ w1p,
                                                    float* __restrict__ h,
                                                    ushort_t* __restrict__ xf_out,
                                                    const short* __restrict__ o1p,
                                                    const float* __restrict__ o1b,
                                                    const short* __restrict__ o2p,
                                                    const float* __restrict__ o2b,
                                                    float* __restrict__ gs) {
    __shared__ short A1[16 * 136];   // bf16, row stride 136 shorts (272 B)
    __shared__ short A2[16 * 136];
    __shared__ float red[4][64];
    const int tid = threadIdx.x;
    const int n0 = blockIdx.x * 16;
    const int wv = tid >> 6;         // 0..7
    const int lane = tid & 63;

    // ---- phase A: half-wave edge streams, nearest table row ----
    {
        const int half = lane >> 5;
        const int c4 = (lane & 31) * 4;
        const int node = n0 + wv * 2 + half;
        int e   = offs[node];
        int end = offs[node + 1];

        float a0 = 0.f, a1 = 0.f, a2 = 0.f, a3 = 0.f;
        float b0 = 0.f, b1 = 0.f, b2 = 0.f, b3 = 0.f;

        for (; e + 8 <= end; e += 8) {
            int m[8];
            #pragma unroll
            for (int u = 0; u < 8; ++u) m[u] = meta[e + u];
            ushort4 xv[8], tv[8];
            #pragma unroll
            for (int u = 0; u < 8; ++u) {
                xv[u] = *(const ushort4*)(xf + (size_t)(m[u] & 0x3FFF) * 128 + c4);
                tv[u] = *(const ushort4*)(tabB + (size_t)((unsigned)m[u] >> 14) * 128 + c4);
            }
            nacc(xv[0], tv[0], a0, a1, a2, a3);
            nacc(xv[1], tv[1], b0, b1, b2, b3);
            nacc(xv[2], tv[2], a0, a1, a2, a3);
            nacc(xv[3], tv[3], b0, b1, b2, b3);
            nacc(xv[4], tv[4], a0, a1, a2, a3);
            nacc(xv[5], tv[5], b0, b1, b2, b3);
            nacc(xv[6], tv[6], a0, a1, a2, a3);
            nacc(xv[7], tv[7], b0, b1, b2, b3);
        }
        for (; e + 4 <= end; e += 4) {
            int m[4];
            #pragma unroll
            for (int u = 0; u < 4; ++u) m[u] = meta[e + u];
            ushort4 xv[4], tv[4];
            #pragma unroll
            for (int u = 0; u < 4; ++u) {
                xv[u] = *(const ushort4*)(xf + (size_t)(m[u] & 0x3FFF) * 128 + c4);
                tv[u] = *(const ushort4*)(tabB + (size_t)((unsigned)m[u] >> 14) * 128 + c4);
            }
            nacc(xv[0], tv[0], a0, a1, a2, a3);
            nacc(xv[1], tv[1], b0, b1, b2, b3);
            nacc(xv[2], tv[2], a0, a1, a2, a3);
            nacc(xv[3], tv[3], b0, b1, b2, b3);
        }
        for (; e < end; ++e) {
            int mm = meta[e];
            ushort4 xv = *(const ushort4*)(xf + (size_t)(mm & 0x3FFF) * 128 + c4);
            ushort4 tv = *(const ushort4*)(tabB + (size_t)((unsigned)mm >> 14) * 128 + c4);
            nacc(xv, tv, a0, a1, a2, a3);
        }

        unsigned p01 = (unsigned)f2bf(a0 + b0) | ((unsigned)f2bf(a1 + b1) << 16);
        unsigned p23 = (unsigned)f2bf(a2 + b2) | ((unsigned)f2bf(a3 + b3) << 16);
        const int row = wv * 2 + half;
        *(unsigned*)&A1[row * 136 + c4]     = p01;
        *(unsigned*)&A1[row * 136 + c4 + 2] = p23;
    }
    __syncthreads();

    const int m = lane & 15, q = lane >> 4;

    // ---- stage 1: t = ssp(agg @ lin2_w + lin2_b) -> A2 ----
    {
        f32x4 acc = {0.f, 0.f, 0.f, 0.f};
        #pragma unroll
        for (int ks = 0; ks < 4; ++ks) {
            short8_t a = *(const short8_t*)(A1 + m * 136 + ks * 32 + q * 8);
            short8_t b = *(const short8_t*)(w2p + (wv * 4 + ks) * 512 + lane * 8);
            acc = __builtin_amdgcn_mfma_f32_16x16x32_bf16(a, b, acc, 0, 0, 0);
        }
        float bv = lin2_b[wv * 16 + m];
        #pragma unroll
        for (int i = 0; i < 4; ++i) {
            int r = q * 4 + i;
            A2[r * 136 + wv * 16 + m] = (short)f2bf(ssp_f(acc[i] + bv));
        }
    }
    __syncthreads();

    // ---- stage 2: h_new = h + t @ lin_w + lin_b -> A1 (+ global h if !LAST) ----
    {
        f32x4 acc = {0.f, 0.f, 0.f, 0.f};
        #pragma unroll
        for (int ks = 0; ks < 4; ++ks) {
            short8_t a = *(const short8_t*)(A2 + m * 136 + ks * 32 + q * 8);
            short8_t b = *(const short8_t*)(wlp + (wv * 4 + ks) * 512 + lane * 8);
            acc = __builtin_amdgcn_mfma_f32_16x16x32_bf16(a, b, acc, 0, 0, 0);
        }
        float bv = lin_b[wv * 16 + m];
        #pragma unroll
        for (int i = 0; i < 4; ++i) {
            int r = q * 4 + i;
            int grow = n0 + r;
            float h0 = h[(size_t)grow * 128 + wv * 16 + m];
            float hn = h0 + acc[i] + bv;
            if (!LAST) h[(size_t)grow * 128 + wv * 16 + m] = hn;
            A1[r * 136 + wv * 16 + m] = (short)f2bf(hn);
        }
    }
    __syncthreads();

    if constexpr (!LAST) {
        // ---- stage 3: xf_out = bf16(h_new @ lin1_next) ----
        f32x4 acc = {0.f, 0.f, 0.f, 0.f};
        #pragma unroll
        for (int ks = 0; ks < 4; ++ks) {
            short8_t a = *(const short8_t*)(A1 + m * 136 + ks * 32 + q * 8);
            short8_t b = *(const short8_t*)(w1p + (wv * 4 + ks) * 512 + lane * 8);
            acc = __builtin_amdgcn_mfma_f32_16x16x32_bf16(a, b, acc, 0, 0, 0);
        }
        #pragma unroll
        for (int i = 0; i < 4; ++i) {
            int r = q * 4 + i;
            int grow = n0 + r;
            xf_out[(size_t)grow * 128 + wv * 16 + m] = f2bf(acc[i]);
        }
    } else {
        // ---- fused head: waves 0-3 compute o1/o2 col-tiles; colsum -> gs ----
        if (wv < 4) {
            f32x4 acc = {0.f, 0.f, 0.f, 0.f};
            #pragma unroll
            for (int ks = 0; ks < 4; ++ks) {
                short8_t a = *(const short8_t*)(A1 + m * 136 + ks * 32 + q * 8);
                short8_t b = *(const short8_t*)(o1p + (wv * 4 + ks) * 512 + lane * 8);
                acc = __builtin_amdgcn_mfma_f32_16x16x32_bf16(a, b, acc, 0, 0, 0);
            }
            float bv = o1b[wv * 16 + m];
            #pragma unroll
            for (int i = 0; i < 4; ++i) {
                int r = q * 4 + i;
                A2[r * 136 + wv * 16 + m] = (short)f2bf(ssp_f(acc[i] + bv));
            }
        }
        __syncthreads();
        if (wv < 4) {
            f32x4 acc = {0.f, 0.f, 0.f, 0.f};
            #pragma unroll
            for (int ks = 0; ks < 2; ++ks) {
                short8_t a = *(const short8_t*)(A2 + m * 136 + ks * 32 + q * 8);
                short8_t b = *(const short8_t*)(o2p + (wv * 2 + ks) * 512 + lane * 8);
                acc = __builtin_amdgcn_mfma_f32_16x16x32_bf16(a, b, acc, 0, 0, 0);
            }
            float bv = o2b[wv * 16 + m];
            float part = acc[0] + acc[1] + acc[2] + acc[3] + 4.0f * bv;
            red[q][wv * 16 + m] = part;
        }
        __syncthreads();
        if (tid < 64) {
            float s = red[0][tid] + red[1][tid] + red[2][tid] + red[3][tid];
            atomicAdd(&gs[tid], s);
        }
    }
}

// out[i] = ro_b[i] + sum_k gs[k] * ro_w[k][i]
__global__ void final_kernel(const float* __restrict__ gs,
                             const float* __restrict__ ro_w,
                             const float* __restrict__ ro_b,
                             float* __restrict__ out) {
    int i = threadIdx.x;
    if (i < 12) {
        float s = ro_b[i];
        for (int k = 0; k < 64; ++k) s = fmaf(gs[k], ro_w[k * 12 + i], s);
        out[i] = s;
    }
}

// ---------------------------------------------------------------------------
extern "C" void kernel_launch(void* const* d_in, const int* in_sizes, int n_in,
                              void* d_out, int out_size, void* d_ws, size_t ws_size,
                              hipStream_t stream) {
    const int*   x      = (const int*)d_in[0];
    const int*   ei     = (const int*)d_in[1];
    const float* dist   = (const float*)d_in[2];
    const float* emb    = (const float*)d_in[3];
    const float* mlp_w1 = (const float*)d_in[4];
    const float* mlp_b1 = (const float*)d_in[5];
    const float* mlp_w2 = (const float*)d_in[6];
    const float* mlp_b2 = (const float*)d_in[7];
    const float* lin1_w = (const float*)d_in[8];
    const float* lin2_w = (const float*)d_in[9];
    const float* lin2_b = (const float*)d_in[10];
    const float* lin_w  = (const float*)d_in[11];
    const float* lin_b  = (const float*)d_in[12];
    const float* out1_w = (const float*)d_in[13];
    const float* out1_b = (const float*)d_in[14];
    const float* out2_w = (const float*)d_in[15];
    const float* out2_b = (const float*)d_in[16];
    const float* ro_w   = (const float*)d_in[17];
    const float* ro_b   = (const float*)d_in[18];
    float* out = (float*)d_out;

    // workspace layout
    char* base = (char*)d_ws;
    float*    h     = (float*)base;     base += (size_t)N_NUM * 128 * 4;
    ushort_t* tabB  = (ushort_t*)base;  base += (size_t)6 * TAB * 128 * 2;
    ushort_t* xf0   = (ushort_t*)base;  base += (size_t)N_NUM * 128 * 2;
    ushort_t* xf1   = (ushort_t*)base;  base += (size_t)N_NUM * 128 * 2;
    int*      meta  = (int*)base;       base += (size_t)E_NUM * 4;
    short*    wpack = (short*)base;     base += (size_t)WP_TOT * 2;
    float*    gs    = (float*)base;     base += 64 * 4;
    int*      offs  = (int*)base;       base += (N_NUM + 1) * 4;
    int*      cursor= (int*)base;       base += N_NUM * 4;
    int*      counts= (int*)base;       base += N_NUM * 4;

    hipMemsetAsync(counts, 0, N_NUM * sizeof(int), stream);
    hipMemsetAsync(gs, 0, 64 * sizeof(float), stream);

    // sort edges by dst (once; dst constant across layers)
    hist_kernel<<<(E_NUM + 255) / 256, 256, 0, stream>>>(ei, counts);
    scan_kernel<<<1, 256, 0, stream>>>(counts, offs, cursor);
    scatter_kernel<<<(E_NUM + 255) / 256, 256, 0, stream>>>(ei, dist, cursor, meta);

    // pack all weights (MFMA B-frag bf16), then build filter tables via MFMA
    pack_kernel<<<(WP_TOT + 255) / 256, 256, 0, stream>>>(
        lin2_w, lin_w, lin1_w, out1_w, out2_w, mlp_w1, mlp_w2, wpack);
    table_kernel<<<6 * (TAB / 16), 512, 0, stream>>>(
        wpack + WP_W1T, mlp_b1, wpack + WP_W2T, mlp_b2, tabB);

    // layer 0 front: h = emb[x], xf0 = bf16(h @ lin1_w[0])
    embed_lin1_kernel<<<NB8, 256, 0, stream>>>(x, emb, lin1_w, h, xf0);

    const short* o1p = wpack + WP_O1;
    const short* o2p = wpack + WP_O2;

    for (int l = 0; l < 6; ++l) {
        ushort_t* xin  = (l & 1) ? xf1 : xf0;
        ushort_t* xout = (l & 1) ? xf0 : xf1;
        const ushort_t* tl = tabB + (size_t)l * TAB * 128;
        const short* w2p = wpack + l * 16384;
        const short* wlp = wpack + (6 + l) * 16384;
        if (l < 5) {
            const short* w1p = wpack + (12 + l + 1) * 16384;   // lin1_w[l+1]
            layer_kernel<false><<<NB16, 512, 0, stream>>>(
                offs, meta, xin, tl,
                w2p, lin2_b + l * 128, wlp, lin_b + l * 128, w1p,
                h, xout, nullptr, nullptr, nullptr, nullptr, nullptr);
        } else {
            layer_kernel<true><<<NB16, 512, 0, stream>>>(
                offs, meta, xin, tl,
                w2p, lin2_b + l * 128, wlp, lin_b + l * 128, nullptr,
                h, nullptr, o1p, out1_b, o2p, out2_b, gs);
        }
    }

    final_kernel<<<1, 64, 0, stream>>>(gs, ro_w, ro_b, out);
}

// Round 11
// 320.690 us; speedup vs baseline: 2.6927x; 1.0991x over previous
//
#include <hip/hip_runtime.h>
#include <math.h>

#define E_NUM 320000
#define N_NUM 10000
#define NB8   (N_NUM / 8)           // 1250 blocks (embed)
#define NB16  (N_NUM / 16)          // 625 blocks (layer)
#define TAB   2048

typedef unsigned short ushort_t;
typedef short short8_t __attribute__((ext_vector_type(8)));   // 8 bf16 (4 VGPRs)
typedef float f32x4    __attribute__((ext_vector_type(4)));   // MFMA acc

// wpack layout (shorts):
//   [0)        6x lin2_w  128x128
//   [98304)    6x lin_w   128x128
//   [196608)   6x lin1_w  128x128
//   [294912)   o1w 128x64
//   [303104)   o2w 64x64
//   [307200)   6x mlp_w1  (K=64 zero-padded)x128  -> 8192 each
//   [356352)   6x mlp_w2  128x128                 -> 16384 each
#define WP_O1   294912
#define WP_O2   303104
#define WP_W1T  307200
#define WP_W2T  356352
#define WP_TOT  454656

__device__ __forceinline__ float ssp_f(float x) {
    return fmaxf(x, 0.f) + __logf(1.f + __expf(-fabsf(x))) - 0.69314718056f;
}

__device__ __forceinline__ float bf2f(ushort_t u) {
    union { unsigned int i; float f; } v;
    v.i = ((unsigned int)u) << 16;
    return v.f;
}
__device__ __forceinline__ ushort_t f2bf(float f) {
    union { float f; unsigned int i; } v;
    v.f = f;
    unsigned int u = v.i;
    unsigned int r = (u + 0x7FFFu + ((u >> 16) & 1u)) >> 16;   // RNE
    return (ushort_t)r;
}

// ---------------------------------------------------------------------------
// counting-sort phase 1: histogram of dst
__global__ __launch_bounds__(256) void hist_kernel(const int* __restrict__ ei,
                                                   int* __restrict__ counts) {
    int e = blockIdx.x * 256 + threadIdx.x;
    if (e < E_NUM) atomicAdd(&counts[ei[E_NUM + e]], 1);
}

// phase 2: exclusive scan over 10000 bins (single block)
__global__ __launch_bounds__(256) void scan_kernel(const int* __restrict__ counts,
                                                   int* __restrict__ offs,
                                                   int* __restrict__ cursor) {
    __shared__ int part[256];
    const int tid = threadIdx.x;
    const int CH = 40;
    int base = tid * CH;
    int s = 0;
    for (int i = 0; i < CH; ++i) {
        int idx = base + i;
        if (idx < N_NUM) s += counts[idx];
    }
    part[tid] = s;
    __syncthreads();
    for (int off = 1; off < 256; off <<= 1) {
        int v = (tid >= off) ? part[tid - off] : 0;
        __syncthreads();
        part[tid] += v;
        __syncthreads();
    }
    int run = (tid > 0) ? part[tid - 1] : 0;
    for (int i = 0; i < CH; ++i) {
        int idx = base + i;
        if (idx < N_NUM) {
            offs[idx] = run;
            cursor[idx] = run;
            run += counts[idx];
        }
    }
    if (tid == 255) offs[N_NUM] = part[255];
}

// phase 3: scatter edges to dst-sorted order.
// meta = (i0 << 14) | src ; i0 = nearest table row (11 bits), src 14 bits.
__global__ __launch_bounds__(256) void scatter_kernel(const int* __restrict__ ei,
                                                      const float* __restrict__ dist,
                                                      int* __restrict__ cursor,
                                                      int* __restrict__ meta) {
    int e = blockIdx.x * 256 + threadIdx.x;
    if (e >= E_NUM) return;
    int d = ei[E_NUM + e];
    int pos = atomicAdd(&cursor[d], 1);
    float t = dist[e] * ((float)(TAB - 1) / 10.0f);
    int i0 = (int)(t + 0.5f);
    if (i0 > TAB - 1) i0 = TAB - 1;
    meta[pos] = (i0 << 14) | ei[e];
}

// ---------------------------------------------------------------------------
// Pack all weights into MFMA B-fragment order (bf16).
// B-frag: idx = ((t*KSP + ks)*64 + L)*8 + j ; n = t*16+(L&15), k = ks*32+(L>>4)*8+j
__global__ __launch_bounds__(256) void pack_kernel(const float* __restrict__ lin2_w,
                                                   const float* __restrict__ lin_w,
                                                   const float* __restrict__ lin1_w,
                                                   const float* __restrict__ o1w,
                                                   const float* __restrict__ o2w,
                                                   const float* __restrict__ mlp_w1,
                                                   const float* __restrict__ mlp_w2,
                                                   short* __restrict__ wpack) {
    int idx = blockIdx.x * 256 + threadIdx.x;
    const int M128 = 16384;
    if (idx < 18 * M128) {
        int g = idx / M128, r = idx % M128;
        const float* src;
        if (g < 6) src = lin2_w + g * M128;
        else if (g < 12) src = lin_w + (g - 6) * M128;
        else src = lin1_w + (g - 12) * M128;
        int j = r & 7, L = (r >> 3) & 63, ks = (r >> 9) & 3, t = r >> 11;
        int n = t * 16 + (L & 15);
        int k = ks * 32 + (L >> 4) * 8 + j;
        wpack[idx] = (short)f2bf(src[k * 128 + n]);
    } else if (idx < WP_O2) {
        int r = idx - WP_O1;              // o1w: K=128, N=64
        int j = r & 7, L = (r >> 3) & 63, ks = (r >> 9) & 3, t = r >> 11;
        int n = t * 16 + (L & 15);
        int k = ks * 32 + (L >> 4) * 8 + j;
        wpack[idx] = (short)f2bf(o1w[k * 64 + n]);
    } else if (idx < WP_W1T) {
        int r = idx - WP_O2;              // o2w: K=64, N=64
        int j = r & 7, L = (r >> 3) & 63, ks = (r >> 9) & 1, t = r >> 10;
        int n = t * 16 + (L & 15);
        int k = ks * 32 + (L >> 4) * 8 + j;
        wpack[idx] = (short)f2bf(o2w[k * 64 + n]);
    } else if (idx < WP_W2T) {
        int r2 = idx - WP_W1T;            // mlp_w1: K=50 pad to 64, N=128
        int g = r2 / 8192, r = r2 % 8192;
        int j = r & 7, L = (r >> 3) & 63, ks = (r >> 9) & 1, t = r >> 10;
        int n = t * 16 + (L & 15);
        int k = ks * 32 + (L >> 4) * 8 + j;
        float v = (k < 50) ? mlp_w1[g * 6400 + k * 128 + n] : 0.f;
        wpack[idx] = (short)f2bf(v);
    } else if (idx < WP_TOT) {
        int r2 = idx - WP_W2T;            // mlp_w2: K=128, N=128
        int g = r2 / M128, r = r2 % M128;
        int j = r & 7, L = (r >> 3) & 63, ks = (r >> 9) & 3, t = r >> 11;
        int n = t * 16 + (L & 15);
        int k = ks * 32 + (L >> 4) * 8 + j;
        wpack[idx] = (short)f2bf(mlp_w2[g * M128 + k * 128 + n]);
    }
}

// ---------------------------------------------------------------------------
// MFMA table build: plain row layout tab[l][i][c] (bf16), nearest-neighbor use.
// 16 d-rows/block, 512 threads, 6*(TAB/16) = 768 blocks.
__global__ __launch_bounds__(512) void table_kernel(const short* __restrict__ w1t,
                                                    const float* __restrict__ mlp_b1,
                                                    const short* __restrict__ w2t,
                                                    const float* __restrict__ mlp_b2,
                                                    ushort_t* __restrict__ tabB) {
    __shared__ short EA[16 * 72];    // bf16 gaussians, K padded to 64
    __shared__ short HD[16 * 136];   // bf16 hidden
    const int tid = threadIdx.x;
    const int wv = tid >> 6;
    const int lane = tid & 63;
    const int l = blockIdx.x >> 7;              // / (TAB/16 = 128)
    const int r0 = (blockIdx.x & 127) * 16;
    const float DG = 10.0f / (float)(TAB - 1);
    const float STEP = 10.0f / 49.0f;
    const float COEFF = -0.5f / (STEP * STEP);

    for (int i = tid; i < 16 * 64; i += 512) {
        int r = i >> 6, k = i & 63;
        float v = 0.f;
        if (k < 50) {
            float d = (float)(r0 + r) * DG;
            float t = d - (float)k * STEP;
            v = __expf(COEFF * t * t);
        }
        EA[r * 72 + k] = (short)f2bf(v);
    }
    __syncthreads();

    const int m = lane & 15, q = lane >> 4;

    // stage 1: hidden = ssp(ea @ w1 + b1), K=64 (padded)
    {
        f32x4 acc = {0.f, 0.f, 0.f, 0.f};
        #pragma unroll
        for (int ks = 0; ks < 2; ++ks) {
            short8_t a = *(const short8_t*)(EA + m * 72 + ks * 32 + q * 8);
            short8_t b = *(const short8_t*)(w1t + l * 8192 + (wv * 2 + ks) * 512 + lane * 8);
            acc = __builtin_amdgcn_mfma_f32_16x16x32_bf16(a, b, acc, 0, 0, 0);
        }
        float bv = mlp_b1[l * 128 + wv * 16 + m];
        #pragma unroll
        for (int i = 0; i < 4; ++i)
            HD[(q * 4 + i) * 136 + wv * 16 + m] = (short)f2bf(ssp_f(acc[i] + bv));
    }
    __syncthreads();

    // stage 2: W = hidden @ w2 + b2, *C(d), plain row write
    {
        f32x4 acc = {0.f, 0.f, 0.f, 0.f};
        #pragma unroll
        for (int ks = 0; ks < 4; ++ks) {
            short8_t a = *(const short8_t*)(HD + m * 136 + ks * 32 + q * 8);
            short8_t b = *(const short8_t*)(w2t + l * 16384 + (wv * 4 + ks) * 512 + lane * 8);
            acc = __builtin_amdgcn_mfma_f32_16x16x32_bf16(a, b, acc, 0, 0, 0);
        }
        int col = wv * 16 + m;
        float bv = mlp_b2[l * 128 + col];
        ushort_t* tl = tabB + (size_t)l * TAB * 128;
        #pragma unroll
        for (int i = 0; i < 4; ++i) {
            int row = r0 + q * 4 + i;
            float d = (float)row * DG;
            float C = 0.5f * (__cosf(d * 0.31415926535f) + 1.0f);
            tl[(size_t)row * 128 + col] = f2bf((acc[i] + bv) * C);
        }
    }
}

// ---------------------------------------------------------------------------
// nearest-neighbor accumulate: 8 cols/lane, one edge
__device__ __forceinline__ void nacc8(short8_t x, short8_t t, float* o) {
    #pragma unroll
    for (int j = 0; j < 8; ++j)
        o[j] = fmaf(bf2f((ushort_t)x[j]), bf2f((ushort_t)t[j]), o[j]);
}

// ---------------------------------------------------------------------------
// Layer 0 front: h = emb[x]; xf = bf16(h @ lin1_w[0]).  8 rows/block, 256 thr.
__global__ __launch_bounds__(256) void embed_lin1_kernel(const int* __restrict__ x,
                                                         const float* __restrict__ emb,
                                                         const float* __restrict__ B,
                                                         float* __restrict__ h,
                                                         ushort_t* __restrict__ xf) {
    __shared__ float AT[128][9];
    __shared__ int s_x[8];
    const int tid = threadIdx.x;
    const int n0 = blockIdx.x * 8;

    if (tid < 8) s_x[tid] = x[n0 + tid];
    __syncthreads();
    for (int i = tid; i < 8 * 128; i += 256) {
        int r = i >> 7, c = i & 127;
        float v = emb[s_x[r] * 128 + c];
        AT[c][r] = v;
        h[(size_t)(n0 + r) * 128 + c] = v;
    }
    __syncthreads();

    const int r  = tid & 7;
    const int c0 = (tid >> 3) * 4;
    float acc[4] = {0.f, 0.f, 0.f, 0.f};
    for (int k = 0; k < 128; k += 4) {
        float a[4];
        #pragma unroll
        for (int u = 0; u < 4; ++u) a[u] = AT[k + u][r];
        #pragma unroll
        for (int u = 0; u < 4; ++u) {
            float4 b = *(const float4*)(B + (size_t)(k + u) * 128 + c0);
            acc[0] = fmaf(a[u], b.x, acc[0]);
            acc[1] = fmaf(a[u], b.y, acc[1]);
            acc[2] = fmaf(a[u], b.z, acc[2]);
            acc[3] = fmaf(a[u], b.w, acc[3]);
        }
    }
    ushort4 o;
    o.x = f2bf(acc[0]); o.y = f2bf(acc[1]); o.z = f2bf(acc[2]); o.w = f2bf(acc[3]);
    *(ushort4*)(xf + (size_t)(n0 + r) * 128 + c0) = o;
}

// ---------------------------------------------------------------------------
// MFMA stage helper: wave computes two 16-col tiles t0,t1.
__device__ __forceinline__ void mfma_stage2(const short* A_lds, const short* wp,
                                            int lane, int t0, int t1,
                                            f32x4& acc0, f32x4& acc1) {
    const int m = lane & 15, q = lane >> 4;
    #pragma unroll
    for (int ks = 0; ks < 4; ++ks) {
        short8_t a  = *(const short8_t*)(A_lds + m * 136 + ks * 32 + q * 8);
        short8_t b0 = *(const short8_t*)(wp + (t0 * 4 + ks) * 512 + lane * 8);
        short8_t b1 = *(const short8_t*)(wp + (t1 * 4 + ks) * 512 + lane * 8);
        acc0 = __builtin_amdgcn_mfma_f32_16x16x32_bf16(a, b0, acc0, 0, 0, 0);
        acc1 = __builtin_amdgcn_mfma_f32_16x16x32_bf16(a, b1, acc1, 0, 0, 0);
    }
}

// ---------------------------------------------------------------------------
// Fused MFMA layer kernel: 16 nodes/block, 256 threads (4 waves).
// phase A: QUARTER-WAVE edge streams — 16 lanes x 8 cols = one 16B/lane load
//          per row; one wave instr serves 4 edges (4 indep streams/wave).
// MFMA stages: wave wv computes col-tiles wv*2, wv*2+1.
template <bool LAST>
__global__ __launch_bounds__(256) void layer_kernel(const int* __restrict__ offs,
                                                    const int* __restrict__ meta,
                                                    const ushort_t* __restrict__ xf,
                                                    const ushort_t* __restrict__ tabB,
                                                    const short* __restrict__ w2p,
                                                    const float* __restrict__ lin2_b,
                                                    const short* __restrict__ wlp,
                                                    const float* __restrict__ lin_b,
                                                    const short* __restrict__ w1p,
                                                    float* __restrict__ h,
                                                    ushort_t* __restrict__ xf_out,
                                                    const short* __restrict__ o1p,
                                                    const float* __restrict__ o1b,
                                                    const short* __restrict__ o2p,
                                                    const float* __restrict__ o2b,
                                                    float* __restrict__ gs) {
    __shared__ short A1[16 * 136];   // bf16, row stride 136 shorts (272 B)
    __shared__ short A2[16 * 136];
    __shared__ float red[4][64];
    const int tid = threadIdx.x;
    const int n0 = blockIdx.x * 16;
    const int wv = tid >> 6;         // 0..3
    const int lane = tid & 63;

    // ---- phase A: quarter-wave edge streams, nearest table row ----
    {
        const int qt = lane >> 4;        // 0..3
        const int c8 = (lane & 15) * 8;  // 8 cols/lane
        const int node = n0 + wv * 4 + qt;
        int e   = offs[node];
        int end = offs[node + 1];

        float accA[8] = {0.f, 0.f, 0.f, 0.f, 0.f, 0.f, 0.f, 0.f};
        float accB[8] = {0.f, 0.f, 0.f, 0.f, 0.f, 0.f, 0.f, 0.f};

        for (; e + 8 <= end; e += 8) {
            int m[8];
            #pragma unroll
            for (int u = 0; u < 8; ++u) m[u] = meta[e + u];
            short8_t xv[8], tv[8];
            #pragma unroll
            for (int u = 0; u < 8; ++u) {
                xv[u] = *(const short8_t*)(xf + (size_t)(m[u] & 0x3FFF) * 128 + c8);
                tv[u] = *(const short8_t*)(tabB + (size_t)((unsigned)m[u] >> 14) * 128 + c8);
            }
            #pragma unroll
            for (int u = 0; u < 8; ++u)
                nacc8(xv[u], tv[u], (u & 1) ? accB : accA);
        }
        for (; e + 4 <= end; e += 4) {
            int m[4];
            #pragma unroll
            for (int u = 0; u < 4; ++u) m[u] = meta[e + u];
            short8_t xv[4], tv[4];
            #pragma unroll
            for (int u = 0; u < 4; ++u) {
                xv[u] = *(const short8_t*)(xf + (size_t)(m[u] & 0x3FFF) * 128 + c8);
                tv[u] = *(const short8_t*)(tabB + (size_t)((unsigned)m[u] >> 14) * 128 + c8);
            }
            #pragma unroll
            for (int u = 0; u < 4; ++u)
                nacc8(xv[u], tv[u], (u & 1) ? accB : accA);
        }
        for (; e < end; ++e) {
            int mm = meta[e];
            short8_t xv = *(const short8_t*)(xf + (size_t)(mm & 0x3FFF) * 128 + c8);
            short8_t tv = *(const short8_t*)(tabB + (size_t)((unsigned)mm >> 14) * 128 + c8);
            nacc8(xv, tv, accA);
        }

        short8_t out;
        #pragma unroll
        for (int j = 0; j < 8; ++j) out[j] = (short)f2bf(accA[j] + accB[j]);
        *(short8_t*)&A1[(wv * 4 + qt) * 136 + c8] = out;
    }
    __syncthreads();

    const int m = lane & 15, q = lane >> 4;
    const int t0 = wv * 2, t1 = wv * 2 + 1;

    // ---- stage 1: t = ssp(agg @ lin2_w + lin2_b) -> A2 ----
    {
        f32x4 acc0 = {0.f, 0.f, 0.f, 0.f}, acc1 = {0.f, 0.f, 0.f, 0.f};
        mfma_stage2(A1, w2p, lane, t0, t1, acc0, acc1);
        float bv0 = lin2_b[t0 * 16 + m];
        float bv1 = lin2_b[t1 * 16 + m];
        #pragma unroll
        for (int i = 0; i < 4; ++i) {
            int r = q * 4 + i;
            A2[r * 136 + t0 * 16 + m] = (short)f2bf(ssp_f(acc0[i] + bv0));
            A2[r * 136 + t1 * 16 + m] = (short)f2bf(ssp_f(acc1[i] + bv1));
        }
    }
    __syncthreads();

    // ---- stage 2: h_new = h + t @ lin_w + lin_b -> A1 (+ global h if !LAST) ----
    {
        f32x4 acc0 = {0.f, 0.f, 0.f, 0.f}, acc1 = {0.f, 0.f, 0.f, 0.f};
        mfma_stage2(A2, wlp, lane, t0, t1, acc0, acc1);
        float bv0 = lin_b[t0 * 16 + m];
        float bv1 = lin_b[t1 * 16 + m];
        #pragma unroll
        for (int i = 0; i < 4; ++i) {
            int r = q * 4 + i;
            int grow = n0 + r;
            float h0 = h[(size_t)grow * 128 + t0 * 16 + m];
            float h1 = h[(size_t)grow * 128 + t1 * 16 + m];
            float hn0 = h0 + acc0[i] + bv0;
            float hn1 = h1 + acc1[i] + bv1;
            if (!LAST) {
                h[(size_t)grow * 128 + t0 * 16 + m] = hn0;
                h[(size_t)grow * 128 + t1 * 16 + m] = hn1;
            }
            A1[r * 136 + t0 * 16 + m] = (short)f2bf(hn0);
            A1[r * 136 + t1 * 16 + m] = (short)f2bf(hn1);
        }
    }
    __syncthreads();

    if constexpr (!LAST) {
        // ---- stage 3: xf_out = bf16(h_new @ lin1_next) ----
        f32x4 acc0 = {0.f, 0.f, 0.f, 0.f}, acc1 = {0.f, 0.f, 0.f, 0.f};
        mfma_stage2(A1, w1p, lane, t0, t1, acc0, acc1);
        #pragma unroll
        for (int i = 0; i < 4; ++i) {
            int r = q * 4 + i;
            int grow = n0 + r;
            xf_out[(size_t)grow * 128 + t0 * 16 + m] = f2bf(acc0[i]);
            xf_out[(size_t)grow * 128 + t1 * 16 + m] = f2bf(acc1[i]);
        }
    } else {
        // ---- fused head: t1 = ssp(h_new@o1w+o1b); t2 = t1@o2w+o2b; colsum ----
        {
            f32x4 acc = {0.f, 0.f, 0.f, 0.f};
            #pragma unroll
            for (int ks = 0; ks < 4; ++ks) {
                short8_t a = *(const short8_t*)(A1 + m * 136 + ks * 32 + q * 8);
                short8_t b = *(const short8_t*)(o1p + (wv * 4 + ks) * 512 + lane * 8);
                acc = __builtin_amdgcn_mfma_f32_16x16x32_bf16(a, b, acc, 0, 0, 0);
            }
            float bv = o1b[wv * 16 + m];
            #pragma unroll
            for (int i = 0; i < 4; ++i) {
                int r = q * 4 + i;
                A2[r * 136 + wv * 16 + m] = (short)f2bf(ssp_f(acc[i] + bv));
            }
        }
        __syncthreads();
        {
            f32x4 acc = {0.f, 0.f, 0.f, 0.f};
            #pragma unroll
            for (int ks = 0; ks < 2; ++ks) {
                short8_t a = *(const short8_t*)(A2 + m * 136 + ks * 32 + q * 8);
                short8_t b = *(const short8_t*)(o2p + (wv * 2 + ks) * 512 + lane * 8);
                acc = __builtin_amdgcn_mfma_f32_16x16x32_bf16(a, b, acc, 0, 0, 0);
            }
            float bv = o2b[wv * 16 + m];
            float part = acc[0] + acc[1] + acc[2] + acc[3] + 4.0f * bv;
            red[q][wv * 16 + m] = part;
        }
        __syncthreads();
        if (tid < 64) {
            float s = red[0][tid] + red[1][tid] + red[2][tid] + red[3][tid];
            atomicAdd(&gs[tid], s);
        }
    }
}

// out[i] = ro_b[i] + sum_k gs[k] * ro_w[k][i]
__global__ void final_kernel(const float* __restrict__ gs,
                             const float* __restrict__ ro_w,
                             const float* __restrict__ ro_b,
                             float* __restrict__ out) {
    int i = threadIdx.x;
    if (i < 12) {
        float s = ro_b[i];
        for (int k = 0; k < 64; ++k) s = fmaf(gs[k], ro_w[k * 12 + i], s);
        out[i] = s;
    }
}

// ---------------------------------------------------------------------------
extern "C" void kernel_launch(void* const* d_in, const int* in_sizes, int n_in,
                              void* d_out, int out_size, void* d_ws, size_t ws_size,
                              hipStream_t stream) {
    const int*   x      = (const int*)d_in[0];
    const int*   ei     = (const int*)d_in[1];
    const float* dist   = (const float*)d_in[2];
    const float* emb    = (const float*)d_in[3];
    const float* mlp_w1 = (const float*)d_in[4];
    const float* mlp_b1 = (const float*)d_in[5];
    const float* mlp_w2 = (const float*)d_in[6];
    const float* mlp_b2 = (const float*)d_in[7];
    const float* lin1_w = (const float*)d_in[8];
    const float* lin2_w = (const float*)d_in[9];
    const float* lin2_b = (const float*)d_in[10];
    const float* lin_w  = (const float*)d_in[11];
    const float* lin_b  = (const float*)d_in[12];
    const float* out1_w = (const float*)d_in[13];
    const float* out1_b = (const float*)d_in[14];
    const float* out2_w = (const float*)d_in[15];
    const float* out2_b = (const float*)d_in[16];
    const float* ro_w   = (const float*)d_in[17];
    const float* ro_b   = (const float*)d_in[18];
    float* out = (float*)d_out;

    // workspace layout
    char* base = (char*)d_ws;
    float*    h     = (float*)base;     base += (size_t)N_NUM * 128 * 4;
    ushort_t* tabB  = (ushort_t*)base;  base += (size_t)6 * TAB * 128 * 2;
    ushort_t* xf0   = (ushort_t*)base;  base += (size_t)N_NUM * 128 * 2;
    ushort_t* xf1   = (ushort_t*)base;  base += (size_t)N_NUM * 128 * 2;
    int*      meta  = (int*)base;       base += (size_t)E_NUM * 4;
    short*    wpack = (short*)base;     base += (size_t)WP_TOT * 2;
    float*    gs    = (float*)base;     base += 64 * 4;
    int*      offs  = (int*)base;       base += (N_NUM + 1) * 4;
    int*      cursor= (int*)base;       base += N_NUM * 4;
    int*      counts= (int*)base;       base += N_NUM * 4;

    hipMemsetAsync(counts, 0, N_NUM * sizeof(int), stream);
    hipMemsetAsync(gs, 0, 64 * sizeof(float), stream);

    // sort edges by dst (once; dst constant across layers)
    hist_kernel<<<(E_NUM + 255) / 256, 256, 0, stream>>>(ei, counts);
    scan_kernel<<<1, 256, 0, stream>>>(counts, offs, cursor);
    scatter_kernel<<<(E_NUM + 255) / 256, 256, 0, stream>>>(ei, dist, cursor, meta);

    // pack all weights (MFMA B-frag bf16), then build filter tables via MFMA
    pack_kernel<<<(WP_TOT + 255) / 256, 256, 0, stream>>>(
        lin2_w, lin_w, lin1_w, out1_w, out2_w, mlp_w1, mlp_w2, wpack);
    table_kernel<<<6 * (TAB / 16), 512, 0, stream>>>(
        wpack + WP_W1T, mlp_b1, wpack + WP_W2T, mlp_b2, tabB);

    // layer 0 front: h = emb[x], xf0 = bf16(h @ lin1_w[0])
    embed_lin1_kernel<<<NB8, 256, 0, stream>>>(x, emb, lin1_w, h, xf0);

    const short* o1p = wpack + WP_O1;
    const short* o2p = wpack + WP_O2;

    for (int l = 0; l < 6; ++l) {
        ushort_t* xin  = (l & 1) ? xf1 : xf0;
        ushort_t* xout = (l & 1) ? xf0 : xf1;
        const ushort_t* tl = tabB + (size_t)l * TAB * 128;
        const short* w2p = wpack + l * 16384;
        const short* wlp = wpack + (6 + l) * 16384;
        if (l < 5) {
            const short* w1p = wpack + (12 + l + 1) * 16384;   // lin1_w[l+1]
            layer_kernel<false><<<NB16, 256, 0, stream>>>(
                offs, meta, xin, tl,
                w2p, lin2_b + l * 128, wlp, lin_b + l * 128, w1p,
                h, xout, nullptr, nullptr, nullptr, nullptr, nullptr);
        } else {
            layer_kernel<true><<<NB16, 256, 0, stream>>>(
                offs, meta, xin, tl,
                w2p, lin2_b + l * 128, wlp, lin_b + l * 128, nullptr,
                h, nullptr, o1p, out1_b, o2p, out2_b, gs);
        }
    }

    final_kernel<<<1, 64, 0, stream>>>(gs, ro_w, ro_b, out);
}